// Round 2
// baseline (2965.823 us; speedup 1.0000x reference)
//
#include <hip/hip_runtime.h>
#include <cstddef>
#include <cstdint>

#define LQ 1024
#define DMQ 768
#define DSQ 256
#define DIQ 512

__device__ __forceinline__ float sigf(float x) { return 1.f / (1.f + __expf(-x)); }
__device__ __forceinline__ float softplusf(float x) {
    return fmaxf(x, 0.f) + log1pf(__expf(-fabsf(x)));
}

// ---------------- lengths from mask ----------------
__global__ void k_lengths(const int* __restrict__ mask, int* __restrict__ lengths) {
    int b = blockIdx.x;
    int s = 0;
    for (int t = threadIdx.x; t < LQ; t += 256) s += mask[b * LQ + t];
    __shared__ int sm[256];
    sm[threadIdx.x] = s;
    __syncthreads();
    for (int o = 128; o > 0; o >>= 1) {
        if (threadIdx.x < o) sm[threadIdx.x] += sm[threadIdx.x + o];
        __syncthreads();
    }
    if (threadIdx.x == 0) lengths[b] = sm[0];
}

// ---------------- dilated dw conv + BN + GELU -> c (one scale) ----------------
// grid 8192 (b,l), block 256 (ch)
__global__ void k_pool(const float* __restrict__ hid, const float* __restrict__ pw,
                       const float* __restrict__ pb, const float* __restrict__ bg,
                       const float* __restrict__ bb, const float* __restrict__ brm,
                       const float* __restrict__ brv, int isc, float* __restrict__ cdst) {
    int idx = blockIdx.x;
    int l = idx & (LQ - 1);
    int b = idx >> 10;
    int ch = threadIdx.x;
    int dil = 1 << isc;
    int wci = isc * DSQ + ch;
    const float* xb = hid + (size_t)b * LQ * DMQ + isc * DSQ + ch;
    float w0 = pw[wci * 3 + 0], w1 = pw[wci * 3 + 1], w2 = pw[wci * 3 + 2];
    float acc = pb[wci];
    int lm = l - dil, lp = l + dil;
    if (lm >= 0) acc += xb[(size_t)lm * DMQ] * w0;
    acc += xb[(size_t)l * DMQ] * w1;
    if (lp < LQ) acc += xb[(size_t)lp * DMQ] * w2;
    float xn = (acc - brm[wci]) * rsqrtf(brv[wci] + 1e-5f) * bg[wci] + bb[wci];
    float y = 0.5f * xn * (1.0f + erff(xn * 0.70710678118654752f));
    cdst[(size_t)idx * DSQ + ch] = y;
}

// ---------------- generic fp32 GEMM: C[m,n] (+)= sum_k A[m,k]*Bw[n,k] ----------------
// 128x128 tile, 256 threads, 8x8/thread. M mult of 128, K mult of 16.
template <int FLIPA, int FLIPC, int BIAS, int ACC>
__global__ __launch_bounds__(256) void gemm_nt(const float* __restrict__ A,
                                               const float* __restrict__ Bw,
                                               float* __restrict__ C,
                                               const float* __restrict__ bias, int N, int Kd,
                                               int lda, int ldc,
                                               const int* __restrict__ lengths) {
    __shared__ float As[16][132];
    __shared__ float Bs[16][132];
    const int tid = threadIdx.x;
    const int tx = tid & 15, ty = tid >> 4;
    const int row0 = blockIdx.y * 128, col0 = blockIdx.x * 128;
    int len = 0;
    if (FLIPA || FLIPC) len = lengths[row0 >> 10];

    float acc[8][8];
#pragma unroll
    for (int i = 0; i < 8; i++)
#pragma unroll
        for (int j = 0; j < 8; j++) acc[i][j] = 0.f;

    const int lr = tid >> 1;
    const int lc = (tid & 1) << 3;
    int gr = row0 + lr;
    if (FLIPA) {
        int t = gr & (LQ - 1);
        int ts = (t < len) ? (len - 1 - t) : t;
        gr = (gr & ~(LQ - 1)) | ts;
    }
    const float* aptr = A + (size_t)gr * lda + lc;
    const int bn = col0 + lr;
    const float* bptr = Bw + (size_t)bn * Kd + lc;
    const bool bvld = (bn < N);

    for (int k0 = 0; k0 < Kd; k0 += 16) {
        float4 a0 = *(const float4*)(aptr + k0);
        float4 a1 = *(const float4*)(aptr + k0 + 4);
        float4 b0 = make_float4(0.f, 0.f, 0.f, 0.f), b1 = make_float4(0.f, 0.f, 0.f, 0.f);
        if (bvld) {
            b0 = *(const float4*)(bptr + k0);
            b1 = *(const float4*)(bptr + k0 + 4);
        }
        __syncthreads();
        As[lc + 0][lr] = a0.x; As[lc + 1][lr] = a0.y; As[lc + 2][lr] = a0.z; As[lc + 3][lr] = a0.w;
        As[lc + 4][lr] = a1.x; As[lc + 5][lr] = a1.y; As[lc + 6][lr] = a1.z; As[lc + 7][lr] = a1.w;
        Bs[lc + 0][lr] = b0.x; Bs[lc + 1][lr] = b0.y; Bs[lc + 2][lr] = b0.z; Bs[lc + 3][lr] = b0.w;
        Bs[lc + 4][lr] = b1.x; Bs[lc + 5][lr] = b1.y; Bs[lc + 6][lr] = b1.z; Bs[lc + 7][lr] = b1.w;
        __syncthreads();
#pragma unroll
        for (int kk = 0; kk < 16; kk++) {
            float av[8], bv[8];
#pragma unroll
            for (int i = 0; i < 8; i++) av[i] = As[kk][ty * 8 + i];
#pragma unroll
            for (int j = 0; j < 8; j++) bv[j] = Bs[kk][tx * 8 + j];
#pragma unroll
            for (int i = 0; i < 8; i++)
#pragma unroll
                for (int j = 0; j < 8; j++) acc[i][j] = fmaf(av[i], bv[j], acc[i][j]);
        }
    }
#pragma unroll
    for (int i = 0; i < 8; i++) {
        int grow = row0 + ty * 8 + i;
        if (FLIPC) {
            int t = grow & (LQ - 1);
            int ts = (t < len) ? (len - 1 - t) : t;
            grow = (grow & ~(LQ - 1)) | ts;
        }
        float* cp = C + (size_t)grow * ldc + col0 + tx * 8;
#pragma unroll
        for (int j = 0; j < 8; j++) {
            int col = col0 + tx * 8 + j;
            if (col < N) {
                float v = acc[i][j];
                if (ACC) v += cp[j];
                if (BIAS) v += bias[col];
                cp[j] = v;
            }
        }
    }
}

// ---------------- causal depthwise conv (K=4) + SiLU ----------------
__global__ void k_dwconv(const float* __restrict__ xin, const float* __restrict__ w4,
                         const float* __restrict__ b1, float* __restrict__ xout) {
    int bt = blockIdx.x;
    int t = bt & (LQ - 1);
    int ch = threadIdx.x;
    const float* w = w4 + ch * 4;
    float acc = b1[ch];
    const float* xp = xin + (size_t)bt * DIQ + ch;
#pragma unroll
    for (int k = 0; k < 4; k++) {
        int ts = t - 3 + k;
        if (ts >= 0) acc += xp[(ptrdiff_t)(ts - t) * DIQ] * w[k];
    }
    xout[(size_t)bt * DIQ + ch] = acc * sigf(acc);
}

// ---------------- fused dt + selective scan + D skip (y overwrites x in place) ----
// grid g*8 (slot,b), block 512 (d)
__global__ __launch_bounds__(512) void k_scan(float* __restrict__ scanX,
                                              const float* __restrict__ xdbl,
                                              const float* __restrict__ dt_w,
                                              const float* __restrict__ dt_b,
                                              const float* __restrict__ A_log,
                                              const float* __restrict__ Dpp, int instBase) {
    int slot = blockIdx.x >> 3, b = blockIdx.x & 7;
    int inst = instBase + slot;
    int ch = threadIdx.x;
    const float* xd = xdbl + ((size_t)slot * 8 + b) * LQ * 48;
    float* xp = scanX + (((size_t)slot * 8 + b) * LQ) * DIQ + ch;
    int wo = inst * DIQ + ch;
    float dtw[16], Ad[16];
#pragma unroll
    for (int r = 0; r < 16; r++) dtw[r] = dt_w[(size_t)wo * 16 + r];
    float dtb = dt_b[wo];
#pragma unroll
    for (int n = 0; n < 16; n++) Ad[n] = -__expf(A_log[(size_t)wo * 16 + n]);
    float Dd = Dpp[wo];
    float h[16];
#pragma unroll
    for (int n = 0; n < 16; n++) h[n] = 0.f;

    __shared__ float sd[256 * 48];  // 48KB
    for (int c0 = 0; c0 < LQ; c0 += 256) {
        __syncthreads();
        for (int u = threadIdx.x; u < 256 * 48; u += 512) sd[u] = xd[(size_t)c0 * 48 + u];
        __syncthreads();
        for (int tl = 0; tl < 256; tl++) {
            const float* s = sd + tl * 48;
            float draw = dtb;
#pragma unroll
            for (int r = 0; r < 16; r++) draw = fmaf(s[r], dtw[r], draw);
            float dt = softplusf(draw);
            float xt = xp[(size_t)(c0 + tl) * DIQ];
            float dtx = dt * xt;
            float y = 0.f;
#pragma unroll
            for (int n = 0; n < 16; n++) {
                float e = __expf(dt * Ad[n]);
                h[n] = fmaf(h[n], e, dtx * s[16 + n]);
                y = fmaf(h[n], s[32 + n], y);
            }
            xp[(size_t)(c0 + tl) * DIQ] = fmaf(xt, Dd, y);
        }
    }
}

// ---------------- y *= silu(z) ----------------
__global__ void k_gate(float* __restrict__ y, const float* __restrict__ z) {
    size_t idx = (size_t)blockIdx.x * 256 + threadIdx.x;
    float zv = z[idx];
    y[idx] *= zv * sigf(zv);
}

// ---------------- fused weight: Wf[m,d] = sum_c opw_half[m,c]*mow[c,d] ----------------
__global__ void k_wfuse(const float* __restrict__ opw_h, const float* __restrict__ mow_i,
                        float* __restrict__ wf) {
    int idx = blockIdx.x * 256 + threadIdx.x;  // 0..131071
    int m = idx >> 9, d = idx & 511;
    const float* a = opw_h + (size_t)m * 512;  // +c
    const float* bm = mow_i + d;               // +c*512
    float s = 0.f;
    for (int c = 0; c < 256; c++) s = fmaf(a[c], bm[(size_t)c * 512], s);
    wf[idx] = s;
}

// ---------------- mean/max over L ----------------
__global__ void k_redu(const float* __restrict__ o, float* __restrict__ avg,
                       float* __restrict__ mx) {
    int idx = blockIdx.x * 256 + threadIdx.x;  // 0..6143
    int b = idx / DMQ, ch = idx % DMQ;
    const float* p = o + (size_t)b * LQ * DMQ + ch;
    float s = 0.f, m = -3.4e38f;
    for (int t = 0; t < LQ; t++) {
        float v = p[(size_t)t * DMQ];
        s += v;
        m = fmaxf(m, v);
    }
    avg[idx] = s * (1.f / LQ);
    mx[idx] = m;
}

__global__ void k_att1(const float* __restrict__ avg, const float* __restrict__ mx,
                       const float* __restrict__ w1, float* __restrict__ hs) {
    int idx = blockIdx.x * 256 + threadIdx.x;  // 0..3071
    int b = idx / 384, j = idx % 384;
    const float* w = w1 + (size_t)j * DMQ;
    const float* a = avg + (size_t)b * DMQ;
    const float* m2 = mx + (size_t)b * DMQ;
    float s1 = 0.f, s2 = 0.f;
    for (int k = 0; k < DMQ; k++) {
        s1 = fmaf(a[k], w[k], s1);
        s2 = fmaf(m2[k], w[k], s2);
    }
    hs[idx] = fmaxf(s1, 0.f) + fmaxf(s2, 0.f);
}

__global__ void k_att2(const float* __restrict__ hs, const float* __restrict__ w2,
                       float* __restrict__ att) {
    int idx = blockIdx.x * 256 + threadIdx.x;  // 0..6143
    int b = idx / DMQ, n = idx % DMQ;
    const float* w = w2 + (size_t)n * 384;
    const float* h = hs + (size_t)b * 384;
    float s = 0.f;
    for (int k = 0; k < 384; k++) s = fmaf(h[k], w[k], s);
    att[idx] = sigf(s);
}

__global__ void k_scale(float* __restrict__ o, const float* __restrict__ att) {
    size_t idx = (size_t)blockIdx.x * 256 + threadIdx.x;
    int ch = (int)(idx % DMQ);
    int b = (int)(idx / ((size_t)LQ * DMQ));
    o[idx] *= att[b * DMQ + ch];
}

__global__ void k_diag(float* __restrict__ o, float v) {
    if (blockIdx.x == 0 && threadIdx.x == 0) o[0] = v;
}

extern "C" void kernel_launch(void* const* d_in, const int* in_sizes, int n_in, void* d_out,
                              int out_size, void* d_ws, size_t ws_size, hipStream_t stream) {
    (void)in_sizes; (void)n_in; (void)out_size;
    const float* hid = (const float*)d_in[0];
    const int* mask = (const int*)d_in[1];
    const float* pool_w = (const float*)d_in[2];
    const float* pool_b = (const float*)d_in[3];
    const float* bn_g = (const float*)d_in[4];
    const float* bn_b = (const float*)d_in[5];
    const float* bn_rm = (const float*)d_in[6];
    const float* bn_rv = (const float*)d_in[7];
    const float* ipw = (const float*)d_in[8];
    const float* cw = (const float*)d_in[9];
    const float* cb = (const float*)d_in[10];
    const float* xpw = (const float*)d_in[11];
    const float* dtw = (const float*)d_in[12];
    const float* dtb = (const float*)d_in[13];
    const float* alog = (const float*)d_in[14];
    const float* Dpp = (const float*)d_in[15];
    const float* mow = (const float*)d_in[16];
    const float* opw = (const float*)d_in[17];
    const float* opb = (const float*)d_in[18];
    const float* caw1 = (const float*)d_in[19];
    const float* caw2 = (const float*)d_in[20];
    const float* fusw = (const float*)d_in[21];
    const float* fusb = (const float*)d_in[22];
    float* out = (float*)d_out;

    const size_t F_SMALL = 32768;
    const size_t F_WT = 131072;        // 256x512 fused weight
    const size_t F_XDBL = 393216;      // per inst: 8*1024*48
    const size_t F_INST = 4194304;     // per inst: 8*1024*512
    const size_t F_CSC = 2097152;      // per scale: 8*1024*256

    auto needB = [&](int g, int ckeep) -> size_t {
        size_t f = F_SMALL + F_WT + (size_t)g * F_XDBL + (size_t)g * F_INST + F_INST +
                   (ckeep ? 3 * F_CSC : F_CSC);
        return f * 4;
    };
    int g = 0, ckeep = 0;
    if (ws_size >= needB(6, 1)) { g = 6; ckeep = 1; }
    else if (ws_size >= needB(3, 1)) { g = 3; ckeep = 1; }
    else if (ws_size >= needB(1, 1)) { g = 1; ckeep = 1; }
    else if (ws_size >= needB(1, 0)) { g = 1; ckeep = 0; }
    else {
        k_diag<<<1, 64, 0, stream>>>(out, (float)(ws_size >> 20));
        return;
    }

    float* ws = (float*)d_ws;
    int* lengths = (int*)ws;
    float* avg = ws + 1024;
    float* mxp = avg + 6144;
    float* hs = mxp + 6144;
    float* att = hs + 3072;
    float* wtmp = ws + F_SMALL;
    float* xdbl = wtmp + F_WT;
    float* cbase = xdbl + (size_t)g * F_XDBL;
    float* scanX = cbase + (ckeep ? 3 * F_CSC : F_CSC);
    float* xzx = scanX + (size_t)g * F_INST;
    float* fusout = scanX;  // overlay: scanX+xzx >= 32MB >= 24MB needed; dead by then

    k_lengths<<<dim3(8), dim3(256), 0, stream>>>(mask, lengths);
    if (ckeep)
        for (int i = 0; i < 3; i++)
            k_pool<<<dim3(8192), dim3(256), 0, stream>>>(hid, pool_w, pool_b, bn_g, bn_b, bn_rm,
                                                         bn_rv, i, cbase + (size_t)i * F_CSC);

    for (int base = 0; base < 6; base += g) {
        // phase 1: x-half in_proj -> dwconv -> xdbl
        for (int s = 0; s < g; s++) {
            int inst = base + s, i = inst >> 1, dir = inst & 1;
            float* ci = ckeep ? cbase + (size_t)i * F_CSC : cbase;
            if (!ckeep)
                k_pool<<<dim3(8192), dim3(256), 0, stream>>>(hid, pool_w, pool_b, bn_g, bn_b,
                                                             bn_rm, bn_rv, i, ci);
            const float* W = ipw + (size_t)inst * 1024 * DSQ;
            float* sx = scanX + (size_t)s * F_INST;
            if (dir == 0)
                gemm_nt<0, 0, 0, 0><<<dim3(4, 64), 256, 0, stream>>>(ci, W, xzx, nullptr, 512,
                                                                     256, 256, 512, lengths);
            else
                gemm_nt<1, 0, 0, 0><<<dim3(4, 64), 256, 0, stream>>>(ci, W, xzx, nullptr, 512,
                                                                     256, 256, 512, lengths);
            k_dwconv<<<dim3(8192), dim3(512), 0, stream>>>(xzx, cw + (size_t)inst * DIQ * 4,
                                                           cb + (size_t)inst * DIQ, sx);
            gemm_nt<0, 0, 0, 0><<<dim3(1, 64), 256, 0, stream>>>(
                sx, xpw + (size_t)inst * 48 * DIQ, xdbl + (size_t)s * F_XDBL, nullptr, 48, 512,
                512, 48, lengths);
        }
        // phase 2: selective scan (in place)
        k_scan<<<dim3(g * 8), dim3(512), 0, stream>>>(scanX, xdbl, dtw, dtb, alog, Dpp, base);
        // phase 3: z-half in_proj -> gate -> fused mo+op accumulate into d_out
        for (int s = 0; s < g; s++) {
            int inst = base + s, i = inst >> 1, dir = inst & 1;
            float* ci = ckeep ? cbase + (size_t)i * F_CSC : cbase;
            if (!ckeep)
                k_pool<<<dim3(8192), dim3(256), 0, stream>>>(hid, pool_w, pool_b, bn_g, bn_b,
                                                             bn_rm, bn_rv, i, ci);
            const float* Wz = ipw + (size_t)inst * 1024 * DSQ + 512 * 256;
            if (dir == 0)
                gemm_nt<0, 0, 0, 0><<<dim3(4, 64), 256, 0, stream>>>(ci, Wz, xzx, nullptr, 512,
                                                                     256, 256, 512, lengths);
            else
                gemm_nt<1, 0, 0, 0><<<dim3(4, 64), 256, 0, stream>>>(ci, Wz, xzx, nullptr, 512,
                                                                     256, 256, 512, lengths);
            float* sx = scanX + (size_t)s * F_INST;
            k_gate<<<dim3(16384), dim3(256), 0, stream>>>(sx, xzx);
            k_wfuse<<<dim3(512), dim3(256), 0, stream>>>(opw + (size_t)i * 131072 + dir * 256,
                                                         mow + (size_t)inst * 131072, wtmp);
            if (dir == 0)
                gemm_nt<0, 0, 0, 0><<<dim3(2, 64), 256, 0, stream>>>(
                    sx, wtmp, out + i * 256, nullptr, 256, 512, 512, DMQ, lengths);
            else
                gemm_nt<0, 1, 1, 1><<<dim3(2, 64), 256, 0, stream>>>(
                    sx, wtmp, out + i * 256, opb + (size_t)i * 256, 256, 512, 512, DMQ, lengths);
        }
    }

    // attention pooling + final projection
    k_redu<<<dim3(24), dim3(256), 0, stream>>>(out, avg, mxp);
    k_att1<<<dim3(12), dim3(256), 0, stream>>>(avg, mxp, caw1, hs);
    k_att2<<<dim3(24), dim3(256), 0, stream>>>(hs, caw2, att);
    k_scale<<<dim3(24576), dim3(256), 0, stream>>>(out, att);
    gemm_nt<0, 0, 1, 0><<<dim3(6, 64), 256, 0, stream>>>(out, fusw, fusout, fusb, DMQ, DMQ, DMQ,
                                                         DMQ, lengths);
    hipMemcpyAsync(d_out, fusout, (size_t)DMQ * LQ * 8 * 4, hipMemcpyDeviceToDevice, stream);
}

// Round 3
// 1990.759 us; speedup vs baseline: 1.4898x; 1.4898x over previous
//
#include <hip/hip_runtime.h>
#include <cstddef>
#include <cstdint>

#define LQ 1024
#define DMQ 768
#define DSQ 256
#define DIQ 512

using f32x4 = __attribute__((ext_vector_type(4))) float;
using bf16x8 = __attribute__((ext_vector_type(8))) short;
using s16x4 = __attribute__((ext_vector_type(4))) short;

__device__ __forceinline__ float sigf(float x) { return 1.f / (1.f + __expf(-x)); }
__device__ __forceinline__ float softplusf(float x) {
    return fmaxf(x, 0.f) + log1pf(__expf(-fabsf(x)));
}
__device__ __forceinline__ short f2bf(float f) {
    unsigned u = __float_as_uint(f);
    u += 0x7FFFu + ((u >> 16) & 1u);  // round-to-nearest-even
    return (short)(u >> 16);
}

// ---------------- lengths from mask ----------------
__global__ void k_lengths(const int* __restrict__ mask, int* __restrict__ lengths) {
    int b = blockIdx.x;
    int s = 0;
    for (int t = threadIdx.x; t < LQ; t += 256) s += mask[b * LQ + t];
    __shared__ int sm[256];
    sm[threadIdx.x] = s;
    __syncthreads();
    for (int o = 128; o > 0; o >>= 1) {
        if (threadIdx.x < o) sm[threadIdx.x] += sm[threadIdx.x + o];
        __syncthreads();
    }
    if (threadIdx.x == 0) lengths[b] = sm[0];
}

// ---------------- dilated dw conv + BN + GELU -> c (one scale) ----------------
__global__ void k_pool(const float* __restrict__ hid, const float* __restrict__ pw,
                       const float* __restrict__ pb, const float* __restrict__ bg,
                       const float* __restrict__ bb, const float* __restrict__ brm,
                       const float* __restrict__ brv, int isc, float* __restrict__ cdst) {
    int idx = blockIdx.x;
    int l = idx & (LQ - 1);
    int b = idx >> 10;
    int ch = threadIdx.x;
    int dil = 1 << isc;
    int wci = isc * DSQ + ch;
    const float* xb = hid + (size_t)b * LQ * DMQ + isc * DSQ + ch;
    float w0 = pw[wci * 3 + 0], w1 = pw[wci * 3 + 1], w2 = pw[wci * 3 + 2];
    float acc = pb[wci];
    int lm = l - dil, lp = l + dil;
    if (lm >= 0) acc += xb[(size_t)lm * DMQ] * w0;
    acc += xb[(size_t)l * DMQ] * w1;
    if (lp < LQ) acc += xb[(size_t)lp * DMQ] * w2;
    float xn = (acc - brm[wci]) * rsqrtf(brv[wci] + 1e-5f) * bg[wci] + bb[wci];
    float y = 0.5f * xn * (1.0f + erff(xn * 0.70710678118654752f));
    cdst[(size_t)idx * DSQ + ch] = y;
}

// ---------------- bf16 MFMA GEMM: C[m,n] (+)= sum_k A[m,k]*Bw[n,k] ----------------
// A,Bw fp32 in global (cast to bf16 during LDS staging), fp32 accumulate.
// 128x128 tile, 256 threads (4 waves, 2x2 of 64x64), BK=64. M mult 128, K mult 64.
template <int FLIPA, int FLIPC, int BIAS, int ACC>
__global__ __launch_bounds__(256) void gemm_mfma(const float* __restrict__ A,
                                                 const float* __restrict__ Bw,
                                                 float* __restrict__ C,
                                                 const float* __restrict__ bias, int N, int Kd,
                                                 int lda, int ldc,
                                                 const int* __restrict__ lengths) {
    __shared__ short Als[128][72];  // +8 pad: row stride 144B -> conflict-free-ish
    __shared__ short Bls[128][72];
    const int tid = threadIdx.x;
    const int lane = tid & 63;
    const int wave = tid >> 6;
    const int wr = wave >> 1, wc = wave & 1;
    const int row0 = blockIdx.y * 128, col0 = blockIdx.x * 128;
    int len = 0;
    if (FLIPA || FLIPC) len = lengths[row0 >> 10];

    const int sr = tid >> 4;         // 0..15 staging row-in-pass
    const int sc4 = (tid & 15) * 4;  // 0..60 staging col (x4 floats)

    f32x4 acc[4][4];
#pragma unroll
    for (int i = 0; i < 4; i++)
#pragma unroll
        for (int j = 0; j < 4; j++) acc[i][j] = (f32x4){0.f, 0.f, 0.f, 0.f};

    for (int k0 = 0; k0 < Kd; k0 += 64) {
        __syncthreads();
#pragma unroll
        for (int p = 0; p < 8; p++) {
            int row = p * 16 + sr;
            int grow = row0 + row;
            if (FLIPA) {
                int t = grow & (LQ - 1);
                int ts = (t < len) ? (len - 1 - t) : t;
                grow = (grow & ~(LQ - 1)) | ts;
            }
            float4 v = *(const float4*)(A + (size_t)grow * lda + k0 + sc4);
            s16x4 w = {f2bf(v.x), f2bf(v.y), f2bf(v.z), f2bf(v.w)};
            *(s16x4*)&Als[row][sc4] = w;
        }
#pragma unroll
        for (int p = 0; p < 8; p++) {
            int row = p * 16 + sr;
            int bn = col0 + row;
            float4 v = make_float4(0.f, 0.f, 0.f, 0.f);
            if (bn < N) v = *(const float4*)(Bw + (size_t)bn * Kd + k0 + sc4);
            s16x4 w = {f2bf(v.x), f2bf(v.y), f2bf(v.z), f2bf(v.w)};
            *(s16x4*)&Bls[row][sc4] = w;
        }
        __syncthreads();
#pragma unroll
        for (int ks = 0; ks < 2; ks++) {
            bf16x8 am[4], bv[4];
#pragma unroll
            for (int f = 0; f < 4; f++) {
                am[f] = *(const bf16x8*)&Als[wr * 64 + f * 16 + (lane & 15)]
                                            [ks * 32 + (lane >> 4) * 8];
                bv[f] = *(const bf16x8*)&Bls[wc * 64 + f * 16 + (lane & 15)]
                                            [ks * 32 + (lane >> 4) * 8];
            }
#pragma unroll
            for (int fm = 0; fm < 4; fm++)
#pragma unroll
                for (int fn = 0; fn < 4; fn++)
                    acc[fm][fn] = __builtin_amdgcn_mfma_f32_16x16x32_bf16(am[fm], bv[fn],
                                                                          acc[fm][fn], 0, 0, 0);
        }
    }
#pragma unroll
    for (int fm = 0; fm < 4; fm++) {
#pragma unroll
        for (int r = 0; r < 4; r++) {
            int grow = row0 + wr * 64 + fm * 16 + (lane >> 4) * 4 + r;
            if (FLIPC) {
                int t = grow & (LQ - 1);
                int ts = (t < len) ? (len - 1 - t) : t;
                grow = (grow & ~(LQ - 1)) | ts;
            }
            float* cp = C + (size_t)grow * ldc;
#pragma unroll
            for (int fn = 0; fn < 4; fn++) {
                int col = col0 + wc * 64 + fn * 16 + (lane & 15);
                if (col < N) {
                    float v = acc[fm][fn][r];
                    if (ACC) v += cp[col];
                    if (BIAS) v += bias[col];
                    cp[col] = v;
                }
            }
        }
    }
}

// ---------------- causal depthwise conv (K=4) + SiLU ----------------
__global__ void k_dwconv(const float* __restrict__ xin, const float* __restrict__ w4,
                         const float* __restrict__ b1, float* __restrict__ xout) {
    int bt = blockIdx.x;
    int t = bt & (LQ - 1);
    int ch = threadIdx.x;
    const float* w = w4 + ch * 4;
    float acc = b1[ch];
    const float* xp = xin + (size_t)bt * DIQ + ch;
#pragma unroll
    for (int k = 0; k < 4; k++) {
        int ts = t - 3 + k;
        if (ts >= 0) acc += xp[(ptrdiff_t)(ts - t) * DIQ] * w[k];
    }
    xout[(size_t)bt * DIQ + ch] = acc * sigf(acc);
}

// ---------------- fused dt + selective scan + D skip (y overwrites x in place) ----
__global__ __launch_bounds__(512) void k_scan(float* __restrict__ scanX,
                                              const float* __restrict__ xdbl,
                                              const float* __restrict__ dt_w,
                                              const float* __restrict__ dt_b,
                                              const float* __restrict__ A_log,
                                              const float* __restrict__ Dpp, int instBase) {
    int slot = blockIdx.x >> 3, b = blockIdx.x & 7;
    int inst = instBase + slot;
    int ch = threadIdx.x;
    const float* xd = xdbl + ((size_t)slot * 8 + b) * LQ * 48;
    float* xp = scanX + (((size_t)slot * 8 + b) * LQ) * DIQ + ch;
    int wo = inst * DIQ + ch;
    float dtw[16], Ad[16];
#pragma unroll
    for (int r = 0; r < 16; r++) dtw[r] = dt_w[(size_t)wo * 16 + r];
    float dtb = dt_b[wo];
#pragma unroll
    for (int n = 0; n < 16; n++) Ad[n] = -__expf(A_log[(size_t)wo * 16 + n]);
    float Dd = Dpp[wo];
    float h[16];
#pragma unroll
    for (int n = 0; n < 16; n++) h[n] = 0.f;

    __shared__ float sd[256 * 48];  // 48KB
    for (int c0 = 0; c0 < LQ; c0 += 256) {
        __syncthreads();
        for (int u = threadIdx.x; u < 256 * 48; u += 512) sd[u] = xd[(size_t)c0 * 48 + u];
        __syncthreads();
        for (int tl = 0; tl < 256; tl++) {
            const float* s = sd + tl * 48;
            float draw = dtb;
#pragma unroll
            for (int r = 0; r < 16; r++) draw = fmaf(s[r], dtw[r], draw);
            float dt = softplusf(draw);
            float xt = xp[(size_t)(c0 + tl) * DIQ];
            float dtx = dt * xt;
            float y = 0.f;
#pragma unroll
            for (int n = 0; n < 16; n++) {
                float e = __expf(dt * Ad[n]);
                h[n] = fmaf(h[n], e, dtx * s[16 + n]);
                y = fmaf(h[n], s[32 + n], y);
            }
            xp[(size_t)(c0 + tl) * DIQ] = fmaf(xt, Dd, y);
        }
    }
}

// ---------------- y *= silu(z) ----------------
__global__ void k_gate(float* __restrict__ y, const float* __restrict__ z) {
    size_t idx = (size_t)blockIdx.x * 256 + threadIdx.x;
    float zv = z[idx];
    y[idx] *= zv * sigf(zv);
}

// ---------------- fused weight: Wf[m,d] = sum_c opw_half[m,c]*mow[c,d] ----------------
__global__ void k_wfuse(const float* __restrict__ opw_h, const float* __restrict__ mow_i,
                        float* __restrict__ wf) {
    int idx = blockIdx.x * 256 + threadIdx.x;  // 0..131071
    int m = idx >> 9, d = idx & 511;
    const float* a = opw_h + (size_t)m * 512;
    const float* bm = mow_i + d;
    float s = 0.f;
    for (int c = 0; c < 256; c++) s = fmaf(a[c], bm[(size_t)c * 512], s);
    wf[idx] = s;
}

// ---------------- mean/max over L ----------------
__global__ void k_redu(const float* __restrict__ o, float* __restrict__ avg,
                       float* __restrict__ mx) {
    int idx = blockIdx.x * 256 + threadIdx.x;  // 0..6143
    int b = idx / DMQ, ch = idx % DMQ;
    const float* p = o + (size_t)b * LQ * DMQ + ch;
    float s = 0.f, m = -3.4e38f;
    for (int t = 0; t < LQ; t++) {
        float v = p[(size_t)t * DMQ];
        s += v;
        m = fmaxf(m, v);
    }
    avg[idx] = s * (1.f / LQ);
    mx[idx] = m;
}

__global__ void k_att1(const float* __restrict__ avg, const float* __restrict__ mx,
                       const float* __restrict__ w1, float* __restrict__ hs) {
    int idx = blockIdx.x * 256 + threadIdx.x;  // 0..3071
    int b = idx / 384, j = idx % 384;
    const float* w = w1 + (size_t)j * DMQ;
    const float* a = avg + (size_t)b * DMQ;
    const float* m2 = mx + (size_t)b * DMQ;
    float s1 = 0.f, s2 = 0.f;
    for (int k = 0; k < DMQ; k++) {
        s1 = fmaf(a[k], w[k], s1);
        s2 = fmaf(m2[k], w[k], s2);
    }
    hs[idx] = fmaxf(s1, 0.f) + fmaxf(s2, 0.f);
}

__global__ void k_att2(const float* __restrict__ hs, const float* __restrict__ w2,
                       float* __restrict__ att) {
    int idx = blockIdx.x * 256 + threadIdx.x;  // 0..6143
    int b = idx / DMQ, n = idx % DMQ;
    const float* w = w2 + (size_t)n * 384;
    const float* h = hs + (size_t)b * 384;
    float s = 0.f;
    for (int k = 0; k < 384; k++) s = fmaf(h[k], w[k], s);
    att[idx] = sigf(s);
}

__global__ void k_scale(float* __restrict__ o, const float* __restrict__ att) {
    size_t idx = (size_t)blockIdx.x * 256 + threadIdx.x;
    int ch = (int)(idx % DMQ);
    int b = (int)(idx / ((size_t)LQ * DMQ));
    o[idx] *= att[b * DMQ + ch];
}

__global__ void k_diag(float* __restrict__ o, float v) {
    if (blockIdx.x == 0 && threadIdx.x == 0) o[0] = v;
}

extern "C" void kernel_launch(void* const* d_in, const int* in_sizes, int n_in, void* d_out,
                              int out_size, void* d_ws, size_t ws_size, hipStream_t stream) {
    (void)in_sizes; (void)n_in; (void)out_size;
    const float* hid = (const float*)d_in[0];
    const int* mask = (const int*)d_in[1];
    const float* pool_w = (const float*)d_in[2];
    const float* pool_b = (const float*)d_in[3];
    const float* bn_g = (const float*)d_in[4];
    const float* bn_b = (const float*)d_in[5];
    const float* bn_rm = (const float*)d_in[6];
    const float* bn_rv = (const float*)d_in[7];
    const float* ipw = (const float*)d_in[8];
    const float* cw = (const float*)d_in[9];
    const float* cb = (const float*)d_in[10];
    const float* xpw = (const float*)d_in[11];
    const float* dtw = (const float*)d_in[12];
    const float* dtb = (const float*)d_in[13];
    const float* alog = (const float*)d_in[14];
    const float* Dpp = (const float*)d_in[15];
    const float* mow = (const float*)d_in[16];
    const float* opw = (const float*)d_in[17];
    const float* opb = (const float*)d_in[18];
    const float* caw1 = (const float*)d_in[19];
    const float* caw2 = (const float*)d_in[20];
    const float* fusw = (const float*)d_in[21];
    const float* fusb = (const float*)d_in[22];
    float* out = (float*)d_out;

    const size_t F_SMALL = 32768;
    const size_t F_WT = 131072;    // 256x512 fused weight
    const size_t F_XDBL = 393216;  // per inst: 8*1024*48
    const size_t F_INST = 4194304; // per inst: 8*1024*512
    const size_t F_CSC = 2097152;  // per scale: 8*1024*256

    auto needB = [&](int g, int ckeep) -> size_t {
        size_t f = F_SMALL + F_WT + (size_t)g * F_XDBL + (size_t)g * F_INST + F_INST +
                   (ckeep ? 3 * F_CSC : F_CSC);
        return f * 4;
    };
    int g = 0, ckeep = 0;
    if (ws_size >= needB(6, 1)) { g = 6; ckeep = 1; }
    else if (ws_size >= needB(3, 1)) { g = 3; ckeep = 1; }
    else if (ws_size >= needB(1, 1)) { g = 1; ckeep = 1; }
    else if (ws_size >= needB(1, 0)) { g = 1; ckeep = 0; }
    else {
        k_diag<<<1, 64, 0, stream>>>(out, (float)(ws_size >> 20));
        return;
    }

    float* ws = (float*)d_ws;
    int* lengths = (int*)ws;
    float* avg = ws + 1024;
    float* mxp = avg + 6144;
    float* hs = mxp + 6144;
    float* att = hs + 3072;
    float* wtmp = ws + F_SMALL;
    float* xdbl = wtmp + F_WT;
    float* cbase = xdbl + (size_t)g * F_XDBL;
    float* scanX = cbase + (ckeep ? 3 * F_CSC : F_CSC);
    float* xzx = scanX + (size_t)g * F_INST;
    float* fusout = scanX;  // overlay: scanX region (>=16MB) is dead by the fus GEMM

    k_lengths<<<dim3(8), dim3(256), 0, stream>>>(mask, lengths);
    if (ckeep)
        for (int i = 0; i < 3; i++)
            k_pool<<<dim3(8192), dim3(256), 0, stream>>>(hid, pool_w, pool_b, bn_g, bn_b, bn_rm,
                                                         bn_rv, i, cbase + (size_t)i * F_CSC);

    for (int base = 0; base < 6; base += g) {
        // phase 1: x-half in_proj -> dwconv -> xdbl
        for (int s = 0; s < g; s++) {
            int inst = base + s, i = inst >> 1, dir = inst & 1;
            float* ci = ckeep ? cbase + (size_t)i * F_CSC : cbase;
            if (!ckeep)
                k_pool<<<dim3(8192), dim3(256), 0, stream>>>(hid, pool_w, pool_b, bn_g, bn_b,
                                                             bn_rm, bn_rv, i, ci);
            const float* W = ipw + (size_t)inst * 1024 * DSQ;
            float* sx = scanX + (size_t)s * F_INST;
            if (dir == 0)
                gemm_mfma<0, 0, 0, 0><<<dim3(4, 64), 256, 0, stream>>>(ci, W, xzx, nullptr, 512,
                                                                       256, 256, 512, lengths);
            else
                gemm_mfma<1, 0, 0, 0><<<dim3(4, 64), 256, 0, stream>>>(ci, W, xzx, nullptr, 512,
                                                                       256, 256, 512, lengths);
            k_dwconv<<<dim3(8192), dim3(512), 0, stream>>>(xzx, cw + (size_t)inst * DIQ * 4,
                                                           cb + (size_t)inst * DIQ, sx);
            gemm_mfma<0, 0, 0, 0><<<dim3(1, 64), 256, 0, stream>>>(
                sx, xpw + (size_t)inst * 48 * DIQ, xdbl + (size_t)s * F_XDBL, nullptr, 48, 512,
                512, 48, lengths);
        }
        // phase 2: selective scan (in place)
        k_scan<<<dim3(g * 8), dim3(512), 0, stream>>>(scanX, xdbl, dtw, dtb, alog, Dpp, base);
        // phase 3: z-half in_proj -> gate -> fused mo+op accumulate into d_out
        for (int s = 0; s < g; s++) {
            int inst = base + s, i = inst >> 1, dir = inst & 1;
            float* ci = ckeep ? cbase + (size_t)i * F_CSC : cbase;
            if (!ckeep)
                k_pool<<<dim3(8192), dim3(256), 0, stream>>>(hid, pool_w, pool_b, bn_g, bn_b,
                                                             bn_rm, bn_rv, i, ci);
            const float* Wz = ipw + (size_t)inst * 1024 * DSQ + 512 * 256;
            if (dir == 0)
                gemm_mfma<0, 0, 0, 0><<<dim3(4, 64), 256, 0, stream>>>(ci, Wz, xzx, nullptr, 512,
                                                                       256, 256, 512, lengths);
            else
                gemm_mfma<1, 0, 0, 0><<<dim3(4, 64), 256, 0, stream>>>(ci, Wz, xzx, nullptr, 512,
                                                                       256, 256, 512, lengths);
            float* sx = scanX + (size_t)s * F_INST;
            k_gate<<<dim3(16384), dim3(256), 0, stream>>>(sx, xzx);
            k_wfuse<<<dim3(512), dim3(256), 0, stream>>>(opw + (size_t)i * 131072 + dir * 256,
                                                         mow + (size_t)inst * 131072, wtmp);
            if (dir == 0)
                gemm_mfma<0, 0, 0, 0><<<dim3(2, 64), 256, 0, stream>>>(
                    sx, wtmp, out + i * 256, nullptr, 256, 512, 512, DMQ, lengths);
            else
                gemm_mfma<0, 1, 1, 1><<<dim3(2, 64), 256, 0, stream>>>(
                    sx, wtmp, out + i * 256, opb + (size_t)i * 256, 256, 512, 512, DMQ, lengths);
        }
    }

    // attention pooling + final projection
    k_redu<<<dim3(24), dim3(256), 0, stream>>>(out, avg, mxp);
    k_att1<<<dim3(12), dim3(256), 0, stream>>>(avg, mxp, caw1, hs);
    k_att2<<<dim3(24), dim3(256), 0, stream>>>(hs, caw2, att);
    k_scale<<<dim3(24576), dim3(256), 0, stream>>>(out, att);
    gemm_mfma<0, 0, 1, 0><<<dim3(6, 64), 256, 0, stream>>>(out, fusw, fusout, fusb, DMQ, DMQ,
                                                           DMQ, DMQ, lengths);
    hipMemcpyAsync(d_out, fusout, (size_t)DMQ * LQ * 8 * 4, hipMemcpyDeviceToDevice, stream);
}

// Round 4
// 1361.828 us; speedup vs baseline: 2.1778x; 1.4618x over previous
//
#include <hip/hip_runtime.h>
#include <cstddef>
#include <cstdint>

#define LQ 1024
#define DMQ 768
#define DSQ 256
#define DIQ 512
#define CCH 8            // scan chunks per sequence
#define CT (LQ / CCH)    // 128 timesteps per chunk

using f32x4 = __attribute__((ext_vector_type(4))) float;
using bf16x8 = __attribute__((ext_vector_type(8))) short;
using s16x4 = __attribute__((ext_vector_type(4))) short;

__device__ __forceinline__ float sigf(float x) { return 1.f / (1.f + __expf(-x)); }
__device__ __forceinline__ float softplusf(float x) {
    return fmaxf(x, 0.f) + log1pf(__expf(-fabsf(x)));
}
__device__ __forceinline__ short f2bf(float f) {
    unsigned u = __float_as_uint(f);
    u += 0x7FFFu + ((u >> 16) & 1u);
    return (short)(u >> 16);
}

// ---------------- lengths from mask ----------------
__global__ void k_lengths(const int* __restrict__ mask, int* __restrict__ lengths) {
    int b = blockIdx.x;
    int s = 0;
    for (int t = threadIdx.x; t < LQ; t += 256) s += mask[b * LQ + t];
    __shared__ int sm[256];
    sm[threadIdx.x] = s;
    __syncthreads();
    for (int o = 128; o > 0; o >>= 1) {
        if (threadIdx.x < o) sm[threadIdx.x] += sm[threadIdx.x + o];
        __syncthreads();
    }
    if (threadIdx.x == 0) lengths[b] = sm[0];
}

// ---------------- dilated dw conv + BN + GELU -> c (one scale) ----------------
__global__ void k_pool(const float* __restrict__ hid, const float* __restrict__ pw,
                       const float* __restrict__ pb, const float* __restrict__ bg,
                       const float* __restrict__ bb, const float* __restrict__ brm,
                       const float* __restrict__ brv, int isc, float* __restrict__ cdst) {
    int idx = blockIdx.x;
    int l = idx & (LQ - 1);
    int b = idx >> 10;
    int ch = threadIdx.x;
    int dil = 1 << isc;
    int wci = isc * DSQ + ch;
    const float* xb = hid + (size_t)b * LQ * DMQ + isc * DSQ + ch;
    float w0 = pw[wci * 3 + 0], w1 = pw[wci * 3 + 1], w2 = pw[wci * 3 + 2];
    float acc = pb[wci];
    int lm = l - dil, lp = l + dil;
    if (lm >= 0) acc += xb[(size_t)lm * DMQ] * w0;
    acc += xb[(size_t)l * DMQ] * w1;
    if (lp < LQ) acc += xb[(size_t)lp * DMQ] * w2;
    float xn = (acc - brm[wci]) * rsqrtf(brv[wci] + 1e-5f) * bg[wci] + bb[wci];
    float y = 0.5f * xn * (1.0f + erff(xn * 0.70710678118654752f));
    cdst[(size_t)idx * DSQ + ch] = y;
}

// ---------------- bf16 MFMA GEMM: C[m,n] (+)= sum_k A[m,k]*Bw[n,k] ----------------
template <int FLIPA, int FLIPC, int BIAS, int ACC>
__global__ __launch_bounds__(256) void gemm_mfma(const float* __restrict__ A,
                                                 const float* __restrict__ Bw,
                                                 float* __restrict__ C,
                                                 const float* __restrict__ bias, int N, int Kd,
                                                 int lda, int ldc,
                                                 const int* __restrict__ lengths) {
    __shared__ short Als[128][72];
    __shared__ short Bls[128][72];
    const int tid = threadIdx.x;
    const int lane = tid & 63;
    const int wave = tid >> 6;
    const int wr = wave >> 1, wc = wave & 1;
    const int row0 = blockIdx.y * 128, col0 = blockIdx.x * 128;
    int len = 0;
    if (FLIPA || FLIPC) len = lengths[row0 >> 10];

    const int sr = tid >> 4;
    const int sc4 = (tid & 15) * 4;

    f32x4 acc[4][4];
#pragma unroll
    for (int i = 0; i < 4; i++)
#pragma unroll
        for (int j = 0; j < 4; j++) acc[i][j] = (f32x4){0.f, 0.f, 0.f, 0.f};

    for (int k0 = 0; k0 < Kd; k0 += 64) {
        __syncthreads();
#pragma unroll
        for (int p = 0; p < 8; p++) {
            int row = p * 16 + sr;
            int grow = row0 + row;
            if (FLIPA) {
                int t = grow & (LQ - 1);
                int ts = (t < len) ? (len - 1 - t) : t;
                grow = (grow & ~(LQ - 1)) | ts;
            }
            float4 v = *(const float4*)(A + (size_t)grow * lda + k0 + sc4);
            s16x4 w = {f2bf(v.x), f2bf(v.y), f2bf(v.z), f2bf(v.w)};
            *(s16x4*)&Als[row][sc4] = w;
        }
#pragma unroll
        for (int p = 0; p < 8; p++) {
            int row = p * 16 + sr;
            int bn = col0 + row;
            float4 v = make_float4(0.f, 0.f, 0.f, 0.f);
            if (bn < N) v = *(const float4*)(Bw + (size_t)bn * Kd + k0 + sc4);
            s16x4 w = {f2bf(v.x), f2bf(v.y), f2bf(v.z), f2bf(v.w)};
            *(s16x4*)&Bls[row][sc4] = w;
        }
        __syncthreads();
#pragma unroll
        for (int ks = 0; ks < 2; ks++) {
            bf16x8 am[4], bv[4];
#pragma unroll
            for (int f = 0; f < 4; f++) {
                am[f] = *(const bf16x8*)&Als[wr * 64 + f * 16 + (lane & 15)]
                                            [ks * 32 + (lane >> 4) * 8];
                bv[f] = *(const bf16x8*)&Bls[wc * 64 + f * 16 + (lane & 15)]
                                            [ks * 32 + (lane >> 4) * 8];
            }
#pragma unroll
            for (int fm = 0; fm < 4; fm++)
#pragma unroll
                for (int fn = 0; fn < 4; fn++)
                    acc[fm][fn] = __builtin_amdgcn_mfma_f32_16x16x32_bf16(am[fm], bv[fn],
                                                                          acc[fm][fn], 0, 0, 0);
        }
    }
#pragma unroll
    for (int fm = 0; fm < 4; fm++) {
#pragma unroll
        for (int r = 0; r < 4; r++) {
            int grow = row0 + wr * 64 + fm * 16 + (lane >> 4) * 4 + r;
            if (FLIPC) {
                int t = grow & (LQ - 1);
                int ts = (t < len) ? (len - 1 - t) : t;
                grow = (grow & ~(LQ - 1)) | ts;
            }
            float* cp = C + (size_t)grow * ldc;
#pragma unroll
            for (int fn = 0; fn < 4; fn++) {
                int col = col0 + wc * 64 + fn * 16 + (lane & 15);
                if (col < N) {
                    float v = acc[fm][fn][r];
                    if (ACC) v += cp[col];
                    if (BIAS) v += bias[col];
                    cp[col] = v;
                }
            }
        }
    }
}

// ---------------- causal depthwise conv (K=4) + SiLU ----------------
__global__ void k_dwconv(const float* __restrict__ xin, const float* __restrict__ w4,
                         const float* __restrict__ b1, float* __restrict__ xout) {
    int bt = blockIdx.x;
    int t = bt & (LQ - 1);
    int ch = threadIdx.x;
    const float* w = w4 + ch * 4;
    float acc = b1[ch];
    const float* xp = xin + (size_t)bt * DIQ + ch;
#pragma unroll
    for (int k = 0; k < 4; k++) {
        int ts = t - 3 + k;
        if (ts >= 0) acc += xp[(ptrdiff_t)(ts - t) * DIQ] * w[k];
    }
    xout[(size_t)bt * DIQ + ch] = acc * sigf(acc);
}

// ======== chunked selective scan ========
// pass 1: per-chunk local scan (h_in = 0). y_local overwrites x in place.
// grid: seqs*CCH*2 blocks of 256 (channel half). Saves h_end + dtsum per chunk.
__global__ __launch_bounds__(256) void k_scan1(float* __restrict__ scanX,
                                               const float* __restrict__ xdbl,
                                               const float* __restrict__ dt_w,
                                               const float* __restrict__ dt_b,
                                               const float* __restrict__ A_log,
                                               const float* __restrict__ Dpp, int instBase,
                                               float* __restrict__ hbuf,
                                               float* __restrict__ sbuf) {
    int bid = blockIdx.x;
    int seq = bid >> 4;            // /(CCH*2)
    int r = bid & 15;
    int c = r >> 1, half = r & 1;
    int inst = instBase + (seq >> 3);
    int ch = half * 256 + threadIdx.x;

    const float* xd = xdbl + ((size_t)seq * LQ + c * CT) * 48;
    float* xp = scanX + ((size_t)seq * LQ + c * CT) * DIQ + ch;
    int wo = inst * DIQ + ch;
    float dtw[16], Ad[16];
#pragma unroll
    for (int rr = 0; rr < 16; rr++) dtw[rr] = dt_w[(size_t)wo * 16 + rr];
    float dtb = dt_b[wo];
#pragma unroll
    for (int n = 0; n < 16; n++) Ad[n] = -__expf(A_log[(size_t)wo * 16 + n]);
    float Dd = Dpp[wo];
    float h[16];
#pragma unroll
    for (int n = 0; n < 16; n++) h[n] = 0.f;
    float S = 0.f;

    __shared__ float sd[CT * 48];  // 24KB
    for (int u = threadIdx.x; u < CT * 48; u += 256) sd[u] = xd[u];
    __syncthreads();

    float xt = xp[0];
    for (int tl = 0; tl < CT; tl++) {
        float xnext = (tl + 1 < CT) ? xp[(size_t)(tl + 1) * DIQ] : 0.f;
        const float* s = sd + tl * 48;
        float draw = dtb;
#pragma unroll
        for (int rr = 0; rr < 16; rr++) draw = fmaf(s[rr], dtw[rr], draw);
        float dt = softplusf(draw);
        S += dt;
        float dtx = dt * xt;
        float y = 0.f;
#pragma unroll
        for (int n = 0; n < 16; n++) {
            float e = __expf(dt * Ad[n]);
            h[n] = fmaf(h[n], e, dtx * s[16 + n]);
            y = fmaf(h[n], s[32 + n], y);
        }
        xp[(size_t)tl * DIQ] = fmaf(xt, Dd, y);
        xt = xnext;
    }
    // save chunk state: hbuf[((seq*CCH+c)*16+n)*DIQ+ch], sbuf[(seq*CCH+c)*DIQ+ch]
    size_t hb = ((size_t)(seq * CCH + c) * 16) * DIQ + ch;
#pragma unroll
    for (int n = 0; n < 16; n++) hbuf[hb + (size_t)n * DIQ] = h[n];
    sbuf[(size_t)(seq * CCH + c) * DIQ + ch] = S;
}

// pass 2: combine chunk states sequentially; overwrite hbuf[c] with h_in of chunk c.
// grid: seqs blocks of 512.
__global__ __launch_bounds__(512) void k_scan2(const float* __restrict__ A_log, int instBase,
                                               float* __restrict__ hbuf,
                                               const float* __restrict__ sbuf) {
    int seq = blockIdx.x;
    int inst = instBase + (seq >> 3);
    int ch = threadIdx.x;
    int wo = inst * DIQ + ch;
    float Ad[16];
#pragma unroll
    for (int n = 0; n < 16; n++) Ad[n] = -__expf(A_log[(size_t)wo * 16 + n]);
    float hin[16];
#pragma unroll
    for (int n = 0; n < 16; n++) hin[n] = 0.f;
    for (int c = 0; c < CCH; c++) {
        size_t hb = ((size_t)(seq * CCH + c) * 16) * DIQ + ch;
        float Sc = sbuf[(size_t)(seq * CCH + c) * DIQ + ch];
        float he[16];
#pragma unroll
        for (int n = 0; n < 16; n++) he[n] = hbuf[hb + (size_t)n * DIQ];
#pragma unroll
        for (int n = 0; n < 16; n++) hbuf[hb + (size_t)n * DIQ] = hin[n];
#pragma unroll
        for (int n = 0; n < 16; n++) hin[n] = fmaf(hin[n], __expf(Ad[n] * Sc), he[n]);
    }
}

// pass 3: add carried-state correction y[t] += C[t]·(exp(Ad*S[t])⊙h_in), chunks 1..CCH-1.
// grid: seqs*(CCH-1)*2 blocks of 256.
__global__ __launch_bounds__(256) void k_scan3(float* __restrict__ scanX,
                                               const float* __restrict__ xdbl,
                                               const float* __restrict__ dt_w,
                                               const float* __restrict__ dt_b,
                                               const float* __restrict__ A_log, int instBase,
                                               const float* __restrict__ hbuf) {
    int bid = blockIdx.x;
    int seq = bid / (2 * (CCH - 1));
    int r = bid % (2 * (CCH - 1));
    int c = 1 + (r >> 1), half = r & 1;
    int inst = instBase + (seq >> 3);
    int ch = half * 256 + threadIdx.x;

    const float* xd = xdbl + ((size_t)seq * LQ + c * CT) * 48;
    float* xp = scanX + ((size_t)seq * LQ + c * CT) * DIQ + ch;
    int wo = inst * DIQ + ch;
    float dtw[16], Ad[16];
#pragma unroll
    for (int rr = 0; rr < 16; rr++) dtw[rr] = dt_w[(size_t)wo * 16 + rr];
    float dtb = dt_b[wo];
    float amax = -1e30f;
#pragma unroll
    for (int n = 0; n < 16; n++) {
        Ad[n] = -__expf(A_log[(size_t)wo * 16 + n]);
        amax = fmaxf(amax, Ad[n]);
    }
    float hin[16];
    size_t hb = ((size_t)(seq * CCH + c) * 16) * DIQ + ch;
#pragma unroll
    for (int n = 0; n < 16; n++) hin[n] = hbuf[hb + (size_t)n * DIQ];

    __shared__ float sd[CT * 48];
    for (int u = threadIdx.x; u < CT * 48; u += 256) sd[u] = xd[u];
    __syncthreads();

    float S = 0.f;
    for (int tl = 0; tl < CT; tl++) {
        const float* s = sd + tl * 48;
        float draw = dtb;
#pragma unroll
        for (int rr = 0; rr < 16; rr++) draw = fmaf(s[rr], dtw[rr], draw);
        S += softplusf(draw);
        if (__all(amax * S < -30.f)) break;  // decayed to nothing wave-wide
        float corr = 0.f;
#pragma unroll
        for (int n = 0; n < 16; n++) corr = fmaf(__expf(Ad[n] * S) * hin[n], s[32 + n], corr);
        xp[(size_t)tl * DIQ] += corr;
    }
}

// ---------------- y *= silu(z) ----------------
__global__ void k_gate(float* __restrict__ y, const float* __restrict__ z) {
    size_t idx = (size_t)blockIdx.x * 256 + threadIdx.x;
    float zv = z[idx];
    y[idx] *= zv * sigf(zv);
}

// ---------------- fused weight: Wf[m,d] = sum_c opw_half[m,c]*mow[c,d] ----------------
__global__ void k_wfuse(const float* __restrict__ opw_h, const float* __restrict__ mow_i,
                        float* __restrict__ wf) {
    int idx = blockIdx.x * 256 + threadIdx.x;
    int m = idx >> 9, d = idx & 511;
    const float* a = opw_h + (size_t)m * 512;
    const float* bm = mow_i + d;
    float s = 0.f;
    for (int c = 0; c < 256; c++) s = fmaf(a[c], bm[(size_t)c * 512], s);
    wf[idx] = s;
}

// ---------------- mean/max over L ----------------
__global__ void k_redu(const float* __restrict__ o, float* __restrict__ avg,
                       float* __restrict__ mx) {
    int idx = blockIdx.x * 256 + threadIdx.x;
    int b = idx / DMQ, ch = idx % DMQ;
    const float* p = o + (size_t)b * LQ * DMQ + ch;
    float s = 0.f, m = -3.4e38f;
    for (int t = 0; t < LQ; t++) {
        float v = p[(size_t)t * DMQ];
        s += v;
        m = fmaxf(m, v);
    }
    avg[idx] = s * (1.f / LQ);
    mx[idx] = m;
}

__global__ void k_att1(const float* __restrict__ avg, const float* __restrict__ mx,
                       const float* __restrict__ w1, float* __restrict__ hs) {
    int idx = blockIdx.x * 256 + threadIdx.x;
    int b = idx / 384, j = idx % 384;
    const float* w = w1 + (size_t)j * DMQ;
    const float* a = avg + (size_t)b * DMQ;
    const float* m2 = mx + (size_t)b * DMQ;
    float s1 = 0.f, s2 = 0.f;
    for (int k = 0; k < DMQ; k++) {
        s1 = fmaf(a[k], w[k], s1);
        s2 = fmaf(m2[k], w[k], s2);
    }
    hs[idx] = fmaxf(s1, 0.f) + fmaxf(s2, 0.f);
}

__global__ void k_att2(const float* __restrict__ hs, const float* __restrict__ w2,
                       float* __restrict__ att) {
    int idx = blockIdx.x * 256 + threadIdx.x;
    int b = idx / DMQ, n = idx % DMQ;
    const float* w = w2 + (size_t)n * 384;
    const float* h = hs + (size_t)b * 384;
    float s = 0.f;
    for (int k = 0; k < 384; k++) s = fmaf(h[k], w[k], s);
    att[idx] = sigf(s);
}

__global__ void k_scale(float* __restrict__ o, const float* __restrict__ att) {
    size_t idx = (size_t)blockIdx.x * 256 + threadIdx.x;
    int ch = (int)(idx % DMQ);
    int b = (int)(idx / ((size_t)LQ * DMQ));
    o[idx] *= att[b * DMQ + ch];
}

__global__ void k_diag(float* __restrict__ o, float v) {
    if (blockIdx.x == 0 && threadIdx.x == 0) o[0] = v;
}

extern "C" void kernel_launch(void* const* d_in, const int* in_sizes, int n_in, void* d_out,
                              int out_size, void* d_ws, size_t ws_size, hipStream_t stream) {
    (void)in_sizes; (void)n_in; (void)out_size;
    const float* hid = (const float*)d_in[0];
    const int* mask = (const int*)d_in[1];
    const float* pool_w = (const float*)d_in[2];
    const float* pool_b = (const float*)d_in[3];
    const float* bn_g = (const float*)d_in[4];
    const float* bn_b = (const float*)d_in[5];
    const float* bn_rm = (const float*)d_in[6];
    const float* bn_rv = (const float*)d_in[7];
    const float* ipw = (const float*)d_in[8];
    const float* cw = (const float*)d_in[9];
    const float* cb = (const float*)d_in[10];
    const float* xpw = (const float*)d_in[11];
    const float* dtw = (const float*)d_in[12];
    const float* dtb = (const float*)d_in[13];
    const float* alog = (const float*)d_in[14];
    const float* Dpp = (const float*)d_in[15];
    const float* mow = (const float*)d_in[16];
    const float* opw = (const float*)d_in[17];
    const float* opb = (const float*)d_in[18];
    const float* caw1 = (const float*)d_in[19];
    const float* caw2 = (const float*)d_in[20];
    const float* fusw = (const float*)d_in[21];
    const float* fusb = (const float*)d_in[22];
    float* out = (float*)d_out;

    const size_t F_SMALL = 32768;
    const size_t F_WT = 131072;
    const size_t F_XDBL = 393216;
    const size_t F_INST = 4194304;
    const size_t F_CSC = 2097152;

    auto needB = [&](int g, int ckeep) -> size_t {
        size_t f = F_SMALL + F_WT + (size_t)g * F_XDBL + (size_t)g * F_INST + F_INST +
                   (ckeep ? 3 * F_CSC : F_CSC);
        return f * 4;
    };
    int g = 0, ckeep = 0;
    if (ws_size >= needB(6, 1)) { g = 6; ckeep = 1; }
    else if (ws_size >= needB(3, 1)) { g = 3; ckeep = 1; }
    else if (ws_size >= needB(1, 1)) { g = 1; ckeep = 1; }
    else if (ws_size >= needB(1, 0)) { g = 1; ckeep = 0; }
    else {
        k_diag<<<1, 64, 0, stream>>>(out, (float)(ws_size >> 20));
        return;
    }

    float* ws = (float*)d_ws;
    int* lengths = (int*)ws;
    float* avg = ws + 1024;
    float* mxp = avg + 6144;
    float* hs = mxp + 6144;
    float* att = hs + 3072;
    float* wtmp = ws + F_SMALL;
    float* xdbl = wtmp + F_WT;
    float* cbase = xdbl + (size_t)g * F_XDBL;
    float* scanX = cbase + (ckeep ? 3 * F_CSC : F_CSC);
    float* xzx = scanX + (size_t)g * F_INST;
    float* fusout = scanX;  // overlay: scanX region is dead by the fus GEMM
    // scan state overlays xzx (dead between dwconv and phase 3):
    // hbuf = g*8*CCH*16*512 floats (<=12.6MB), sbuf = g*8*CCH*512 floats
    float* hbuf = xzx;
    float* sbuf = xzx + (size_t)g * 8 * CCH * 16 * DIQ;

    k_lengths<<<dim3(8), dim3(256), 0, stream>>>(mask, lengths);
    if (ckeep)
        for (int i = 0; i < 3; i++)
            k_pool<<<dim3(8192), dim3(256), 0, stream>>>(hid, pool_w, pool_b, bn_g, bn_b, bn_rm,
                                                         bn_rv, i, cbase + (size_t)i * F_CSC);

    for (int base = 0; base < 6; base += g) {
        // phase 1: x-half in_proj -> dwconv -> xdbl
        for (int s = 0; s < g; s++) {
            int inst = base + s, i = inst >> 1, dir = inst & 1;
            float* ci = ckeep ? cbase + (size_t)i * F_CSC : cbase;
            if (!ckeep)
                k_pool<<<dim3(8192), dim3(256), 0, stream>>>(hid, pool_w, pool_b, bn_g, bn_b,
                                                             bn_rm, bn_rv, i, ci);
            const float* W = ipw + (size_t)inst * 1024 * DSQ;
            float* sx = scanX + (size_t)s * F_INST;
            if (dir == 0)
                gemm_mfma<0, 0, 0, 0><<<dim3(4, 64), 256, 0, stream>>>(ci, W, xzx, nullptr, 512,
                                                                       256, 256, 512, lengths);
            else
                gemm_mfma<1, 0, 0, 0><<<dim3(4, 64), 256, 0, stream>>>(ci, W, xzx, nullptr, 512,
                                                                       256, 256, 512, lengths);
            k_dwconv<<<dim3(8192), dim3(512), 0, stream>>>(xzx, cw + (size_t)inst * DIQ * 4,
                                                           cb + (size_t)inst * DIQ, sx);
            gemm_mfma<0, 0, 0, 0><<<dim3(1, 64), 256, 0, stream>>>(
                sx, xpw + (size_t)inst * 48 * DIQ, xdbl + (size_t)s * F_XDBL, nullptr, 48, 512,
                512, 48, lengths);
        }
        // phase 2: chunked selective scan (in place on scanX)
        k_scan1<<<dim3(g * 8 * CCH * 2), dim3(256), 0, stream>>>(scanX, xdbl, dtw, dtb, alog,
                                                                 Dpp, base, hbuf, sbuf);
        k_scan2<<<dim3(g * 8), dim3(512), 0, stream>>>(alog, base, hbuf, sbuf);
        k_scan3<<<dim3(g * 8 * (CCH - 1) * 2), dim3(256), 0, stream>>>(scanX, xdbl, dtw, dtb,
                                                                       alog, base, hbuf);
        // phase 3: z-half in_proj -> gate -> fused mo+op accumulate into d_out
        for (int s = 0; s < g; s++) {
            int inst = base + s, i = inst >> 1, dir = inst & 1;
            float* ci = ckeep ? cbase + (size_t)i * F_CSC : cbase;
            if (!ckeep)
                k_pool<<<dim3(8192), dim3(256), 0, stream>>>(hid, pool_w, pool_b, bn_g, bn_b,
                                                             bn_rm, bn_rv, i, ci);
            const float* Wz = ipw + (size_t)inst * 1024 * DSQ + 512 * 256;
            if (dir == 0)
                gemm_mfma<0, 0, 0, 0><<<dim3(4, 64), 256, 0, stream>>>(ci, Wz, xzx, nullptr, 512,
                                                                       256, 256, 512, lengths);
            else
                gemm_mfma<1, 0, 0, 0><<<dim3(4, 64), 256, 0, stream>>>(ci, Wz, xzx, nullptr, 512,
                                                                       256, 256, 512, lengths);
            float* sx = scanX + (size_t)s * F_INST;
            k_gate<<<dim3(16384), dim3(256), 0, stream>>>(sx, xzx);
            k_wfuse<<<dim3(512), dim3(256), 0, stream>>>(opw + (size_t)i * 131072 + dir * 256,
                                                         mow + (size_t)inst * 131072, wtmp);
            if (dir == 0)
                gemm_mfma<0, 0, 0, 0><<<dim3(2, 64), 256, 0, stream>>>(
                    sx, wtmp, out + i * 256, nullptr, 256, 512, 512, DMQ, lengths);
            else
                gemm_mfma<0, 1, 1, 1><<<dim3(2, 64), 256, 0, stream>>>(
                    sx, wtmp, out + i * 256, opb + (size_t)i * 256, 256, 512, 512, DMQ, lengths);
        }
    }

    // attention pooling + final projection
    k_redu<<<dim3(24), dim3(256), 0, stream>>>(out, avg, mxp);
    k_att1<<<dim3(12), dim3(256), 0, stream>>>(avg, mxp, caw1, hs);
    k_att2<<<dim3(24), dim3(256), 0, stream>>>(hs, caw2, att);
    k_scale<<<dim3(24576), dim3(256), 0, stream>>>(out, att);
    gemm_mfma<0, 0, 1, 0><<<dim3(6, 64), 256, 0, stream>>>(out, fusw, fusout, fusb, DMQ, DMQ,
                                                           DMQ, DMQ, lengths);
    hipMemcpyAsync(d_out, fusout, (size_t)DMQ * LQ * 8 * 4, hipMemcpyDeviceToDevice, stream);
}

// Round 5
// 1003.335 us; speedup vs baseline: 2.9560x; 1.3573x over previous
//
#include <hip/hip_runtime.h>
#include <cstddef>
#include <cstdint>

#define LQ 1024
#define DMQ 768
#define DSQ 256
#define DIQ 512
#define CCH 8
#define CT (LQ / CCH)

typedef unsigned short ushortT;
using f32x4 = __attribute__((ext_vector_type(4))) float;
using bf16x8 = __attribute__((ext_vector_type(8))) short;

__device__ __forceinline__ float sigf(float x) { return 1.f / (1.f + __expf(-x)); }
__device__ __forceinline__ float softplusf(float x) {
    return fmaxf(x, 0.f) + log1pf(__expf(-fabsf(x)));
}
__device__ __forceinline__ ushortT f2bf(float f) {
    unsigned u = __float_as_uint(f);
    u += 0x7FFFu + ((u >> 16) & 1u);
    return (ushortT)(u >> 16);
}
__device__ __forceinline__ void gload_lds16(const void* g, void* l) {
    __builtin_amdgcn_global_load_lds((const __attribute__((address_space(1))) void*)g,
                                     (__attribute__((address_space(3))) void*)l, 16, 0, 0);
}

// ---------------- lengths ----------------
__global__ void k_lengths(const int* __restrict__ mask, int* __restrict__ lengths) {
    int b = blockIdx.x;
    int s = 0;
    for (int t = threadIdx.x; t < LQ; t += 256) s += mask[b * LQ + t];
    __shared__ int sm[256];
    sm[threadIdx.x] = s;
    __syncthreads();
    for (int o = 128; o > 0; o >>= 1) {
        if (threadIdx.x < o) sm[threadIdx.x] += sm[threadIdx.x + o];
        __syncthreads();
    }
    if (threadIdx.x == 0) lengths[b] = sm[0];
}

// ---------------- fp32 -> bf16 converters ----------------
__global__ void k_cvt(const float* __restrict__ in, ushortT* __restrict__ out, int n) {
    int i = blockIdx.x * 256 + threadIdx.x;
    if (i < n) out[i] = f2bf(in[i]);
}
__global__ void k_cvtpad48(const float* __restrict__ xpw, ushortT* __restrict__ out) {
    int idx = blockIdx.x * 256 + threadIdx.x;  // 6*128*512
    int inst = idx >> 16, rem = idx & 65535;
    int row = rem >> 9, col = rem & 511;
    float v = (row < 48) ? xpw[((size_t)inst * 48 + row) * 512 + col] : 0.f;
    out[idx] = f2bf(v);
}

// ---------------- dilated dw conv + BN + GELU -> c bf16 ----------------
__global__ void k_pool(const float* __restrict__ hid, const float* __restrict__ pw,
                       const float* __restrict__ pb, const float* __restrict__ bg,
                       const float* __restrict__ bb, const float* __restrict__ brm,
                       const float* __restrict__ brv, int isc, ushortT* __restrict__ cdst) {
    int idx = blockIdx.x;
    int l = idx & (LQ - 1);
    int b = idx >> 10;
    int ch = threadIdx.x;
    int dil = 1 << isc;
    int wci = isc * DSQ + ch;
    const float* xb = hid + (size_t)b * LQ * DMQ + isc * DSQ + ch;
    float w0 = pw[wci * 3 + 0], w1 = pw[wci * 3 + 1], w2 = pw[wci * 3 + 2];
    float acc = pb[wci];
    int lm = l - dil, lp = l + dil;
    if (lm >= 0) acc += xb[(size_t)lm * DMQ] * w0;
    acc += xb[(size_t)l * DMQ] * w1;
    if (lp < LQ) acc += xb[(size_t)lp * DMQ] * w2;
    float xn = (acc - brm[wci]) * rsqrtf(brv[wci] + 1e-5f) * bg[wci] + bb[wci];
    float y = 0.5f * xn * (1.0f + erff(xn * 0.70710678118654752f));
    cdst[(size_t)idx * DSQ + ch] = f2bf(y);
}

// ---------------- bf16 GEMM (global_load_lds staging): C (+)= A*Bw^T ----------------
// A,Bw bf16; C fp32. 128x128 tile, 256 threads (4 waves), BK=64. M mult 128, K mult 64.
// Bw must have >= gridDim.x*128 valid rows (pad with zeros when N < that).
template <int FLIPA, int FLIPC, int BIAS, int ACC>
__global__ __launch_bounds__(256) void gemm_bf16(const ushortT* __restrict__ A,
                                                 const ushortT* __restrict__ Bw,
                                                 float* __restrict__ C,
                                                 const float* __restrict__ bias, int N, int Kd,
                                                 int lda, int ldc,
                                                 const int* __restrict__ lengths) {
    __shared__ ushortT Als[128 * 64];
    __shared__ ushortT Bls[128 * 64];
    const int tid = threadIdx.x;
    const int lane = tid & 63;
    const int wave = tid >> 6;
    const int wr = wave >> 1, wc = wave & 1;
    const int row0 = blockIdx.y * 128, col0 = blockIdx.x * 128;
    int len = 0;
    if (FLIPA || FLIPC) len = lengths[row0 >> 10];

    // staging geometry: short idx e = it*2048 + wave*512 + lane*8
    const int srow = wave * 8 + (lane >> 3);   // + it*32
    const int scol = (lane & 7) * 8;

    f32x4 acc[4][4];
#pragma unroll
    for (int i = 0; i < 4; i++)
#pragma unroll
        for (int j = 0; j < 4; j++) acc[i][j] = (f32x4){0.f, 0.f, 0.f, 0.f};

    for (int k0 = 0; k0 < Kd; k0 += 64) {
        __syncthreads();
#pragma unroll
        for (int it = 0; it < 4; it++) {
            int row = it * 32 + srow;
            int grow = row0 + row;
            if (FLIPA) {
                int t = grow & (LQ - 1);
                int ts = (t < len) ? (len - 1 - t) : t;
                grow = (grow & ~(LQ - 1)) | ts;
            }
            gload_lds16(A + (size_t)grow * lda + k0 + scol, &Als[it * 2048 + wave * 512]);
        }
#pragma unroll
        for (int it = 0; it < 4; it++) {
            int row = it * 32 + srow;
            gload_lds16(Bw + (size_t)(col0 + row) * Kd + k0 + scol,
                        &Bls[it * 2048 + wave * 512]);
        }
        __syncthreads();
#pragma unroll
        for (int ks = 0; ks < 2; ks++) {
            bf16x8 am[4], bv[4];
#pragma unroll
            for (int f = 0; f < 4; f++) {
                am[f] = *(const bf16x8*)&Als[(wr * 64 + f * 16 + (lane & 15)) * 64 + ks * 32 +
                                             (lane >> 4) * 8];
                bv[f] = *(const bf16x8*)&Bls[(wc * 64 + f * 16 + (lane & 15)) * 64 + ks * 32 +
                                             (lane >> 4) * 8];
            }
#pragma unroll
            for (int fm = 0; fm < 4; fm++)
#pragma unroll
                for (int fn = 0; fn < 4; fn++)
                    acc[fm][fn] = __builtin_amdgcn_mfma_f32_16x16x32_bf16(am[fm], bv[fn],
                                                                          acc[fm][fn], 0, 0, 0);
        }
    }
#pragma unroll
    for (int fm = 0; fm < 4; fm++) {
#pragma unroll
        for (int r = 0; r < 4; r++) {
            int grow = row0 + wr * 64 + fm * 16 + (lane >> 4) * 4 + r;
            if (FLIPC) {
                int t = grow & (LQ - 1);
                int ts = (t < len) ? (len - 1 - t) : t;
                grow = (grow & ~(LQ - 1)) | ts;
            }
            float* cp = C + (size_t)grow * ldc;
#pragma unroll
            for (int fn = 0; fn < 4; fn++) {
                int col = col0 + wc * 64 + fn * 16 + (lane & 15);
                if (col < N) {
                    float v = acc[fm][fn][r];
                    if (ACC) v += cp[col];
                    if (BIAS) v += bias[col];
                    cp[col] = v;
                }
            }
        }
    }
}

// ---------------- legacy reg-staged fp32-input MFMA GEMM (g==1 fus path) ----------------
template <int BIAS>
__global__ __launch_bounds__(256) void gemm_mfma(const float* __restrict__ A,
                                                 const float* __restrict__ Bw,
                                                 float* __restrict__ C,
                                                 const float* __restrict__ bias, int N, int Kd,
                                                 int lda, int ldc) {
    __shared__ short Als[128][72];
    __shared__ short Bls[128][72];
    const int tid = threadIdx.x;
    const int lane = tid & 63;
    const int wave = tid >> 6;
    const int wr = wave >> 1, wc = wave & 1;
    const int row0 = blockIdx.y * 128, col0 = blockIdx.x * 128;
    const int sr = tid >> 4;
    const int sc4 = (tid & 15) * 4;
    f32x4 acc[4][4];
#pragma unroll
    for (int i = 0; i < 4; i++)
#pragma unroll
        for (int j = 0; j < 4; j++) acc[i][j] = (f32x4){0.f, 0.f, 0.f, 0.f};
    for (int k0 = 0; k0 < Kd; k0 += 64) {
        __syncthreads();
#pragma unroll
        for (int p = 0; p < 8; p++) {
            int row = p * 16 + sr;
            float4 v = *(const float4*)(A + (size_t)(row0 + row) * lda + k0 + sc4);
            short4 w = {(short)f2bf(v.x), (short)f2bf(v.y), (short)f2bf(v.z), (short)f2bf(v.w)};
            *(short4*)&Als[row][sc4] = w;
            int bn = col0 + row;
            float4 u = make_float4(0.f, 0.f, 0.f, 0.f);
            if (bn < N) u = *(const float4*)(Bw + (size_t)bn * Kd + k0 + sc4);
            short4 x = {(short)f2bf(u.x), (short)f2bf(u.y), (short)f2bf(u.z), (short)f2bf(u.w)};
            *(short4*)&Bls[row][sc4] = x;
        }
        __syncthreads();
#pragma unroll
        for (int ks = 0; ks < 2; ks++) {
            bf16x8 am[4], bv[4];
#pragma unroll
            for (int f = 0; f < 4; f++) {
                am[f] = *(const bf16x8*)&Als[wr * 64 + f * 16 + (lane & 15)]
                                            [ks * 32 + (lane >> 4) * 8];
                bv[f] = *(const bf16x8*)&Bls[wc * 64 + f * 16 + (lane & 15)]
                                            [ks * 32 + (lane >> 4) * 8];
            }
#pragma unroll
            for (int fm = 0; fm < 4; fm++)
#pragma unroll
                for (int fn = 0; fn < 4; fn++)
                    acc[fm][fn] = __builtin_amdgcn_mfma_f32_16x16x32_bf16(am[fm], bv[fn],
                                                                          acc[fm][fn], 0, 0, 0);
        }
    }
#pragma unroll
    for (int fm = 0; fm < 4; fm++) {
#pragma unroll
        for (int r = 0; r < 4; r++) {
            int grow = row0 + wr * 64 + fm * 16 + (lane >> 4) * 4 + r;
            float* cp = C + (size_t)grow * ldc;
#pragma unroll
            for (int fn = 0; fn < 4; fn++) {
                int col = col0 + wc * 64 + fn * 16 + (lane & 15);
                if (col < N) {
                    float v = acc[fm][fn][r];
                    if (BIAS) v += bias[col];
                    cp[col] = v;
                }
            }
        }
    }
}

// ---------------- causal dw conv (K=4) + SiLU -> fp32 + bf16 ----------------
__global__ void k_dwconv(const float* __restrict__ xin, const float* __restrict__ w4,
                         const float* __restrict__ b1, float* __restrict__ xout,
                         ushortT* __restrict__ xoutb) {
    int bt = blockIdx.x;
    int t = bt & (LQ - 1);
    int ch = threadIdx.x;
    const float* w = w4 + ch * 4;
    float acc = b1[ch];
    const float* xp = xin + (size_t)bt * DIQ + ch;
#pragma unroll
    for (int k = 0; k < 4; k++) {
        int ts = t - 3 + k;
        if (ts >= 0) acc += xp[(ptrdiff_t)(ts - t) * DIQ] * w[k];
    }
    float y = acc * sigf(acc);
    xout[(size_t)bt * DIQ + ch] = y;
    xoutb[(size_t)bt * DIQ + ch] = f2bf(y);
}

// ======== chunked selective scan (unchanged from round 4) ========
__global__ __launch_bounds__(256) void k_scan1(float* __restrict__ scanX,
                                               const float* __restrict__ xdbl,
                                               const float* __restrict__ dt_w,
                                               const float* __restrict__ dt_b,
                                               const float* __restrict__ A_log,
                                               const float* __restrict__ Dpp, int instBase,
                                               float* __restrict__ hbuf,
                                               float* __restrict__ sbuf) {
    int bid = blockIdx.x;
    int seq = bid >> 4;
    int r = bid & 15;
    int c = r >> 1, half = r & 1;
    int inst = instBase + (seq >> 3);
    int ch = half * 256 + threadIdx.x;

    const float* xd = xdbl + ((size_t)seq * LQ + c * CT) * 48;
    float* xp = scanX + ((size_t)seq * LQ + c * CT) * DIQ + ch;
    int wo = inst * DIQ + ch;
    float dtw[16], Ad[16];
#pragma unroll
    for (int rr = 0; rr < 16; rr++) dtw[rr] = dt_w[(size_t)wo * 16 + rr];
    float dtb = dt_b[wo];
#pragma unroll
    for (int n = 0; n < 16; n++) Ad[n] = -__expf(A_log[(size_t)wo * 16 + n]);
    float Dd = Dpp[wo];
    float h[16];
#pragma unroll
    for (int n = 0; n < 16; n++) h[n] = 0.f;
    float S = 0.f;

    __shared__ float sd[CT * 48];
    for (int u = threadIdx.x; u < CT * 48; u += 256) sd[u] = xd[u];
    __syncthreads();

    float xt = xp[0];
    for (int tl = 0; tl < CT; tl++) {
        float xnext = (tl + 1 < CT) ? xp[(size_t)(tl + 1) * DIQ] : 0.f;
        const float* s = sd + tl * 48;
        float draw = dtb;
#pragma unroll
        for (int rr = 0; rr < 16; rr++) draw = fmaf(s[rr], dtw[rr], draw);
        float dt = softplusf(draw);
        S += dt;
        float dtx = dt * xt;
        float y = 0.f;
#pragma unroll
        for (int n = 0; n < 16; n++) {
            float e = __expf(dt * Ad[n]);
            h[n] = fmaf(h[n], e, dtx * s[16 + n]);
            y = fmaf(h[n], s[32 + n], y);
        }
        xp[(size_t)tl * DIQ] = fmaf(xt, Dd, y);
        xt = xnext;
    }
    size_t hb = ((size_t)(seq * CCH + c) * 16) * DIQ + ch;
#pragma unroll
    for (int n = 0; n < 16; n++) hbuf[hb + (size_t)n * DIQ] = h[n];
    sbuf[(size_t)(seq * CCH + c) * DIQ + ch] = S;
}

__global__ __launch_bounds__(512) void k_scan2(const float* __restrict__ A_log, int instBase,
                                               float* __restrict__ hbuf,
                                               const float* __restrict__ sbuf) {
    int seq = blockIdx.x;
    int inst = instBase + (seq >> 3);
    int ch = threadIdx.x;
    int wo = inst * DIQ + ch;
    float Ad[16];
#pragma unroll
    for (int n = 0; n < 16; n++) Ad[n] = -__expf(A_log[(size_t)wo * 16 + n]);
    float hin[16];
#pragma unroll
    for (int n = 0; n < 16; n++) hin[n] = 0.f;
    for (int c = 0; c < CCH; c++) {
        size_t hb = ((size_t)(seq * CCH + c) * 16) * DIQ + ch;
        float Sc = sbuf[(size_t)(seq * CCH + c) * DIQ + ch];
        float he[16];
#pragma unroll
        for (int n = 0; n < 16; n++) he[n] = hbuf[hb + (size_t)n * DIQ];
#pragma unroll
        for (int n = 0; n < 16; n++) hbuf[hb + (size_t)n * DIQ] = hin[n];
#pragma unroll
        for (int n = 0; n < 16; n++) hin[n] = fmaf(hin[n], __expf(Ad[n] * Sc), he[n]);
    }
}

__global__ __launch_bounds__(256) void k_scan3(float* __restrict__ scanX,
                                               const float* __restrict__ xdbl,
                                               const float* __restrict__ dt_w,
                                               const float* __restrict__ dt_b,
                                               const float* __restrict__ A_log, int instBase,
                                               const float* __restrict__ hbuf) {
    int bid = blockIdx.x;
    int seq = bid / (2 * (CCH - 1));
    int r = bid % (2 * (CCH - 1));
    int c = 1 + (r >> 1), half = r & 1;
    int inst = instBase + (seq >> 3);
    int ch = half * 256 + threadIdx.x;

    const float* xd = xdbl + ((size_t)seq * LQ + c * CT) * 48;
    float* xp = scanX + ((size_t)seq * LQ + c * CT) * DIQ + ch;
    int wo = inst * DIQ + ch;
    float dtw[16], Ad[16];
#pragma unroll
    for (int rr = 0; rr < 16; rr++) dtw[rr] = dt_w[(size_t)wo * 16 + rr];
    float dtb = dt_b[wo];
    float amax = -1e30f;
#pragma unroll
    for (int n = 0; n < 16; n++) {
        Ad[n] = -__expf(A_log[(size_t)wo * 16 + n]);
        amax = fmaxf(amax, Ad[n]);
    }
    float hin[16];
    size_t hb = ((size_t)(seq * CCH + c) * 16) * DIQ + ch;
#pragma unroll
    for (int n = 0; n < 16; n++) hin[n] = hbuf[hb + (size_t)n * DIQ];

    __shared__ float sd[CT * 48];
    for (int u = threadIdx.x; u < CT * 48; u += 256) sd[u] = xd[u];
    __syncthreads();

    float S = 0.f;
    for (int tl = 0; tl < CT; tl++) {
        const float* s = sd + tl * 48;
        float draw = dtb;
#pragma unroll
        for (int rr = 0; rr < 16; rr++) draw = fmaf(s[rr], dtw[rr], draw);
        S += softplusf(draw);
        if (__all(amax * S < -30.f)) break;
        float corr = 0.f;
#pragma unroll
        for (int n = 0; n < 16; n++) corr = fmaf(__expf(Ad[n] * S) * hin[n], s[32 + n], corr);
        xp[(size_t)tl * DIQ] += corr;
    }
}

// ---------------- gate: yb = bf16(y * silu(z)) ----------------
__global__ void k_gate(const float* __restrict__ y, const float* __restrict__ z,
                       ushortT* __restrict__ yb) {
    size_t idx = (size_t)blockIdx.x * 256 + threadIdx.x;
    float zv = z[idx];
    yb[idx] = f2bf(y[idx] * zv * sigf(zv));
}

// ---------------- fused weight (bf16 out) ----------------
__global__ void k_wfuse(const float* __restrict__ opw_h, const float* __restrict__ mow_i,
                        ushortT* __restrict__ wf) {
    int idx = blockIdx.x * 256 + threadIdx.x;
    int m = idx >> 9, d = idx & 511;
    const float* a = opw_h + (size_t)m * 512;
    const float* bm = mow_i + d;
    float s = 0.f;
    for (int c = 0; c < 256; c++) s = fmaf(a[c], bm[(size_t)c * 512], s);
    wf[idx] = f2bf(s);
}

// ---------------- 2-stage mean/max over L ----------------
__global__ void k_redu1(const float* __restrict__ o, float* __restrict__ psum,
                        float* __restrict__ pmax) {
    int b = blockIdx.x >> 5, tc = blockIdx.x & 31;
#pragma unroll
    for (int c3 = 0; c3 < 3; c3++) {
        int ch = c3 * 256 + threadIdx.x;
        const float* p = o + ((size_t)b * LQ + tc * 32) * DMQ + ch;
        float s = 0.f, m = -3.4e38f;
        for (int t = 0; t < 32; t++) {
            float v = p[(size_t)t * DMQ];
            s += v;
            m = fmaxf(m, v);
        }
        psum[(size_t)(b * 32 + tc) * DMQ + ch] = s;
        pmax[(size_t)(b * 32 + tc) * DMQ + ch] = m;
    }
}
__global__ void k_redu2(const float* __restrict__ psum, const float* __restrict__ pmax,
                        float* __restrict__ avg, float* __restrict__ mx) {
    int idx = blockIdx.x * 256 + threadIdx.x;  // 0..6143
    int b = idx / DMQ, ch = idx % DMQ;
    float s = 0.f, m = -3.4e38f;
    for (int tc = 0; tc < 32; tc++) {
        s += psum[(size_t)(b * 32 + tc) * DMQ + ch];
        m = fmaxf(m, pmax[(size_t)(b * 32 + tc) * DMQ + ch]);
    }
    avg[idx] = s * (1.f / LQ);
    mx[idx] = m;
}

__global__ void k_att1(const float* __restrict__ avg, const float* __restrict__ mx,
                       const float* __restrict__ w1, float* __restrict__ hs) {
    int idx = blockIdx.x * 256 + threadIdx.x;
    int b = idx / 384, j = idx % 384;
    const float* w = w1 + (size_t)j * DMQ;
    const float* a = avg + (size_t)b * DMQ;
    const float* m2 = mx + (size_t)b * DMQ;
    float s1 = 0.f, s2 = 0.f;
    for (int k = 0; k < DMQ; k++) {
        s1 = fmaf(a[k], w[k], s1);
        s2 = fmaf(m2[k], w[k], s2);
    }
    hs[idx] = fmaxf(s1, 0.f) + fmaxf(s2, 0.f);
}

__global__ void k_att2(const float* __restrict__ hs, const float* __restrict__ w2,
                       float* __restrict__ att) {
    int idx = blockIdx.x * 256 + threadIdx.x;
    int b = idx / DMQ, n = idx % DMQ;
    const float* w = w2 + (size_t)n * 384;
    const float* h = hs + (size_t)b * 384;
    float s = 0.f;
    for (int k = 0; k < 384; k++) s = fmaf(h[k], w[k], s);
    att[idx] = sigf(s);
}

// scale -> bf16 copy (out untouched)
__global__ void k_scaleb(const float* __restrict__ o, const float* __restrict__ att,
                         ushortT* __restrict__ ob) {
    size_t idx = (size_t)blockIdx.x * 256 + threadIdx.x;
    int ch = (int)(idx % DMQ);
    int b = (int)(idx / ((size_t)LQ * DMQ));
    ob[idx] = f2bf(o[idx] * att[b * DMQ + ch]);
}
// in-place scale (g==1 fallback)
__global__ void k_scale(float* __restrict__ o, const float* __restrict__ att) {
    size_t idx = (size_t)blockIdx.x * 256 + threadIdx.x;
    int ch = (int)(idx % DMQ);
    int b = (int)(idx / ((size_t)LQ * DMQ));
    o[idx] *= att[b * DMQ + ch];
}

__global__ void k_diag(float* __restrict__ o, float v) {
    if (blockIdx.x == 0 && threadIdx.x == 0) o[0] = v;
}

extern "C" void kernel_launch(void* const* d_in, const int* in_sizes, int n_in, void* d_out,
                              int out_size, void* d_ws, size_t ws_size, hipStream_t stream) {
    (void)in_sizes; (void)n_in; (void)out_size;
    const float* hid = (const float*)d_in[0];
    const int* mask = (const int*)d_in[1];
    const float* pool_w = (const float*)d_in[2];
    const float* pool_b = (const float*)d_in[3];
    const float* bn_g = (const float*)d_in[4];
    const float* bn_b = (const float*)d_in[5];
    const float* bn_rm = (const float*)d_in[6];
    const float* bn_rv = (const float*)d_in[7];
    const float* ipw = (const float*)d_in[8];
    const float* cw = (const float*)d_in[9];
    const float* cb = (const float*)d_in[10];
    const float* xpw = (const float*)d_in[11];
    const float* dtw = (const float*)d_in[12];
    const float* dtb = (const float*)d_in[13];
    const float* alog = (const float*)d_in[14];
    const float* Dpp = (const float*)d_in[15];
    const float* mow = (const float*)d_in[16];
    const float* opw = (const float*)d_in[17];
    const float* opb = (const float*)d_in[18];
    const float* caw1 = (const float*)d_in[19];
    const float* caw2 = (const float*)d_in[20];
    const float* fusw = (const float*)d_in[21];
    const float* fusb = (const float*)d_in[22];
    float* out = (float*)d_out;

    // layout (float-equivalent units)
    const size_t O_WTMPB = 32768;            // 65536 f.e. (256x512 bf16)
    const size_t O_IPWB = 98304;             // 786432 f.e.
    const size_t O_XPWB = 884736;            // 196608 f.e.
    const size_t O_FUSWB = 1081344;          // 294912 f.e.
    const size_t O_XDBL = 1376256;           // g*393216
    const size_t F_XDBL = 393216;
    const size_t F_CSC = 1048576;            // per-scale c bf16 (f.e.)
    const size_t F_SXB = 2097152;            // 8192x512 bf16 (f.e.)
    const size_t F_INST = 4194304;

    auto needF = [&](int g, int ck) -> size_t {
        return O_XDBL + (size_t)g * F_XDBL + (ck ? 3 : 1) * F_CSC + F_SXB +
               (size_t)g * F_INST + F_INST;
    };
    int g = 0, ckeep = 0;
    if (ws_size >= needF(6, 1) * 4) { g = 6; ckeep = 1; }
    else if (ws_size >= needF(3, 1) * 4) { g = 3; ckeep = 1; }
    else if (ws_size >= needF(1, 1) * 4) { g = 1; ckeep = 1; }
    else if (ws_size >= needF(1, 0) * 4) { g = 1; ckeep = 0; }
    else {
        k_diag<<<1, 64, 0, stream>>>(out, (float)(ws_size >> 20));
        return;
    }

    float* ws = (float*)d_ws;
    int* lengths = (int*)ws;
    float* avg = ws + 1024;
    float* mxp = avg + 6144;
    float* hs = mxp + 6144;
    float* att = hs + 3072;
    ushortT* wtmpb = (ushortT*)(ws + O_WTMPB);
    ushortT* ipwb = (ushortT*)(ws + O_IPWB);
    ushortT* xpwb = (ushortT*)(ws + O_XPWB);
    ushortT* fuswb = (ushortT*)(ws + O_FUSWB);
    float* xdbl = ws + O_XDBL;
    size_t o_cbase = O_XDBL + (size_t)g * F_XDBL;
    ushortT* cbase = (ushortT*)(ws + o_cbase);
    size_t o_sxb = o_cbase + (ckeep ? 3 : 1) * F_CSC;
    ushortT* sxb = (ushortT*)(ws + o_sxb);   // shared: dwconv bf16 out / gated bf16
    size_t o_scanX = o_sxb + F_SXB;
    float* scanX = ws + o_scanX;
    float* xzx = ws + o_scanX + (size_t)g * F_INST;
    // overlays
    float* hbuf = xzx;                               // scan state (xzx dead then)
    float* sbuf = xzx + (size_t)g * 524288;
    float* fusout = scanX;                           // scanX dead at fus time
    ushortT* outb = (ushortT*)(scanX + 6291456);     // g>=3 only
    float* psum = (float*)cbase;                     // cbase dead at redu time
    float* pmax = psum + 196608;

    k_lengths<<<dim3(8), dim3(256), 0, stream>>>(mask, lengths);
    // weight conversions (once per launch)
    k_cvt<<<dim3(6144), dim3(256), 0, stream>>>(ipw, ipwb, 6 * 1024 * 256);
    k_cvt<<<dim3(2304), dim3(256), 0, stream>>>(fusw, fuswb, 768 * 768);
    k_cvtpad48<<<dim3(1536), dim3(256), 0, stream>>>(xpw, xpwb);

    if (ckeep)
        for (int i = 0; i < 3; i++)
            k_pool<<<dim3(8192), dim3(256), 0, stream>>>(hid, pool_w, pool_b, bn_g, bn_b, bn_rm,
                                                         bn_rv, i, cbase + (size_t)i * 2097152);

    for (int base = 0; base < 6; base += g) {
        // phase 1: x-half in_proj -> dwconv -> xdbl
        for (int s = 0; s < g; s++) {
            int inst = base + s, i = inst >> 1, dir = inst & 1;
            ushortT* ci = ckeep ? cbase + (size_t)i * 2097152 : cbase;
            if (!ckeep)
                k_pool<<<dim3(8192), dim3(256), 0, stream>>>(hid, pool_w, pool_b, bn_g, bn_b,
                                                             bn_rm, bn_rv, i, ci);
            const ushortT* Wx = ipwb + (size_t)inst * 262144;
            float* sx = scanX + (size_t)s * F_INST;
            if (dir == 0)
                gemm_bf16<0, 0, 0, 0><<<dim3(4, 64), 256, 0, stream>>>(ci, Wx, xzx, nullptr,
                                                                       512, 256, 256, 512,
                                                                       lengths);
            else
                gemm_bf16<1, 0, 0, 0><<<dim3(4, 64), 256, 0, stream>>>(ci, Wx, xzx, nullptr,
                                                                       512, 256, 256, 512,
                                                                       lengths);
            k_dwconv<<<dim3(8192), dim3(512), 0, stream>>>(xzx, cw + (size_t)inst * DIQ * 4,
                                                           cb + (size_t)inst * DIQ, sx, sxb);
            gemm_bf16<0, 0, 0, 0><<<dim3(1, 64), 256, 0, stream>>>(
                sxb, xpwb + (size_t)inst * 65536, xdbl + (size_t)s * F_XDBL, nullptr, 48, 512,
                512, 48, lengths);
        }
        // phase 2: chunked selective scan
        k_scan1<<<dim3(g * 8 * CCH * 2), dim3(256), 0, stream>>>(scanX, xdbl, dtw, dtb, alog,
                                                                 Dpp, base, hbuf, sbuf);
        k_scan2<<<dim3(g * 8), dim3(512), 0, stream>>>(alog, base, hbuf, sbuf);
        k_scan3<<<dim3(g * 8 * (CCH - 1) * 2), dim3(256), 0, stream>>>(scanX, xdbl, dtw, dtb,
                                                                       alog, base, hbuf);
        // phase 3: z-half in_proj -> gate -> fused mo+op into d_out
        for (int s = 0; s < g; s++) {
            int inst = base + s, i = inst >> 1, dir = inst & 1;
            ushortT* ci = ckeep ? cbase + (size_t)i * 2097152 : cbase;
            if (!ckeep)
                k_pool<<<dim3(8192), dim3(256), 0, stream>>>(hid, pool_w, pool_b, bn_g, bn_b,
                                                             bn_rm, bn_rv, i, ci);
            const ushortT* Wz = ipwb + (size_t)inst * 262144 + 131072;
            if (dir == 0)
                gemm_bf16<0, 0, 0, 0><<<dim3(4, 64), 256, 0, stream>>>(ci, Wz, xzx, nullptr,
                                                                       512, 256, 256, 512,
                                                                       lengths);
            else
                gemm_bf16<1, 0, 0, 0><<<dim3(4, 64), 256, 0, stream>>>(ci, Wz, xzx, nullptr,
                                                                       512, 256, 256, 512,
                                                                       lengths);
            float* sx = scanX + (size_t)s * F_INST;
            k_gate<<<dim3(16384), dim3(256), 0, stream>>>(sx, xzx, sxb);
            k_wfuse<<<dim3(512), dim3(256), 0, stream>>>(opw + (size_t)i * 131072 + dir * 256,
                                                         mow + (size_t)inst * 131072, wtmpb);
            if (dir == 0)
                gemm_bf16<0, 0, 0, 0><<<dim3(2, 64), 256, 0, stream>>>(
                    sxb, wtmpb, out + i * 256, nullptr, 256, 512, 512, DMQ, lengths);
            else
                gemm_bf16<0, 1, 1, 1><<<dim3(2, 64), 256, 0, stream>>>(
                    sxb, wtmpb, out + i * 256, opb + (size_t)i * 256, 256, 512, 512, DMQ,
                    lengths);
        }
    }

    // attention pooling + final projection
    k_redu1<<<dim3(256), dim3(256), 0, stream>>>(out, psum, pmax);
    k_redu2<<<dim3(24), dim3(256), 0, stream>>>(psum, pmax, avg, mxp);
    k_att1<<<dim3(12), dim3(256), 0, stream>>>(avg, mxp, caw1, hs);
    k_att2<<<dim3(24), dim3(256), 0, stream>>>(hs, caw2, att);
    if (g >= 3) {
        k_scaleb<<<dim3(24576), dim3(256), 0, stream>>>(out, att, outb);
        gemm_bf16<0, 0, 1, 0><<<dim3(6, 64), 256, 0, stream>>>(outb, fuswb, fusout, fusb, DMQ,
                                                               DMQ, DMQ, DMQ, lengths);
    } else {
        k_scale<<<dim3(24576), dim3(256), 0, stream>>>(out, att);
        gemm_mfma<1><<<dim3(6, 64), 256, 0, stream>>>(out, fusw, fusout, fusb, DMQ, DMQ, DMQ,
                                                      DMQ);
    }
    hipMemcpyAsync(d_out, fusout, (size_t)DMQ * LQ * 8 * 4, hipMemcpyDeviceToDevice, stream);
}

// Round 6
// 679.044 us; speedup vs baseline: 4.3676x; 1.4776x over previous
//
#include <hip/hip_runtime.h>
#include <cstddef>
#include <cstdint>

#define LQ 1024
#define DMQ 768
#define DSQ 256
#define DIQ 512
#define CCH 8
#define CT (LQ / CCH)

typedef unsigned short ushortT;
using f32x4 = __attribute__((ext_vector_type(4))) float;
using bf16x8 = __attribute__((ext_vector_type(8))) short;

__device__ __forceinline__ float sigf(float x) { return 1.f / (1.f + __expf(-x)); }
__device__ __forceinline__ float softplusf(float x) {
    return fmaxf(x, 0.f) + log1pf(__expf(-fabsf(x)));
}
__device__ __forceinline__ ushortT f2bf(float f) {
    unsigned u = __float_as_uint(f);
    u += 0x7FFFu + ((u >> 16) & 1u);
    return (ushortT)(u >> 16);
}
__device__ __forceinline__ float bf2f(ushortT u) {
    return __uint_as_float(((unsigned)u) << 16);
}
__device__ __forceinline__ void gload_lds16(const void* g, void* l) {
    __builtin_amdgcn_global_load_lds((const __attribute__((address_space(1))) void*)g,
                                     (__attribute__((address_space(3))) void*)l, 16, 0, 0);
}

// ---------------- lengths ----------------
__global__ void k_lengths(const int* __restrict__ mask, int* __restrict__ lengths) {
    int b = blockIdx.x;
    int s = 0;
    for (int t = threadIdx.x; t < LQ; t += 256) s += mask[b * LQ + t];
    __shared__ int sm[256];
    sm[threadIdx.x] = s;
    __syncthreads();
    for (int o = 128; o > 0; o >>= 1) {
        if (threadIdx.x < o) sm[threadIdx.x] += sm[threadIdx.x + o];
        __syncthreads();
    }
    if (threadIdx.x == 0) lengths[b] = sm[0];
}

// ---------------- fp32 -> bf16 converters ----------------
__global__ void k_cvt(const float* __restrict__ in, ushortT* __restrict__ out, int n) {
    int i = blockIdx.x * 256 + threadIdx.x;
    if (i < n) out[i] = f2bf(in[i]);
}
__global__ void k_cvtpad48(const float* __restrict__ xpw, ushortT* __restrict__ out) {
    int idx = blockIdx.x * 256 + threadIdx.x;  // 6*128*512
    int inst = idx >> 16, rem = idx & 65535;
    int row = rem >> 9, col = rem & 511;
    float v = (row < 48) ? xpw[((size_t)inst * 48 + row) * 512 + col] : 0.f;
    out[idx] = f2bf(v);
}

// ---------------- batched fused weight: wf[inst][m][d] ----------------
__global__ void k_wfuse(const float* __restrict__ opw, const float* __restrict__ mow,
                        ushortT* __restrict__ wf) {
    int idx = blockIdx.x * 256 + threadIdx.x;  // 6*131072
    int inst = idx >> 17, rem = idx & 131071;
    int m = rem >> 9, d = rem & 511;
    int i = inst >> 1, dir = inst & 1;
    const float* a = opw + (size_t)i * 131072 + dir * 256 + (size_t)m * 512;
    const float* bm = mow + (size_t)inst * 131072 + d;
    float s = 0.f;
    for (int c = 0; c < 256; c++) s = fmaf(a[c], bm[(size_t)c * 512], s);
    wf[idx] = f2bf(s);
}

// ---------------- dilated dw conv + BN + GELU -> c bf16 (all 3 scales) ----------------
__global__ void k_pool(const float* __restrict__ hid, const float* __restrict__ pw,
                       const float* __restrict__ pb, const float* __restrict__ bg,
                       const float* __restrict__ bb, const float* __restrict__ brm,
                       const float* __restrict__ brv, ushortT* __restrict__ cdst) {
    int gidx = blockIdx.x;        // 3*8192
    int isc = gidx >> 13;
    int idx = gidx & 8191;
    int l = idx & (LQ - 1);
    int b = idx >> 10;
    int ch = threadIdx.x;
    int dil = 1 << isc;
    int wci = isc * DSQ + ch;
    const float* xb = hid + (size_t)b * LQ * DMQ + isc * DSQ + ch;
    float w0 = pw[wci * 3 + 0], w1 = pw[wci * 3 + 1], w2 = pw[wci * 3 + 2];
    float acc = pb[wci];
    int lm = l - dil, lp = l + dil;
    if (lm >= 0) acc += xb[(size_t)lm * DMQ] * w0;
    acc += xb[(size_t)l * DMQ] * w1;
    if (lp < LQ) acc += xb[(size_t)lp * DMQ] * w2;
    float xn = (acc - brm[wci]) * rsqrtf(brv[wci] + 1e-5f) * bg[wci] + bb[wci];
    float y = 0.5f * xn * (1.0f + erff(xn * 0.70710678118654752f));
    cdst[(size_t)isc * 2097152 + (size_t)idx * DSQ + ch] = f2bf(y);
}

// ---------------- batched bf16 GEMM: C[z] (+)= A[z] * Bw[z]^T ----------------
// FLIPA: 0 none, 1 always, 2 when (z&1). CBF16: C is bf16.
template <int FLIPA, int FLIPC, int BIAS, int ACC, int CBF16>
__global__ __launch_bounds__(256) void gemm_bf16(const ushortT* __restrict__ A,
                                                 const ushortT* __restrict__ Bw,
                                                 void* __restrict__ Cv,
                                                 const float* __restrict__ bias, int N, int Kd,
                                                 int lda, int ldc,
                                                 const int* __restrict__ lengths, long sAz,
                                                 int zshiftA, long sBz, long sCz, int sBiasz) {
    __shared__ ushortT Als[128 * 64];
    __shared__ ushortT Bls[128 * 64];
    const int z = blockIdx.z;
    A += (size_t)(z >> zshiftA) * sAz;
    Bw += (size_t)z * sBz;
    float* Cf = (float*)Cv + (CBF16 ? 0 : (size_t)z * sCz);
    ushortT* Cb = (ushortT*)Cv + (CBF16 ? (size_t)z * sCz : 0);
    if (BIAS) bias += (size_t)z * sBiasz;

    const int tid = threadIdx.x;
    const int lane = tid & 63;
    const int wave = tid >> 6;
    const int wr = wave >> 1, wc = wave & 1;
    const int row0 = blockIdx.y * 128, col0 = blockIdx.x * 128;
    const bool doflip = (FLIPA == 1) || (FLIPA == 2 && (z & 1));
    int len = 0;
    if (FLIPA || FLIPC) len = lengths[row0 >> 10];

    const int srow = wave * 8 + (lane >> 3);  // + it*32
    const int scol = (lane & 7) * 8;

    f32x4 acc[4][4];
#pragma unroll
    for (int i = 0; i < 4; i++)
#pragma unroll
        for (int j = 0; j < 4; j++) acc[i][j] = (f32x4){0.f, 0.f, 0.f, 0.f};

    for (int k0 = 0; k0 < Kd; k0 += 64) {
        __syncthreads();
#pragma unroll
        for (int it = 0; it < 4; it++) {
            int row = it * 32 + srow;
            int grow = row0 + row;
            if (FLIPA) {
                if (doflip) {
                    int t = grow & (LQ - 1);
                    int ts = (t < len) ? (len - 1 - t) : t;
                    grow = (grow & ~(LQ - 1)) | ts;
                }
            }
            gload_lds16(A + (size_t)grow * lda + k0 + scol, &Als[it * 2048 + wave * 512]);
        }
#pragma unroll
        for (int it = 0; it < 4; it++) {
            int row = it * 32 + srow;
            gload_lds16(Bw + (size_t)(col0 + row) * Kd + k0 + scol,
                        &Bls[it * 2048 + wave * 512]);
        }
        __syncthreads();
#pragma unroll
        for (int ks = 0; ks < 2; ks++) {
            bf16x8 am[4], bv[4];
#pragma unroll
            for (int f = 0; f < 4; f++) {
                am[f] = *(const bf16x8*)&Als[(wr * 64 + f * 16 + (lane & 15)) * 64 + ks * 32 +
                                             (lane >> 4) * 8];
                bv[f] = *(const bf16x8*)&Bls[(wc * 64 + f * 16 + (lane & 15)) * 64 + ks * 32 +
                                             (lane >> 4) * 8];
            }
#pragma unroll
            for (int fm = 0; fm < 4; fm++)
#pragma unroll
                for (int fn = 0; fn < 4; fn++)
                    acc[fm][fn] = __builtin_amdgcn_mfma_f32_16x16x32_bf16(am[fm], bv[fn],
                                                                          acc[fm][fn], 0, 0, 0);
        }
    }
#pragma unroll
    for (int fm = 0; fm < 4; fm++) {
#pragma unroll
        for (int r = 0; r < 4; r++) {
            int grow = row0 + wr * 64 + fm * 16 + (lane >> 4) * 4 + r;
            if (FLIPC) {
                int t = grow & (LQ - 1);
                int ts = (t < len) ? (len - 1 - t) : t;
                grow = (grow & ~(LQ - 1)) | ts;
            }
#pragma unroll
            for (int fn = 0; fn < 4; fn++) {
                int col = col0 + wc * 64 + fn * 16 + (lane & 15);
                if (col < N) {
                    float v = acc[fm][fn][r];
                    if (CBF16) {
                        Cb[(size_t)grow * ldc + col] = f2bf(v);
                    } else {
                        float* cp = Cf + (size_t)grow * ldc + col;
                        if (ACC) v += *cp;
                        if (BIAS) v += bias[col];
                        *cp = v;
                    }
                }
            }
        }
    }
}

// ---------------- batched causal dw conv (K=4) + SiLU: rawx bf16 -> scanX bf16 ----------
__global__ void k_dwconv(const ushortT* __restrict__ rawx, const float* __restrict__ cw,
                         const float* __restrict__ cb, ushortT* __restrict__ sx) {
    int bt = blockIdx.x;  // 6*8192
    int inst = bt >> 13;
    int t = bt & (LQ - 1);
    int ch = threadIdx.x;
    const float* w = cw + (size_t)inst * 2048 + ch * 4;
    float acc = cb[inst * DIQ + ch];
    const ushortT* xp = rawx + (size_t)bt * DIQ + ch;
#pragma unroll
    for (int k = 0; k < 4; k++) {
        int ts = t - 3 + k;
        if (ts >= 0) acc += bf2f(xp[(ptrdiff_t)(ts - t) * DIQ]) * w[k];
    }
    sx[(size_t)bt * DIQ + ch] = f2bf(acc * sigf(acc));
}

// ======== chunked selective scan (bf16 x/y, exp-structure fast path) ========
// pass 1: per-chunk local scan. grid 48*CCH*2 blocks of 256.
__global__ __launch_bounds__(256) void k_scan1(ushortT* __restrict__ scanX,
                                               const float* __restrict__ xdbl,
                                               const float* __restrict__ dt_w,
                                               const float* __restrict__ dt_b,
                                               const float* __restrict__ A_log,
                                               const float* __restrict__ Dpp,
                                               float* __restrict__ hbuf,
                                               float* __restrict__ sbuf) {
    int bid = blockIdx.x;
    int seq = bid >> 4;
    int r = bid & 15;
    int c = r >> 1, half = r & 1;
    int inst = seq >> 3;
    int ch = half * 256 + threadIdx.x;

    const float* xd = xdbl + ((size_t)seq * LQ + c * CT) * 48;
    ushortT* xp = scanX + ((size_t)seq * LQ + c * CT) * DIQ + ch;
    int wo = inst * DIQ + ch;
    float dtw[16], Ad[16];
#pragma unroll
    for (int rr = 0; rr < 16; rr++) dtw[rr] = dt_w[(size_t)wo * 16 + rr];
    float dtb = dt_b[wo];
    bool fastA = true;
#pragma unroll
    for (int n = 0; n < 16; n++) {
        Ad[n] = -__expf(A_log[(size_t)wo * 16 + n]);
        fastA = fastA && (fabsf(Ad[n] + (float)(n + 1)) < 1e-3f * (n + 1));
    }
    float Dd = Dpp[wo];
    float h[16];
#pragma unroll
    for (int n = 0; n < 16; n++) h[n] = 0.f;
    float S = 0.f;

    __shared__ float sd[CT * 48];
    for (int u = threadIdx.x; u < CT * 48; u += 256) sd[u] = xd[u];
    __syncthreads();

    float xt = bf2f(xp[0]);
    if (fastA) {
        for (int tl = 0; tl < CT; tl++) {
            float xnext = (tl + 1 < CT) ? bf2f(xp[(size_t)(tl + 1) * DIQ]) : 0.f;
            const float* s = sd + tl * 48;
            float draw = dtb;
#pragma unroll
            for (int rr = 0; rr < 16; rr++) draw = fmaf(s[rr], dtw[rr], draw);
            float dt = softplusf(draw);
            S += dt;
            float e1 = __expf(-dt);
            float dtx = dt * xt;
            float y = 0.f, e = 1.f;
#pragma unroll
            for (int n = 0; n < 16; n++) {
                e *= e1;
                h[n] = fmaf(h[n], e, dtx * s[16 + n]);
                y = fmaf(h[n], s[32 + n], y);
            }
            xp[(size_t)tl * DIQ] = f2bf(fmaf(xt, Dd, y));
            xt = xnext;
        }
    } else {
        for (int tl = 0; tl < CT; tl++) {
            float xnext = (tl + 1 < CT) ? bf2f(xp[(size_t)(tl + 1) * DIQ]) : 0.f;
            const float* s = sd + tl * 48;
            float draw = dtb;
#pragma unroll
            for (int rr = 0; rr < 16; rr++) draw = fmaf(s[rr], dtw[rr], draw);
            float dt = softplusf(draw);
            S += dt;
            float dtx = dt * xt;
            float y = 0.f;
#pragma unroll
            for (int n = 0; n < 16; n++) {
                float e = __expf(dt * Ad[n]);
                h[n] = fmaf(h[n], e, dtx * s[16 + n]);
                y = fmaf(h[n], s[32 + n], y);
            }
            xp[(size_t)tl * DIQ] = f2bf(fmaf(xt, Dd, y));
            xt = xnext;
        }
    }
    size_t hb = ((size_t)(seq * CCH + c) * 16) * DIQ + ch;
#pragma unroll
    for (int n = 0; n < 16; n++) hbuf[hb + (size_t)n * DIQ] = h[n];
    sbuf[(size_t)(seq * CCH + c) * DIQ + ch] = S;
}

// pass 2: sequential chunk-state combine. grid 48 blocks of 512.
__global__ __launch_bounds__(512) void k_scan2(const float* __restrict__ A_log,
                                               float* __restrict__ hbuf,
                                               const float* __restrict__ sbuf) {
    int seq = blockIdx.x;
    int inst = seq >> 3;
    int ch = threadIdx.x;
    int wo = inst * DIQ + ch;
    float Ad[16];
#pragma unroll
    for (int n = 0; n < 16; n++) Ad[n] = -__expf(A_log[(size_t)wo * 16 + n]);
    float hin[16];
#pragma unroll
    for (int n = 0; n < 16; n++) hin[n] = 0.f;
    for (int c = 0; c < CCH; c++) {
        size_t hb = ((size_t)(seq * CCH + c) * 16) * DIQ + ch;
        float Sc = sbuf[(size_t)(seq * CCH + c) * DIQ + ch];
        float he[16];
#pragma unroll
        for (int n = 0; n < 16; n++) he[n] = hbuf[hb + (size_t)n * DIQ];
#pragma unroll
        for (int n = 0; n < 16; n++) hbuf[hb + (size_t)n * DIQ] = hin[n];
#pragma unroll
        for (int n = 0; n < 16; n++) hin[n] = fmaf(hin[n], __expf(Ad[n] * Sc), he[n]);
    }
}

// pass 3: carried-state correction. grid 48*(CCH-1)*2 blocks of 256.
__global__ __launch_bounds__(256) void k_scan3(ushortT* __restrict__ scanX,
                                               const float* __restrict__ xdbl,
                                               const float* __restrict__ dt_w,
                                               const float* __restrict__ dt_b,
                                               const float* __restrict__ A_log,
                                               const float* __restrict__ hbuf) {
    int bid = blockIdx.x;
    int seq = bid / (2 * (CCH - 1));
    int r = bid % (2 * (CCH - 1));
    int c = 1 + (r >> 1), half = r & 1;
    int inst = seq >> 3;
    int ch = half * 256 + threadIdx.x;

    const float* xd = xdbl + ((size_t)seq * LQ + c * CT) * 48;
    ushortT* xp = scanX + ((size_t)seq * LQ + c * CT) * DIQ + ch;
    int wo = inst * DIQ + ch;
    float dtw[16], Ad[16];
#pragma unroll
    for (int rr = 0; rr < 16; rr++) dtw[rr] = dt_w[(size_t)wo * 16 + rr];
    float dtb = dt_b[wo];
    float amax = -1e30f;
    bool fastA = true;
#pragma unroll
    for (int n = 0; n < 16; n++) {
        Ad[n] = -__expf(A_log[(size_t)wo * 16 + n]);
        amax = fmaxf(amax, Ad[n]);
        fastA = fastA && (fabsf(Ad[n] + (float)(n + 1)) < 1e-3f * (n + 1));
    }
    float hin[16];
    size_t hb = ((size_t)(seq * CCH + c) * 16) * DIQ + ch;
#pragma unroll
    for (int n = 0; n < 16; n++) hin[n] = hbuf[hb + (size_t)n * DIQ];

    __shared__ float sd[CT * 48];
    for (int u = threadIdx.x; u < CT * 48; u += 256) sd[u] = xd[u];
    __syncthreads();

    float S = 0.f;
    for (int tl = 0; tl < CT; tl++) {
        const float* s = sd + tl * 48;
        float draw = dtb;
#pragma unroll
        for (int rr = 0; rr < 16; rr++) draw = fmaf(s[rr], dtw[rr], draw);
        S += softplusf(draw);
        if (__all(amax * S < -30.f)) break;
        float corr = 0.f;
        if (fastA) {
            float eS = __expf(-S);
            float e = 1.f;
#pragma unroll
            for (int n = 0; n < 16; n++) {
                e *= eS;
                corr = fmaf(e * hin[n], s[32 + n], corr);
            }
        } else {
#pragma unroll
            for (int n = 0; n < 16; n++)
                corr = fmaf(__expf(Ad[n] * S) * hin[n], s[32 + n], corr);
        }
        xp[(size_t)tl * DIQ] = f2bf(bf2f(xp[(size_t)tl * DIQ]) + corr);
    }
}

// ---------------- batched gate: y = bf16(y * silu(z)) in place ----------------
__global__ void k_gate(ushortT* __restrict__ y, const ushortT* __restrict__ z) {
    size_t idx = (size_t)blockIdx.x * 256 + threadIdx.x;
    float zv = bf2f(z[idx]);
    y[idx] = f2bf(bf2f(y[idx]) * zv * sigf(zv));
}

// ---------------- 2-stage mean/max over L ----------------
__global__ void k_redu1(const float* __restrict__ o, float* __restrict__ psum,
                        float* __restrict__ pmax) {
    int b = blockIdx.x >> 5, tc = blockIdx.x & 31;
#pragma unroll
    for (int c3 = 0; c3 < 3; c3++) {
        int ch = c3 * 256 + threadIdx.x;
        const float* p = o + ((size_t)b * LQ + tc * 32) * DMQ + ch;
        float s = 0.f, m = -3.4e38f;
        for (int t = 0; t < 32; t++) {
            float v = p[(size_t)t * DMQ];
            s += v;
            m = fmaxf(m, v);
        }
        psum[(size_t)(b * 32 + tc) * DMQ + ch] = s;
        pmax[(size_t)(b * 32 + tc) * DMQ + ch] = m;
    }
}
__global__ void k_redu2(const float* __restrict__ psum, const float* __restrict__ pmax,
                        float* __restrict__ avg, float* __restrict__ mx) {
    int idx = blockIdx.x * 256 + threadIdx.x;
    int b = idx / DMQ, ch = idx % DMQ;
    float s = 0.f, m = -3.4e38f;
    for (int tc = 0; tc < 32; tc++) {
        s += psum[(size_t)(b * 32 + tc) * DMQ + ch];
        m = fmaxf(m, pmax[(size_t)(b * 32 + tc) * DMQ + ch]);
    }
    avg[idx] = s * (1.f / LQ);
    mx[idx] = m;
}

__global__ void k_att1(const float* __restrict__ avg, const float* __restrict__ mx,
                       const float* __restrict__ w1, float* __restrict__ hs) {
    int idx = blockIdx.x * 256 + threadIdx.x;
    int b = idx / 384, j = idx % 384;
    const float* w = w1 + (size_t)j * DMQ;
    const float* a = avg + (size_t)b * DMQ;
    const float* m2 = mx + (size_t)b * DMQ;
    float s1 = 0.f, s2 = 0.f;
    for (int k = 0; k < DMQ; k++) {
        s1 = fmaf(a[k], w[k], s1);
        s2 = fmaf(m2[k], w[k], s2);
    }
    hs[idx] = fmaxf(s1, 0.f) + fmaxf(s2, 0.f);
}

__global__ void k_att2(const float* __restrict__ hs, const float* __restrict__ w2,
                       float* __restrict__ att) {
    int idx = blockIdx.x * 256 + threadIdx.x;
    int b = idx / DMQ, n = idx % DMQ;
    const float* w = w2 + (size_t)n * 384;
    const float* h = hs + (size_t)b * 384;
    float s = 0.f;
    for (int k = 0; k < 384; k++) s = fmaf(h[k], w[k], s);
    att[idx] = sigf(s);
}

__global__ void k_scaleb(const float* __restrict__ o, const float* __restrict__ att,
                         ushortT* __restrict__ ob) {
    size_t idx = (size_t)blockIdx.x * 256 + threadIdx.x;
    int ch = (int)(idx % DMQ);
    int b = (int)(idx / ((size_t)LQ * DMQ));
    ob[idx] = f2bf(o[idx] * att[b * DMQ + ch]);
}

__global__ void k_diag(float* __restrict__ o, float v) {
    if (blockIdx.x == 0 && threadIdx.x == 0) o[0] = v;
}

extern "C" void kernel_launch(void* const* d_in, const int* in_sizes, int n_in, void* d_out,
                              int out_size, void* d_ws, size_t ws_size, hipStream_t stream) {
    (void)in_sizes; (void)n_in; (void)out_size;
    const float* hid = (const float*)d_in[0];
    const int* mask = (const int*)d_in[1];
    const float* pool_w = (const float*)d_in[2];
    const float* pool_b = (const float*)d_in[3];
    const float* bn_g = (const float*)d_in[4];
    const float* bn_b = (const float*)d_in[5];
    const float* bn_rm = (const float*)d_in[6];
    const float* bn_rv = (const float*)d_in[7];
    const float* ipw = (const float*)d_in[8];
    const float* cw = (const float*)d_in[9];
    const float* cb = (const float*)d_in[10];
    const float* xpw = (const float*)d_in[11];
    const float* dtw = (const float*)d_in[12];
    const float* dtb = (const float*)d_in[13];
    const float* alog = (const float*)d_in[14];
    const float* Dpp = (const float*)d_in[15];
    const float* mow = (const float*)d_in[16];
    const float* opw = (const float*)d_in[17];
    const float* opb = (const float*)d_in[18];
    const float* caw1 = (const float*)d_in[19];
    const float* caw2 = (const float*)d_in[20];
    const float* fusw = (const float*)d_in[21];
    const float* fusb = (const float*)d_in[22];
    float* out = (float*)d_out;

    // workspace layout (float-equivalent offsets)
    const size_t O_IPWB = 32768;       // 786432 f.e. (6*1024*256 bf16)
    const size_t O_XPWB = 819200;      // 196608 f.e.
    const size_t O_FUSWB = 1015808;    // 294912 f.e.
    const size_t O_WTMPB = 1310720;    // 393216 f.e. (6*256*512 bf16)
    const size_t O_XDBL = 1703936;     // 2359296 f (6*8192*48)
    const size_t O_CBASE = 4063232;    // 3145728 f.e. (3*8192*256 bf16)
    const size_t O_RAWX = 7208960;     // 12582912 f.e. (6*8192*512 bf16)
    const size_t O_SCANX = 19791872;   // 12582912 f.e.
    const size_t TOTAL_F = 32374784;   // 129.5 MB
    if (ws_size < TOTAL_F * 4) {
        k_diag<<<1, 64, 0, stream>>>(out, (float)(ws_size >> 20));
        return;
    }

    float* ws = (float*)d_ws;
    int* lengths = (int*)ws;
    float* avg = ws + 1024;
    float* mxp = avg + 6144;
    float* hs = mxp + 6144;
    float* att = hs + 3072;
    ushortT* ipwb = (ushortT*)(ws + O_IPWB);
    ushortT* xpwb = (ushortT*)(ws + O_XPWB);
    ushortT* fuswb = (ushortT*)(ws + O_FUSWB);
    ushortT* wtmpb = (ushortT*)(ws + O_WTMPB);
    float* xdbl = ws + O_XDBL;
    ushortT* cbase = (ushortT*)(ws + O_CBASE);
    ushortT* rawx = (ushortT*)(ws + O_RAWX);     // also: zbuf (after scan)
    ushortT* scanX = (ushortT*)(ws + O_SCANX);
    // overlays
    float* hbuf = ws + O_RAWX;                   // rawx dead after dwconv, until z-GEMM
    float* sbuf = hbuf + 3145728;
    float* psum = (float*)cbase;                 // cbase dead after z-GEMM
    float* pmax = psum + 196608;
    ushortT* outb = scanX;                       // scanX dead after mo/op GEMMs

    // ---- weight prep (independent) ----
    k_lengths<<<dim3(8), dim3(256), 0, stream>>>(mask, lengths);
    k_cvt<<<dim3(6144), dim3(256), 0, stream>>>(ipw, ipwb, 6 * 1024 * 256);
    k_cvt<<<dim3(2304), dim3(256), 0, stream>>>(fusw, fuswb, 768 * 768);
    k_cvtpad48<<<dim3(1536), dim3(256), 0, stream>>>(xpw, xpwb);
    k_wfuse<<<dim3(3072), dim3(256), 0, stream>>>(opw, mow, wtmpb);

    // ---- pool (all scales) ----
    k_pool<<<dim3(3 * 8192), dim3(256), 0, stream>>>(hid, pool_w, pool_b, bn_g, bn_b, bn_rm,
                                                     bn_rv, cbase);

    // ---- in_proj x-half (all 6 insts), flip odd insts ----
    gemm_bf16<2, 0, 0, 0, 1><<<dim3(4, 64, 6), 256, 0, stream>>>(
        cbase, ipwb, rawx, nullptr, 512, 256, 256, 512, lengths, 2097152, 1, 262144, 4194304, 0);

    // ---- dwconv + SiLU (all insts) ----
    k_dwconv<<<dim3(6 * 8192), dim3(512), 0, stream>>>(rawx, cw, cb, scanX);

    // ---- x_proj (all insts) ----
    gemm_bf16<0, 0, 0, 0, 0><<<dim3(1, 64, 6), 256, 0, stream>>>(
        scanX, xpwb, xdbl, nullptr, 48, 512, 512, 48, lengths, 4194304, 0, 65536, 393216, 0);

    // ---- chunked selective scan (in place on scanX) ----
    k_scan1<<<dim3(48 * CCH * 2), dim3(256), 0, stream>>>(scanX, xdbl, dtw, dtb, alog, Dpp,
                                                          hbuf, sbuf);
    k_scan2<<<dim3(48), dim3(512), 0, stream>>>(alog, hbuf, sbuf);
    k_scan3<<<dim3(48 * (CCH - 1) * 2), dim3(256), 0, stream>>>(scanX, xdbl, dtw, dtb, alog,
                                                                hbuf);

    // ---- in_proj z-half (all insts) -> zbuf (= rawx region) ----
    gemm_bf16<2, 0, 0, 0, 1><<<dim3(4, 64, 6), 256, 0, stream>>>(
        cbase, ipwb + 131072, rawx, nullptr, 512, 256, 256, 512, lengths, 2097152, 1, 262144,
        4194304, 0);

    // ---- gate (all insts, in place on scanX) ----
    k_gate<<<dim3(6 * 16384), dim3(256), 0, stream>>>(scanX, rawx);

    // ---- fused mo+op: dir0 write, dir1 accumulate+bias+flip ----
    gemm_bf16<0, 0, 0, 0, 0><<<dim3(2, 64, 3), 256, 0, stream>>>(
        scanX, wtmpb, out, nullptr, 256, 512, 512, DMQ, lengths, 8388608, 0, 262144, 256, 0);
    gemm_bf16<0, 1, 1, 1, 0><<<dim3(2, 64, 3), 256, 0, stream>>>(
        scanX + 4194304, wtmpb + 131072, out, opb, 256, 512, 512, DMQ, lengths, 8388608, 0,
        262144, 256, 256);

    // ---- attention pooling + final projection (writes d_out in place) ----
    k_redu1<<<dim3(256), dim3(256), 0, stream>>>(out, psum, pmax);
    k_redu2<<<dim3(24), dim3(256), 0, stream>>>(psum, pmax, avg, mxp);
    k_att1<<<dim3(12), dim3(256), 0, stream>>>(avg, mxp, caw1, hs);
    k_att2<<<dim3(24), dim3(256), 0, stream>>>(hs, caw2, att);
    k_scaleb<<<dim3(24576), dim3(256), 0, stream>>>(out, att, outb);
    gemm_bf16<0, 0, 1, 0, 0><<<dim3(6, 64, 1), 256, 0, stream>>>(
        outb, fuswb, out, fusb, DMQ, DMQ, DMQ, DMQ, lengths, 0, 0, 0, 0, 0);
}

// Round 7
// 598.296 us; speedup vs baseline: 4.9571x; 1.1350x over previous
//
#include <hip/hip_runtime.h>
#include <cstddef>
#include <cstdint>

#define LQ 1024
#define DMQ 768
#define DSQ 256
#define DIQ 512
#define CCH 8
#define CT (LQ / CCH)

typedef unsigned short ushortT;
using f32x4 = __attribute__((ext_vector_type(4))) float;
using bf16x8 = __attribute__((ext_vector_type(8))) short;

__device__ __forceinline__ float sigf(float x) { return 1.f / (1.f + __expf(-x)); }
__device__ __forceinline__ float softplusf(float x) {
    return fmaxf(x, 0.f) + __logf(1.f + __expf(-fabsf(x)));
}
__device__ __forceinline__ ushortT f2bf(float f) {
    unsigned u = __float_as_uint(f);
    u += 0x7FFFu + ((u >> 16) & 1u);
    return (ushortT)(u >> 16);
}
__device__ __forceinline__ float bf2f(ushortT u) {
    return __uint_as_float(((unsigned)u) << 16);
}
__device__ __forceinline__ void gload_lds16(const void* g, void* l) {
    __builtin_amdgcn_global_load_lds((const __attribute__((address_space(1))) void*)g,
                                     (__attribute__((address_space(3))) void*)l, 16, 0, 0);
}

// ---------------- lengths ----------------
__global__ void k_lengths(const int* __restrict__ mask, int* __restrict__ lengths) {
    int b = blockIdx.x;
    int s = 0;
    for (int t = threadIdx.x; t < LQ; t += 256) s += mask[b * LQ + t];
    __shared__ int sm[256];
    sm[threadIdx.x] = s;
    __syncthreads();
    for (int o = 128; o > 0; o >>= 1) {
        if (threadIdx.x < o) sm[threadIdx.x] += sm[threadIdx.x + o];
        __syncthreads();
    }
    if (threadIdx.x == 0) lengths[b] = sm[0];
}

// ---------------- fp32 -> bf16 converters ----------------
__global__ void k_cvt(const float* __restrict__ in, ushortT* __restrict__ out, int n) {
    int i = blockIdx.x * 256 + threadIdx.x;
    if (i < n) out[i] = f2bf(in[i]);
}
__global__ void k_cvtpad48(const float* __restrict__ xpw, ushortT* __restrict__ out) {
    int idx = blockIdx.x * 256 + threadIdx.x;  // 6*128*512
    int inst = idx >> 16, rem = idx & 65535;
    int row = rem >> 9, col = rem & 511;
    float v = (row < 48) ? xpw[((size_t)inst * 48 + row) * 512 + col] : 0.f;
    out[idx] = f2bf(v);
}

// ---------------- batched fused weight: wf[inst][m][d] ----------------
__global__ void k_wfuse(const float* __restrict__ opw, const float* __restrict__ mow,
                        ushortT* __restrict__ wf) {
    int idx = blockIdx.x * 256 + threadIdx.x;  // 6*131072
    int inst = idx >> 17, rem = idx & 131071;
    int m = rem >> 9, d = rem & 511;
    int i = inst >> 1, dir = inst & 1;
    const float* a = opw + (size_t)i * 131072 + dir * 256 + (size_t)m * 512;
    const float* bm = mow + (size_t)inst * 131072 + d;
    float s = 0.f;
    for (int c = 0; c < 256; c++) s = fmaf(a[c], bm[(size_t)c * 512], s);
    wf[idx] = f2bf(s);
}

// ---------------- dilated dw conv + BN + GELU -> c bf16 (all 3 scales) ----------------
__global__ void k_pool(const float* __restrict__ hid, const float* __restrict__ pw,
                       const float* __restrict__ pb, const float* __restrict__ bg,
                       const float* __restrict__ bb, const float* __restrict__ brm,
                       const float* __restrict__ brv, ushortT* __restrict__ cdst) {
    int gidx = blockIdx.x;  // 3*8192
    int isc = gidx >> 13;
    int idx = gidx & 8191;
    int l = idx & (LQ - 1);
    int b = idx >> 10;
    int ch = threadIdx.x;
    int dil = 1 << isc;
    int wci = isc * DSQ + ch;
    const float* xb = hid + (size_t)b * LQ * DMQ + isc * DSQ + ch;
    float w0 = pw[wci * 3 + 0], w1 = pw[wci * 3 + 1], w2 = pw[wci * 3 + 2];
    float acc = pb[wci];
    int lm = l - dil, lp = l + dil;
    if (lm >= 0) acc += xb[(size_t)lm * DMQ] * w0;
    acc += xb[(size_t)l * DMQ] * w1;
    if (lp < LQ) acc += xb[(size_t)lp * DMQ] * w2;
    float xn = (acc - brm[wci]) * rsqrtf(brv[wci] + 1e-5f) * bg[wci] + bb[wci];
    float y = 0.5f * xn * (1.0f + erff(xn * 0.70710678118654752f));
    cdst[(size_t)isc * 2097152 + (size_t)idx * DSQ + ch] = f2bf(y);
}

// ---------------- batched bf16 GEMM: C[z] (+)= A[z] * Bw[z]^T ----------------
// FLIPA: 0 none, 1 always, 2 when (z&1). CBF16: C bf16. GATE: C = C*silu(acc).
template <int FLIPA, int FLIPC, int BIAS, int ACC, int CBF16, int GATE>
__global__ __launch_bounds__(256) void gemm_bf16(const ushortT* __restrict__ A,
                                                 const ushortT* __restrict__ Bw,
                                                 void* __restrict__ Cv,
                                                 const float* __restrict__ bias, int N, int Kd,
                                                 int lda, int ldc,
                                                 const int* __restrict__ lengths, long sAz,
                                                 int zshiftA, long sBz, long sCz, int sBiasz) {
    __shared__ ushortT Als[128 * 64];
    __shared__ ushortT Bls[128 * 64];
    const int z = blockIdx.z;
    A += (size_t)(z >> zshiftA) * sAz;
    Bw += (size_t)z * sBz;
    float* Cf = (float*)Cv + (CBF16 ? 0 : (size_t)z * sCz);
    ushortT* Cb = (ushortT*)Cv + (CBF16 ? (size_t)z * sCz : 0);
    if (BIAS) bias += (size_t)z * sBiasz;

    const int tid = threadIdx.x;
    const int lane = tid & 63;
    const int wave = tid >> 6;
    const int wr = wave >> 1, wc = wave & 1;
    const int row0 = blockIdx.y * 128, col0 = blockIdx.x * 128;
    const bool doflip = (FLIPA == 1) || (FLIPA == 2 && (z & 1));
    int len = 0;
    if (FLIPA || FLIPC) len = lengths[row0 >> 10];

    const int srow = wave * 8 + (lane >> 3);  // + it*32
    const int scol = (lane & 7) * 8;

    f32x4 acc[4][4];
#pragma unroll
    for (int i = 0; i < 4; i++)
#pragma unroll
        for (int j = 0; j < 4; j++) acc[i][j] = (f32x4){0.f, 0.f, 0.f, 0.f};

    for (int k0 = 0; k0 < Kd; k0 += 64) {
        __syncthreads();
#pragma unroll
        for (int it = 0; it < 4; it++) {
            int row = it * 32 + srow;
            int grow = row0 + row;
            if (FLIPA) {
                if (doflip) {
                    int t = grow & (LQ - 1);
                    int ts = (t < len) ? (len - 1 - t) : t;
                    grow = (grow & ~(LQ - 1)) | ts;
                }
            }
            gload_lds16(A + (size_t)grow * lda + k0 + scol, &Als[it * 2048 + wave * 512]);
        }
#pragma unroll
        for (int it = 0; it < 4; it++) {
            int row = it * 32 + srow;
            gload_lds16(Bw + (size_t)(col0 + row) * Kd + k0 + scol,
                        &Bls[it * 2048 + wave * 512]);
        }
        __syncthreads();
#pragma unroll
        for (int ks = 0; ks < 2; ks++) {
            bf16x8 am[4], bv[4];
#pragma unroll
            for (int f = 0; f < 4; f++) {
                am[f] = *(const bf16x8*)&Als[(wr * 64 + f * 16 + (lane & 15)) * 64 + ks * 32 +
                                             (lane >> 4) * 8];
                bv[f] = *(const bf16x8*)&Bls[(wc * 64 + f * 16 + (lane & 15)) * 64 + ks * 32 +
                                             (lane >> 4) * 8];
            }
#pragma unroll
            for (int fm = 0; fm < 4; fm++)
#pragma unroll
                for (int fn = 0; fn < 4; fn++)
                    acc[fm][fn] = __builtin_amdgcn_mfma_f32_16x16x32_bf16(am[fm], bv[fn],
                                                                          acc[fm][fn], 0, 0, 0);
        }
    }
#pragma unroll
    for (int fm = 0; fm < 4; fm++) {
#pragma unroll
        for (int r = 0; r < 4; r++) {
            int grow = row0 + wr * 64 + fm * 16 + (lane >> 4) * 4 + r;
            if (FLIPC) {
                int t = grow & (LQ - 1);
                int ts = (t < len) ? (len - 1 - t) : t;
                grow = (grow & ~(LQ - 1)) | ts;
            }
#pragma unroll
            for (int fn = 0; fn < 4; fn++) {
                int col = col0 + wc * 64 + fn * 16 + (lane & 15);
                if (col < N) {
                    float v = acc[fm][fn][r];
                    if (CBF16) {
                        size_t p = (size_t)grow * ldc + col;
                        if (GATE) {
                            Cb[p] = f2bf(bf2f(Cb[p]) * v * sigf(v));
                        } else {
                            Cb[p] = f2bf(v);
                        }
                    } else {
                        float* cp = Cf + (size_t)grow * ldc + col;
                        if (ACC) v += *cp;
                        if (BIAS) v += bias[col];
                        *cp = v;
                    }
                }
            }
        }
    }
}

// ---------------- batched causal dw conv (K=4) + SiLU: rawx bf16 -> scanX bf16 ----------
__global__ void k_dwconv(const ushortT* __restrict__ rawx, const float* __restrict__ cw,
                         const float* __restrict__ cb, ushortT* __restrict__ sx) {
    int bt = blockIdx.x;  // 6*8192
    int inst = bt >> 13;
    int t = bt & (LQ - 1);
    int ch = threadIdx.x;
    const float* w = cw + (size_t)inst * 2048 + ch * 4;
    float acc = cb[inst * DIQ + ch];
    const ushortT* xp = rawx + (size_t)bt * DIQ + ch;
#pragma unroll
    for (int k = 0; k < 4; k++) {
        int ts = t - 3 + k;
        if (ts >= 0) acc += bf2f(xp[(ptrdiff_t)(ts - t) * DIQ]) * w[k];
    }
    sx[(size_t)bt * DIQ + ch] = f2bf(acc * sigf(acc));
}

// ======== chunked selective scan (float4 LDS, exp-structure fast path) ========
// pass 1: per-chunk local scan. grid 48*CCH*2 blocks of 256.
__global__ __launch_bounds__(256) void k_scan1(ushortT* __restrict__ scanX,
                                               const float* __restrict__ xdbl,
                                               const float* __restrict__ dt_w,
                                               const float* __restrict__ dt_b,
                                               const float* __restrict__ A_log,
                                               const float* __restrict__ Dpp,
                                               float* __restrict__ hbuf,
                                               float* __restrict__ sbuf) {
    int bid = blockIdx.x;
    int seq = bid >> 4;
    int r = bid & 15;
    int c = r >> 1, half = r & 1;
    int inst = seq >> 3;
    int ch = half * 256 + threadIdx.x;

    const float4* xd4 = (const float4*)(xdbl + ((size_t)seq * LQ + c * CT) * 48);
    ushortT* xp = scanX + ((size_t)seq * LQ + c * CT) * DIQ + ch;
    int wo = inst * DIQ + ch;
    float dtw[16], Ad[16];
#pragma unroll
    for (int rr = 0; rr < 16; rr++) dtw[rr] = dt_w[(size_t)wo * 16 + rr];
    float dtb = dt_b[wo];
    bool fastA = true;
#pragma unroll
    for (int n = 0; n < 16; n++) {
        Ad[n] = -__expf(A_log[(size_t)wo * 16 + n]);
        fastA = fastA && (fabsf(Ad[n] + (float)(n + 1)) < 1e-3f * (n + 1));
    }
    float Dd = Dpp[wo];
    float h[16];
#pragma unroll
    for (int n = 0; n < 16; n++) h[n] = 0.f;
    float S = 0.f;

    __shared__ float4 sd4[CT * 12];  // 24KB
    for (int u = threadIdx.x; u < CT * 12; u += 256) sd4[u] = xd4[u];
    __syncthreads();

    float xt = bf2f(xp[0]);
    if (fastA) {
        for (int tl = 0; tl < CT; tl++) {
            float xnext = (tl + 1 < CT) ? bf2f(xp[(size_t)(tl + 1) * DIQ]) : 0.f;
            const float4* s4 = sd4 + tl * 12;
            float4 q0 = s4[0], q1 = s4[1], q2 = s4[2], q3 = s4[3];
            float draw = dtb;
            draw = fmaf(q0.x, dtw[0], draw); draw = fmaf(q0.y, dtw[1], draw);
            draw = fmaf(q0.z, dtw[2], draw); draw = fmaf(q0.w, dtw[3], draw);
            draw = fmaf(q1.x, dtw[4], draw); draw = fmaf(q1.y, dtw[5], draw);
            draw = fmaf(q1.z, dtw[6], draw); draw = fmaf(q1.w, dtw[7], draw);
            draw = fmaf(q2.x, dtw[8], draw); draw = fmaf(q2.y, dtw[9], draw);
            draw = fmaf(q2.z, dtw[10], draw); draw = fmaf(q2.w, dtw[11], draw);
            draw = fmaf(q3.x, dtw[12], draw); draw = fmaf(q3.y, dtw[13], draw);
            draw = fmaf(q3.z, dtw[14], draw); draw = fmaf(q3.w, dtw[15], draw);
            float dt = softplusf(draw);
            S += dt;
            float e1 = __expf(-dt);
            float dtx = dt * xt;
            float bb[16], cc[16];
            *(float4*)&bb[0] = s4[4]; *(float4*)&bb[4] = s4[5];
            *(float4*)&bb[8] = s4[6]; *(float4*)&bb[12] = s4[7];
            *(float4*)&cc[0] = s4[8]; *(float4*)&cc[4] = s4[9];
            *(float4*)&cc[8] = s4[10]; *(float4*)&cc[12] = s4[11];
            float y = 0.f, e = 1.f;
#pragma unroll
            for (int n = 0; n < 16; n++) {
                e *= e1;
                h[n] = fmaf(h[n], e, dtx * bb[n]);
                y = fmaf(h[n], cc[n], y);
            }
            xp[(size_t)tl * DIQ] = f2bf(fmaf(xt, Dd, y));
            xt = xnext;
        }
    } else {
        for (int tl = 0; tl < CT; tl++) {
            float xnext = (tl + 1 < CT) ? bf2f(xp[(size_t)(tl + 1) * DIQ]) : 0.f;
            const float4* s4 = sd4 + tl * 12;
            float qq[16], bb[16], cc[16];
            *(float4*)&qq[0] = s4[0]; *(float4*)&qq[4] = s4[1];
            *(float4*)&qq[8] = s4[2]; *(float4*)&qq[12] = s4[3];
            *(float4*)&bb[0] = s4[4]; *(float4*)&bb[4] = s4[5];
            *(float4*)&bb[8] = s4[6]; *(float4*)&bb[12] = s4[7];
            *(float4*)&cc[0] = s4[8]; *(float4*)&cc[4] = s4[9];
            *(float4*)&cc[8] = s4[10]; *(float4*)&cc[12] = s4[11];
            float draw = dtb;
#pragma unroll
            for (int rr = 0; rr < 16; rr++) draw = fmaf(qq[rr], dtw[rr], draw);
            float dt = softplusf(draw);
            S += dt;
            float dtx = dt * xt;
            float y = 0.f;
#pragma unroll
            for (int n = 0; n < 16; n++) {
                float e = __expf(dt * Ad[n]);
                h[n] = fmaf(h[n], e, dtx * bb[n]);
                y = fmaf(h[n], cc[n], y);
            }
            xp[(size_t)tl * DIQ] = f2bf(fmaf(xt, Dd, y));
            xt = xnext;
        }
    }
    size_t hb = ((size_t)(seq * CCH + c) * 16) * DIQ + ch;
#pragma unroll
    for (int n = 0; n < 16; n++) hbuf[hb + (size_t)n * DIQ] = h[n];
    sbuf[(size_t)(seq * CCH + c) * DIQ + ch] = S;
}

// pass 2: sequential chunk-state combine. grid 48 blocks of 512.
__global__ __launch_bounds__(512) void k_scan2(const float* __restrict__ A_log,
                                               float* __restrict__ hbuf,
                                               const float* __restrict__ sbuf) {
    int seq = blockIdx.x;
    int inst = seq >> 3;
    int ch = threadIdx.x;
    int wo = inst * DIQ + ch;
    float Ad[16];
#pragma unroll
    for (int n = 0; n < 16; n++) Ad[n] = -__expf(A_log[(size_t)wo * 16 + n]);
    float hin[16];
#pragma unroll
    for (int n = 0; n < 16; n++) hin[n] = 0.f;
    for (int c = 0; c < CCH; c++) {
        size_t hb = ((size_t)(seq * CCH + c) * 16) * DIQ + ch;
        float Sc = sbuf[(size_t)(seq * CCH + c) * DIQ + ch];
        float he[16];
#pragma unroll
        for (int n = 0; n < 16; n++) he[n] = hbuf[hb + (size_t)n * DIQ];
#pragma unroll
        for (int n = 0; n < 16; n++) hbuf[hb + (size_t)n * DIQ] = hin[n];
#pragma unroll
        for (int n = 0; n < 16; n++) hin[n] = fmaf(hin[n], __expf(Ad[n] * Sc), he[n]);
    }
}

// pass 3: carried-state correction. grid 48*(CCH-1)*2 blocks of 256.
__global__ __launch_bounds__(256) void k_scan3(ushortT* __restrict__ scanX,
                                               const float* __restrict__ xdbl,
                                               const float* __restrict__ dt_w,
                                               const float* __restrict__ dt_b,
                                               const float* __restrict__ A_log,
                                               const float* __restrict__ hbuf) {
    int bid = blockIdx.x;
    int seq = bid / (2 * (CCH - 1));
    int r = bid % (2 * (CCH - 1));
    int c = 1 + (r >> 1), half = r & 1;
    int inst = seq >> 3;
    int ch = half * 256 + threadIdx.x;

    const float4* xd4 = (const float4*)(xdbl + ((size_t)seq * LQ + c * CT) * 48);
    ushortT* xp = scanX + ((size_t)seq * LQ + c * CT) * DIQ + ch;
    int wo = inst * DIQ + ch;
    float dtw[16], Ad[16];
#pragma unroll
    for (int rr = 0; rr < 16; rr++) dtw[rr] = dt_w[(size_t)wo * 16 + rr];
    float dtb = dt_b[wo];
    float amax = -1e30f;
    bool fastA = true;
#pragma unroll
    for (int n = 0; n < 16; n++) {
        Ad[n] = -__expf(A_log[(size_t)wo * 16 + n]);
        amax = fmaxf(amax, Ad[n]);
        fastA = fastA && (fabsf(Ad[n] + (float)(n + 1)) < 1e-3f * (n + 1));
    }
    float hin[16];
    size_t hb = ((size_t)(seq * CCH + c) * 16) * DIQ + ch;
#pragma unroll
    for (int n = 0; n < 16; n++) hin[n] = hbuf[hb + (size_t)n * DIQ];

    __shared__ float4 sd4[CT * 12];
    for (int u = threadIdx.x; u < CT * 12; u += 256) sd4[u] = xd4[u];
    __syncthreads();

    float S = 0.f;
    for (int tl = 0; tl < CT; tl++) {
        const float4* s4 = sd4 + tl * 12;
        float4 q0 = s4[0], q1 = s4[1], q2 = s4[2], q3 = s4[3];
        float draw = dtb;
        draw = fmaf(q0.x, dtw[0], draw); draw = fmaf(q0.y, dtw[1], draw);
        draw = fmaf(q0.z, dtw[2], draw); draw = fmaf(q0.w, dtw[3], draw);
        draw = fmaf(q1.x, dtw[4], draw); draw = fmaf(q1.y, dtw[5], draw);
        draw = fmaf(q1.z, dtw[6], draw); draw = fmaf(q1.w, dtw[7], draw);
        draw = fmaf(q2.x, dtw[8], draw); draw = fmaf(q2.y, dtw[9], draw);
        draw = fmaf(q2.z, dtw[10], draw); draw = fmaf(q2.w, dtw[11], draw);
        draw = fmaf(q3.x, dtw[12], draw); draw = fmaf(q3.y, dtw[13], draw);
        draw = fmaf(q3.z, dtw[14], draw); draw = fmaf(q3.w, dtw[15], draw);
        S += softplusf(draw);
        if (__all(amax * S < -30.f)) break;
        float cc[16];
        *(float4*)&cc[0] = s4[8]; *(float4*)&cc[4] = s4[9];
        *(float4*)&cc[8] = s4[10]; *(float4*)&cc[12] = s4[11];
        float corr = 0.f;
        if (fastA) {
            float eS = __expf(-S);
            float e = 1.f;
#pragma unroll
            for (int n = 0; n < 16; n++) {
                e *= eS;
                corr = fmaf(e * hin[n], cc[n], corr);
            }
        } else {
#pragma unroll
            for (int n = 0; n < 16; n++)
                corr = fmaf(__expf(Ad[n] * S) * hin[n], cc[n], corr);
        }
        xp[(size_t)tl * DIQ] = f2bf(bf2f(xp[(size_t)tl * DIQ]) + corr);
    }
}

// ---------------- 2-stage mean/max over L ----------------
__global__ void k_redu1(const float* __restrict__ o, float* __restrict__ psum,
                        float* __restrict__ pmax) {
    int b = blockIdx.x >> 5, tc = blockIdx.x & 31;
#pragma unroll
    for (int c3 = 0; c3 < 3; c3++) {
        int ch = c3 * 256 + threadIdx.x;
        const float* p = o + ((size_t)b * LQ + tc * 32) * DMQ + ch;
        float s = 0.f, m = -3.4e38f;
        for (int t = 0; t < 32; t++) {
            float v = p[(size_t)t * DMQ];
            s += v;
            m = fmaxf(m, v);
        }
        psum[(size_t)(b * 32 + tc) * DMQ + ch] = s;
        pmax[(size_t)(b * 32 + tc) * DMQ + ch] = m;
    }
}
__global__ void k_redu2(const float* __restrict__ psum, const float* __restrict__ pmax,
                        float* __restrict__ avg, float* __restrict__ mx) {
    int idx = blockIdx.x * 256 + threadIdx.x;
    int b = idx / DMQ, ch = idx % DMQ;
    float s = 0.f, m = -3.4e38f;
    for (int tc = 0; tc < 32; tc++) {
        s += psum[(size_t)(b * 32 + tc) * DMQ + ch];
        m = fmaxf(m, pmax[(size_t)(b * 32 + tc) * DMQ + ch]);
    }
    avg[idx] = s * (1.f / LQ);
    mx[idx] = m;
}

__global__ void k_att1(const float* __restrict__ avg, const float* __restrict__ mx,
                       const float* __restrict__ w1, float* __restrict__ hs) {
    int idx = blockIdx.x * 256 + threadIdx.x;
    int b = idx / 384, j = idx % 384;
    const float* w = w1 + (size_t)j * DMQ;
    const float* a = avg + (size_t)b * DMQ;
    const float* m2 = mx + (size_t)b * DMQ;
    float s1 = 0.f, s2 = 0.f;
    for (int k = 0; k < DMQ; k++) {
        s1 = fmaf(a[k], w[k], s1);
        s2 = fmaf(m2[k], w[k], s2);
    }
    hs[idx] = fmaxf(s1, 0.f) + fmaxf(s2, 0.f);
}

__global__ void k_att2(const float* __restrict__ hs, const float* __restrict__ w2,
                       float* __restrict__ att) {
    int idx = blockIdx.x * 256 + threadIdx.x;
    int b = idx / DMQ, n = idx % DMQ;
    const float* w = w2 + (size_t)n * 384;
    const float* h = hs + (size_t)b * 384;
    float s = 0.f;
    for (int k = 0; k < 384; k++) s = fmaf(h[k], w[k], s);
    att[idx] = sigf(s);
}

__global__ void k_scaleb(const float* __restrict__ o, const float* __restrict__ att,
                         ushortT* __restrict__ ob) {
    size_t idx = (size_t)blockIdx.x * 256 + threadIdx.x;
    int ch = (int)(idx % DMQ);
    int b = (int)(idx / ((size_t)LQ * DMQ));
    ob[idx] = f2bf(o[idx] * att[b * DMQ + ch]);
}

__global__ void k_diag(float* __restrict__ o, float v) {
    if (blockIdx.x == 0 && threadIdx.x == 0) o[0] = v;
}

extern "C" void kernel_launch(void* const* d_in, const int* in_sizes, int n_in, void* d_out,
                              int out_size, void* d_ws, size_t ws_size, hipStream_t stream) {
    (void)in_sizes; (void)n_in; (void)out_size;
    const float* hid = (const float*)d_in[0];
    const int* mask = (const int*)d_in[1];
    const float* pool_w = (const float*)d_in[2];
    const float* pool_b = (const float*)d_in[3];
    const float* bn_g = (const float*)d_in[4];
    const float* bn_b = (const float*)d_in[5];
    const float* bn_rm = (const float*)d_in[6];
    const float* bn_rv = (const float*)d_in[7];
    const float* ipw = (const float*)d_in[8];
    const float* cw = (const float*)d_in[9];
    const float* cb = (const float*)d_in[10];
    const float* xpw = (const float*)d_in[11];
    const float* dtw = (const float*)d_in[12];
    const float* dtb = (const float*)d_in[13];
    const float* alog = (const float*)d_in[14];
    const float* Dpp = (const float*)d_in[15];
    const float* mow = (const float*)d_in[16];
    const float* opw = (const float*)d_in[17];
    const float* opb = (const float*)d_in[18];
    const float* caw1 = (const float*)d_in[19];
    const float* caw2 = (const float*)d_in[20];
    const float* fusw = (const float*)d_in[21];
    const float* fusb = (const float*)d_in[22];
    float* out = (float*)d_out;

    // workspace layout (float-equivalent offsets)
    const size_t O_IPWB = 32768;
    const size_t O_XPWB = 819200;
    const size_t O_FUSWB = 1015808;
    const size_t O_WTMPB = 1310720;
    const size_t O_XDBL = 1703936;
    const size_t O_CBASE = 4063232;
    const size_t O_RAWX = 7208960;
    const size_t O_SCANX = 19791872;
    const size_t TOTAL_F = 32374784;  // 129.5 MB
    if (ws_size < TOTAL_F * 4) {
        k_diag<<<1, 64, 0, stream>>>(out, (float)(ws_size >> 20));
        return;
    }

    float* ws = (float*)d_ws;
    int* lengths = (int*)ws;
    float* avg = ws + 1024;
    float* mxp = avg + 6144;
    float* hs = mxp + 6144;
    float* att = hs + 3072;
    ushortT* ipwb = (ushortT*)(ws + O_IPWB);
    ushortT* xpwb = (ushortT*)(ws + O_XPWB);
    ushortT* fuswb = (ushortT*)(ws + O_FUSWB);
    ushortT* wtmpb = (ushortT*)(ws + O_WTMPB);
    float* xdbl = ws + O_XDBL;
    ushortT* cbase = (ushortT*)(ws + O_CBASE);
    ushortT* rawx = (ushortT*)(ws + O_RAWX);
    ushortT* scanX = (ushortT*)(ws + O_SCANX);
    // overlays
    float* hbuf = ws + O_RAWX;   // rawx dead after dwconv
    float* sbuf = hbuf + 3145728;
    float* psum = (float*)cbase; // cbase dead after z-GEMM
    float* pmax = psum + 196608;
    ushortT* outb = scanX;       // scanX dead after mo/op GEMMs

    // ---- weight prep ----
    k_lengths<<<dim3(8), dim3(256), 0, stream>>>(mask, lengths);
    k_cvt<<<dim3(6144), dim3(256), 0, stream>>>(ipw, ipwb, 6 * 1024 * 256);
    k_cvt<<<dim3(2304), dim3(256), 0, stream>>>(fusw, fuswb, 768 * 768);
    k_cvtpad48<<<dim3(1536), dim3(256), 0, stream>>>(xpw, xpwb);
    k_wfuse<<<dim3(3072), dim3(256), 0, stream>>>(opw, mow, wtmpb);

    // ---- pool (all scales) ----
    k_pool<<<dim3(3 * 8192), dim3(256), 0, stream>>>(hid, pool_w, pool_b, bn_g, bn_b, bn_rm,
                                                     bn_rv, cbase);

    // ---- in_proj x-half (all 6 insts), flip odd insts ----
    gemm_bf16<2, 0, 0, 0, 1, 0><<<dim3(4, 64, 6), 256, 0, stream>>>(
        cbase, ipwb, rawx, nullptr, 512, 256, 256, 512, lengths, 2097152, 1, 262144, 4194304, 0);

    // ---- dwconv + SiLU (all insts) ----
    k_dwconv<<<dim3(6 * 8192), dim3(512), 0, stream>>>(rawx, cw, cb, scanX);

    // ---- x_proj (all insts) ----
    gemm_bf16<0, 0, 0, 0, 0, 0><<<dim3(1, 64, 6), 256, 0, stream>>>(
        scanX, xpwb, xdbl, nullptr, 48, 512, 512, 48, lengths, 4194304, 0, 65536, 393216, 0);

    // ---- chunked selective scan (in place on scanX) ----
    k_scan1<<<dim3(48 * CCH * 2), dim3(256), 0, stream>>>(scanX, xdbl, dtw, dtb, alog, Dpp,
                                                          hbuf, sbuf);
    k_scan2<<<dim3(48), dim3(512), 0, stream>>>(alog, hbuf, sbuf);
    k_scan3<<<dim3(48 * (CCH - 1) * 2), dim3(256), 0, stream>>>(scanX, xdbl, dtw, dtb, alog,
                                                                hbuf);

    // ---- in_proj z-half (all insts) + fused gate epilogue into scanX ----
    gemm_bf16<2, 0, 0, 0, 1, 1><<<dim3(4, 64, 6), 256, 0, stream>>>(
        cbase, ipwb + 131072, scanX, nullptr, 512, 256, 256, 512, lengths, 2097152, 1, 262144,
        4194304, 0);

    // ---- fused mo+op: dir0 write, dir1 accumulate+bias+flip ----
    gemm_bf16<0, 0, 0, 0, 0, 0><<<dim3(2, 64, 3), 256, 0, stream>>>(
        scanX, wtmpb, out, nullptr, 256, 512, 512, DMQ, lengths, 8388608, 0, 262144, 256, 0);
    gemm_bf16<0, 1, 1, 1, 0, 0><<<dim3(2, 64, 3), 256, 0, stream>>>(
        scanX + 4194304, wtmpb + 131072, out, opb, 256, 512, 512, DMQ, lengths, 8388608, 0,
        262144, 256, 256);

    // ---- attention pooling + final projection ----
    k_redu1<<<dim3(256), dim3(256), 0, stream>>>(out, psum, pmax);
    k_redu2<<<dim3(24), dim3(256), 0, stream>>>(psum, pmax, avg, mxp);
    k_att1<<<dim3(12), dim3(256), 0, stream>>>(avg, mxp, caw1, hs);
    k_att2<<<dim3(24), dim3(256), 0, stream>>>(hs, caw2, att);
    k_scaleb<<<dim3(24576), dim3(256), 0, stream>>>(out, att, outb);
    gemm_bf16<0, 0, 1, 0, 0, 0><<<dim3(6, 64, 1), 256, 0, stream>>>(
        outb, fuswb, out, fusb, DMQ, DMQ, DMQ, DMQ, lengths, 0, 0, 0, 0, 0);
}

// Round 8
// 488.666 us; speedup vs baseline: 6.0692x; 1.2243x over previous
//
#include <hip/hip_runtime.h>
#include <cstddef>
#include <cstdint>

#define LQ 1024
#define DMQ 768
#define DSQ 256
#define DIQ 512
#define CCH 8
#define CT (LQ / CCH)

typedef unsigned short ushortT;
using f32x4 = __attribute__((ext_vector_type(4))) float;
using bf16x8 = __attribute__((ext_vector_type(8))) short;
using u16x8 = __attribute__((ext_vector_type(8))) unsigned short;

__device__ __forceinline__ float sigf(float x) { return 1.f / (1.f + __expf(-x)); }
__device__ __forceinline__ float softplusf(float x) {
    return fmaxf(x, 0.f) + __logf(1.f + __expf(-fabsf(x)));
}
__device__ __forceinline__ ushortT f2bf(float f) {
    unsigned u = __float_as_uint(f);
    u += 0x7FFFu + ((u >> 16) & 1u);
    return (ushortT)(u >> 16);
}
__device__ __forceinline__ float bf2f(ushortT u) {
    return __uint_as_float(((unsigned)u) << 16);
}
__device__ __forceinline__ void gload_lds16(const void* g, void* l) {
    __builtin_amdgcn_global_load_lds((const __attribute__((address_space(1))) void*)g,
                                     (__attribute__((address_space(3))) void*)l, 16, 0, 0);
}

// ---------------- lengths ----------------
__global__ void k_lengths(const int* __restrict__ mask, int* __restrict__ lengths) {
    int b = blockIdx.x;
    int s = 0;
    for (int t = threadIdx.x; t < LQ; t += 256) s += mask[b * LQ + t];
    __shared__ int sm[256];
    sm[threadIdx.x] = s;
    __syncthreads();
    for (int o = 128; o > 0; o >>= 1) {
        if (threadIdx.x < o) sm[threadIdx.x] += sm[threadIdx.x + o];
        __syncthreads();
    }
    if (threadIdx.x == 0) lengths[b] = sm[0];
}

// ---------------- fp32 -> bf16 converters ----------------
__global__ void k_cvt(const float* __restrict__ in, ushortT* __restrict__ out, int n) {
    int i = blockIdx.x * 256 + threadIdx.x;
    if (i < n) out[i] = f2bf(in[i]);
}
__global__ void k_cvtpad48(const float* __restrict__ xpw, ushortT* __restrict__ out) {
    int idx = blockIdx.x * 256 + threadIdx.x;  // 6*128*512
    int inst = idx >> 16, rem = idx & 65535;
    int row = rem >> 9, col = rem & 511;
    float v = (row < 48) ? xpw[((size_t)inst * 48 + row) * 512 + col] : 0.f;
    out[idx] = f2bf(v);
}

// ---------------- batched fused weight: wf[inst][m][d] (4 d per thread) -------------
__global__ void k_wfuse(const float* __restrict__ opw, const float* __restrict__ mow,
                        ushortT* __restrict__ wf) {
    int idx = blockIdx.x * 256 + threadIdx.x;  // 196608 = 6*256*128
    int inst = idx >> 15;
    int rem = idx & 32767;
    int m = rem >> 7;
    int d0 = (rem & 127) * 4;
    int i = inst >> 1, dir = inst & 1;
    const float* a = opw + (size_t)i * 131072 + dir * 256 + (size_t)m * 512;
    const float* bm = mow + (size_t)inst * 131072 + d0;
    float s0 = 0.f, s1 = 0.f, s2 = 0.f, s3 = 0.f;
    for (int c = 0; c < 256; c++) {
        float av = a[c];
        float4 bv = *(const float4*)(bm + (size_t)c * 512);
        s0 = fmaf(av, bv.x, s0);
        s1 = fmaf(av, bv.y, s1);
        s2 = fmaf(av, bv.z, s2);
        s3 = fmaf(av, bv.w, s3);
    }
    ushort4 r = {f2bf(s0), f2bf(s1), f2bf(s2), f2bf(s3)};
    *(ushort4*)(wf + (size_t)inst * 131072 + (size_t)m * 512 + d0) = r;
}

// ------- dilated dw conv + BN + GELU -> c bf16 (all 3 scales, float4/thread) -------
__global__ __launch_bounds__(64) void k_pool(const float* __restrict__ hid,
                                             const float* __restrict__ pw,
                                             const float* __restrict__ pb,
                                             const float* __restrict__ bg,
                                             const float* __restrict__ bb,
                                             const float* __restrict__ brm,
                                             const float* __restrict__ brv,
                                             ushortT* __restrict__ cdst) {
    int gidx = blockIdx.x;  // 3*8192
    int isc = gidx >> 13;
    int idx = gidx & 8191;
    int l = idx & (LQ - 1);
    int b = idx >> 10;
    int ch0 = threadIdx.x * 4;
    int dil = 1 << isc;
    int wci0 = isc * DSQ + ch0;
    const float* xb = hid + (size_t)b * LQ * DMQ + isc * DSQ + ch0;
    float wv[12];
    *(float4*)&wv[0] = *(const float4*)(pw + (size_t)wci0 * 3);
    *(float4*)&wv[4] = *(const float4*)(pw + (size_t)wci0 * 3 + 4);
    *(float4*)&wv[8] = *(const float4*)(pw + (size_t)wci0 * 3 + 8);
    float pbv[4], bgv[4], bbv[4], rmv[4], rvv[4];
    *(float4*)pbv = *(const float4*)(pb + wci0);
    *(float4*)bgv = *(const float4*)(bg + wci0);
    *(float4*)bbv = *(const float4*)(bb + wci0);
    *(float4*)rmv = *(const float4*)(brm + wci0);
    *(float4*)rvv = *(const float4*)(brv + wci0);
    float xm[4] = {0.f, 0.f, 0.f, 0.f}, xc[4], xp[4] = {0.f, 0.f, 0.f, 0.f};
    int lm = l - dil, lp = l + dil;
    if (lm >= 0) *(float4*)xm = *(const float4*)(xb + (size_t)lm * DMQ);
    *(float4*)xc = *(const float4*)(xb + (size_t)l * DMQ);
    if (lp < LQ) *(float4*)xp = *(const float4*)(xb + (size_t)lp * DMQ);
    ushort4 o;
#pragma unroll
    for (int j = 0; j < 4; j++) {
        float acc = pbv[j];
        acc = fmaf(wv[j * 3 + 0], xm[j], acc);
        acc = fmaf(wv[j * 3 + 1], xc[j], acc);
        acc = fmaf(wv[j * 3 + 2], xp[j], acc);
        float xn = (acc - rmv[j]) * rsqrtf(rvv[j] + 1e-5f) * bgv[j] + bbv[j];
        float y = 0.5f * xn * (1.0f + erff(xn * 0.70710678118654752f));
        ((ushortT*)&o)[j] = f2bf(y);
    }
    *(ushort4*)(cdst + (size_t)isc * 2097152 + (size_t)idx * DSQ + ch0) = o;
}

// ---------------- batched bf16 GEMM: C[z] (+)= A[z] * Bw[z]^T ----------------
// FLIPA: 0 none, 1 always, 2 when (z&1). CBF16: C bf16. GATE: C = C*silu(acc).
template <int FLIPA, int FLIPC, int BIAS, int ACC, int CBF16, int GATE>
__global__ __launch_bounds__(256) void gemm_bf16(const ushortT* __restrict__ A,
                                                 const ushortT* __restrict__ Bw,
                                                 void* __restrict__ Cv,
                                                 const float* __restrict__ bias, int N, int Kd,
                                                 int lda, int ldc,
                                                 const int* __restrict__ lengths, long sAz,
                                                 int zshiftA, long sBz, long sCz, int sBiasz) {
    __shared__ ushortT Als[128 * 64];
    __shared__ ushortT Bls[128 * 64];
    const int z = blockIdx.z;
    A += (size_t)(z >> zshiftA) * sAz;
    Bw += (size_t)z * sBz;
    float* Cf = (float*)Cv + (CBF16 ? 0 : (size_t)z * sCz);
    ushortT* Cb = (ushortT*)Cv + (CBF16 ? (size_t)z * sCz : 0);
    if (BIAS) bias += (size_t)z * sBiasz;

    const int tid = threadIdx.x;
    const int lane = tid & 63;
    const int wave = tid >> 6;
    const int wr = wave >> 1, wc = wave & 1;
    const int row0 = blockIdx.y * 128, col0 = blockIdx.x * 128;
    const bool doflip = (FLIPA == 1) || (FLIPA == 2 && (z & 1));
    int len = 0;
    if (FLIPA || FLIPC) len = lengths[row0 >> 10];

    const int srow = wave * 8 + (lane >> 3);  // + it*32
    const int scol = (lane & 7) * 8;

    f32x4 acc[4][4];
#pragma unroll
    for (int i = 0; i < 4; i++)
#pragma unroll
        for (int j = 0; j < 4; j++) acc[i][j] = (f32x4){0.f, 0.f, 0.f, 0.f};

    for (int k0 = 0; k0 < Kd; k0 += 64) {
        __syncthreads();
#pragma unroll
        for (int it = 0; it < 4; it++) {
            int row = it * 32 + srow;
            int grow = row0 + row;
            if (FLIPA) {
                if (doflip) {
                    int t = grow & (LQ - 1);
                    int ts = (t < len) ? (len - 1 - t) : t;
                    grow = (grow & ~(LQ - 1)) | ts;
                }
            }
            gload_lds16(A + (size_t)grow * lda + k0 + scol, &Als[it * 2048 + wave * 512]);
        }
#pragma unroll
        for (int it = 0; it < 4; it++) {
            int row = it * 32 + srow;
            gload_lds16(Bw + (size_t)(col0 + row) * Kd + k0 + scol,
                        &Bls[it * 2048 + wave * 512]);
        }
        __syncthreads();
#pragma unroll
        for (int ks = 0; ks < 2; ks++) {
            bf16x8 am[4], bv[4];
#pragma unroll
            for (int f = 0; f < 4; f++) {
                am[f] = *(const bf16x8*)&Als[(wr * 64 + f * 16 + (lane & 15)) * 64 + ks * 32 +
                                             (lane >> 4) * 8];
                bv[f] = *(const bf16x8*)&Bls[(wc * 64 + f * 16 + (lane & 15)) * 64 + ks * 32 +
                                             (lane >> 4) * 8];
            }
#pragma unroll
            for (int fm = 0; fm < 4; fm++)
#pragma unroll
                for (int fn = 0; fn < 4; fn++)
                    acc[fm][fn] = __builtin_amdgcn_mfma_f32_16x16x32_bf16(am[fm], bv[fn],
                                                                          acc[fm][fn], 0, 0, 0);
        }
    }
#pragma unroll
    for (int fm = 0; fm < 4; fm++) {
#pragma unroll
        for (int r = 0; r < 4; r++) {
            int grow = row0 + wr * 64 + fm * 16 + (lane >> 4) * 4 + r;
            if (FLIPC) {
                int t = grow & (LQ - 1);
                int ts = (t < len) ? (len - 1 - t) : t;
                grow = (grow & ~(LQ - 1)) | ts;
            }
#pragma unroll
            for (int fn = 0; fn < 4; fn++) {
                int col = col0 + wc * 64 + fn * 16 + (lane & 15);
                if (col < N) {
                    float v = acc[fm][fn][r];
                    if (CBF16) {
                        size_t p = (size_t)grow * ldc + col;
                        if (GATE) {
                            Cb[p] = f2bf(bf2f(Cb[p]) * v * sigf(v));
                        } else {
                            Cb[p] = f2bf(v);
                        }
                    } else {
                        float* cp = Cf + (size_t)grow * ldc + col;
                        if (ACC) v += *cp;
                        if (BIAS) v += bias[col];
                        *cp = v;
                    }
                }
            }
        }
    }
}

// ---- causal dw conv (K=4) + SiLU: register-window, 8ch x 32t per thread ----
// grid 6*8*8=384 (inst,b,tchunk), block 256: (tid&63)=ch-group of 8, (tid>>6)=32-t slice
__global__ __launch_bounds__(256) void k_dwconv(const ushortT* __restrict__ rawx,
                                                const float* __restrict__ cw,
                                                const float* __restrict__ cb,
                                                ushortT* __restrict__ sx) {
    int blk = blockIdx.x;
    int tc = blk & 7;
    int sb = blk >> 3;        // inst*8+b
    int inst = sb >> 3;
    int cg = threadIdx.x & 63;
    int sub = threadIdx.x >> 6;
    int ch0 = cg * 8;
    int t0 = tc * 128 + sub * 32;
    const ushortT* base = rawx + (size_t)sb * LQ * DIQ + ch0;
    ushortT* obase = sx + (size_t)sb * LQ * DIQ + ch0;

    float w[8][4], bs[8];
#pragma unroll
    for (int j = 0; j < 8; j++) {
        float4 wv = *(const float4*)(cw + (size_t)inst * 2048 + (size_t)(ch0 + j) * 4);
        w[j][0] = wv.x; w[j][1] = wv.y; w[j][2] = wv.z; w[j][3] = wv.w;
        bs[j] = cb[inst * DIQ + ch0 + j];
    }
    float x3[8], x2[8], x1[8];
#pragma unroll
    for (int j = 0; j < 8; j++) { x3[j] = 0.f; x2[j] = 0.f; x1[j] = 0.f; }
    if (t0 >= 3) {
        u16x8 v3 = *(const u16x8*)(base + (size_t)(t0 - 3) * DIQ);
        u16x8 v2 = *(const u16x8*)(base + (size_t)(t0 - 2) * DIQ);
        u16x8 v1 = *(const u16x8*)(base + (size_t)(t0 - 1) * DIQ);
#pragma unroll
        for (int j = 0; j < 8; j++) {
            x3[j] = bf2f(v3[j]); x2[j] = bf2f(v2[j]); x1[j] = bf2f(v1[j]);
        }
    }
#pragma unroll 4
    for (int t = t0; t < t0 + 32; t++) {
        u16x8 v = *(const u16x8*)(base + (size_t)t * DIQ);
        float xc[8];
#pragma unroll
        for (int j = 0; j < 8; j++) xc[j] = bf2f(v[j]);
        u16x8 o;
#pragma unroll
        for (int j = 0; j < 8; j++) {
            float acc = bs[j];
            acc = fmaf(w[j][0], x3[j], acc);
            acc = fmaf(w[j][1], x2[j], acc);
            acc = fmaf(w[j][2], x1[j], acc);
            acc = fmaf(w[j][3], xc[j], acc);
            o[j] = f2bf(acc * sigf(acc));
        }
        *(u16x8*)(obase + (size_t)t * DIQ) = o;
#pragma unroll
        for (int j = 0; j < 8; j++) { x3[j] = x2[j]; x2[j] = x1[j]; x1[j] = xc[j]; }
    }
}

// ======== chunked selective scan (float4 LDS, exp-structure fast path) ========
__global__ __launch_bounds__(256) void k_scan1(ushortT* __restrict__ scanX,
                                               const float* __restrict__ xdbl,
                                               const float* __restrict__ dt_w,
                                               const float* __restrict__ dt_b,
                                               const float* __restrict__ A_log,
                                               const float* __restrict__ Dpp,
                                               float* __restrict__ hbuf,
                                               float* __restrict__ sbuf) {
    int bid = blockIdx.x;
    int seq = bid >> 4;
    int r = bid & 15;
    int c = r >> 1, half = r & 1;
    int inst = seq >> 3;
    int ch = half * 256 + threadIdx.x;

    const float4* xd4 = (const float4*)(xdbl + ((size_t)seq * LQ + c * CT) * 48);
    ushortT* xp = scanX + ((size_t)seq * LQ + c * CT) * DIQ + ch;
    int wo = inst * DIQ + ch;
    float dtw[16], Ad[16];
#pragma unroll
    for (int rr = 0; rr < 16; rr++) dtw[rr] = dt_w[(size_t)wo * 16 + rr];
    float dtb = dt_b[wo];
    bool fastA = true;
#pragma unroll
    for (int n = 0; n < 16; n++) {
        Ad[n] = -__expf(A_log[(size_t)wo * 16 + n]);
        fastA = fastA && (fabsf(Ad[n] + (float)(n + 1)) < 1e-3f * (n + 1));
    }
    float Dd = Dpp[wo];
    float h[16];
#pragma unroll
    for (int n = 0; n < 16; n++) h[n] = 0.f;
    float S = 0.f;

    __shared__ float4 sd4[CT * 12];  // 24KB
    for (int u = threadIdx.x; u < CT * 12; u += 256) sd4[u] = xd4[u];
    __syncthreads();

    float xt = bf2f(xp[0]);
    if (fastA) {
        for (int tl = 0; tl < CT; tl++) {
            float xnext = (tl + 1 < CT) ? bf2f(xp[(size_t)(tl + 1) * DIQ]) : 0.f;
            const float4* s4 = sd4 + tl * 12;
            float4 q0 = s4[0], q1 = s4[1], q2 = s4[2], q3 = s4[3];
            float draw = dtb;
            draw = fmaf(q0.x, dtw[0], draw); draw = fmaf(q0.y, dtw[1], draw);
            draw = fmaf(q0.z, dtw[2], draw); draw = fmaf(q0.w, dtw[3], draw);
            draw = fmaf(q1.x, dtw[4], draw); draw = fmaf(q1.y, dtw[5], draw);
            draw = fmaf(q1.z, dtw[6], draw); draw = fmaf(q1.w, dtw[7], draw);
            draw = fmaf(q2.x, dtw[8], draw); draw = fmaf(q2.y, dtw[9], draw);
            draw = fmaf(q2.z, dtw[10], draw); draw = fmaf(q2.w, dtw[11], draw);
            draw = fmaf(q3.x, dtw[12], draw); draw = fmaf(q3.y, dtw[13], draw);
            draw = fmaf(q3.z, dtw[14], draw); draw = fmaf(q3.w, dtw[15], draw);
            float dt = softplusf(draw);
            S += dt;
            float e1 = __expf(-dt);
            float dtx = dt * xt;
            float bb[16], cc[16];
            *(float4*)&bb[0] = s4[4]; *(float4*)&bb[4] = s4[5];
            *(float4*)&bb[8] = s4[6]; *(float4*)&bb[12] = s4[7];
            *(float4*)&cc[0] = s4[8]; *(float4*)&cc[4] = s4[9];
            *(float4*)&cc[8] = s4[10]; *(float4*)&cc[12] = s4[11];
            float y = 0.f, e = 1.f;
#pragma unroll
            for (int n = 0; n < 16; n++) {
                e *= e1;
                h[n] = fmaf(h[n], e, dtx * bb[n]);
                y = fmaf(h[n], cc[n], y);
            }
            xp[(size_t)tl * DIQ] = f2bf(fmaf(xt, Dd, y));
            xt = xnext;
        }
    } else {
        for (int tl = 0; tl < CT; tl++) {
            float xnext = (tl + 1 < CT) ? bf2f(xp[(size_t)(tl + 1) * DIQ]) : 0.f;
            const float4* s4 = sd4 + tl * 12;
            float qq[16], bb[16], cc[16];
            *(float4*)&qq[0] = s4[0]; *(float4*)&qq[4] = s4[1];
            *(float4*)&qq[8] = s4[2]; *(float4*)&qq[12] = s4[3];
            *(float4*)&bb[0] = s4[4]; *(float4*)&bb[4] = s4[5];
            *(float4*)&bb[8] = s4[6]; *(float4*)&bb[12] = s4[7];
            *(float4*)&cc[0] = s4[8]; *(float4*)&cc[4] = s4[9];
            *(float4*)&cc[8] = s4[10]; *(float4*)&cc[12] = s4[11];
            float draw = dtb;
#pragma unroll
            for (int rr = 0; rr < 16; rr++) draw = fmaf(qq[rr], dtw[rr], draw);
            float dt = softplusf(draw);
            S += dt;
            float dtx = dt * xt;
            float y = 0.f;
#pragma unroll
            for (int n = 0; n < 16; n++) {
                float e = __expf(dt * Ad[n]);
                h[n] = fmaf(h[n], e, dtx * bb[n]);
                y = fmaf(h[n], cc[n], y);
            }
            xp[(size_t)tl * DIQ] = f2bf(fmaf(xt, Dd, y));
            xt = xnext;
        }
    }
    size_t hb = ((size_t)(seq * CCH + c) * 16) * DIQ + ch;
#pragma unroll
    for (int n = 0; n < 16; n++) hbuf[hb + (size_t)n * DIQ] = h[n];
    sbuf[(size_t)(seq * CCH + c) * DIQ + ch] = S;
}

__global__ __launch_bounds__(512) void k_scan2(const float* __restrict__ A_log,
                                               float* __restrict__ hbuf,
                                               const float* __restrict__ sbuf) {
    int seq = blockIdx.x;
    int inst = seq >> 3;
    int ch = threadIdx.x;
    int wo = inst * DIQ + ch;
    float Ad[16];
#pragma unroll
    for (int n = 0; n < 16; n++) Ad[n] = -__expf(A_log[(size_t)wo * 16 + n]);
    float hin[16];
#pragma unroll
    for (int n = 0; n < 16; n++) hin[n] = 0.f;
    for (int c = 0; c < CCH; c++) {
        size_t hb = ((size_t)(seq * CCH + c) * 16) * DIQ + ch;
        float Sc = sbuf[(size_t)(seq * CCH + c) * DIQ + ch];
        float he[16];
#pragma unroll
        for (int n = 0; n < 16; n++) he[n] = hbuf[hb + (size_t)n * DIQ];
#pragma unroll
        for (int n = 0; n < 16; n++) hbuf[hb + (size_t)n * DIQ] = hin[n];
#pragma unroll
        for (int n = 0; n < 16; n++) hin[n] = fmaf(hin[n], __expf(Ad[n] * Sc), he[n]);
    }
}

__global__ __launch_bounds__(256) void k_scan3(ushortT* __restrict__ scanX,
                                               const float* __restrict__ xdbl,
                                               const float* __restrict__ dt_w,
                                               const float* __restrict__ dt_b,
                                               const float* __restrict__ A_log,
                                               const float* __restrict__ hbuf) {
    int bid = blockIdx.x;
    int seq = bid / (2 * (CCH - 1));
    int r = bid % (2 * (CCH - 1));
    int c = 1 + (r >> 1), half = r & 1;
    int inst = seq >> 3;
    int ch = half * 256 + threadIdx.x;

    const float4* xd4 = (const float4*)(xdbl + ((size_t)seq * LQ + c * CT) * 48);
    ushortT* xp = scanX + ((size_t)seq * LQ + c * CT) * DIQ + ch;
    int wo = inst * DIQ + ch;
    float dtw[16], Ad[16];
#pragma unroll
    for (int rr = 0; rr < 16; rr++) dtw[rr] = dt_w[(size_t)wo * 16 + rr];
    float dtb = dt_b[wo];
    float amax = -1e30f;
    bool fastA = true;
#pragma unroll
    for (int n = 0; n < 16; n++) {
        Ad[n] = -__expf(A_log[(size_t)wo * 16 + n]);
        amax = fmaxf(amax, Ad[n]);
        fastA = fastA && (fabsf(Ad[n] + (float)(n + 1)) < 1e-3f * (n + 1));
    }
    float hin[16];
    size_t hb = ((size_t)(seq * CCH + c) * 16) * DIQ + ch;
#pragma unroll
    for (int n = 0; n < 16; n++) hin[n] = hbuf[hb + (size_t)n * DIQ];

    __shared__ float4 sd4[CT * 12];
    for (int u = threadIdx.x; u < CT * 12; u += 256) sd4[u] = xd4[u];
    __syncthreads();

    float S = 0.f;
    for (int tl = 0; tl < CT; tl++) {
        const float4* s4 = sd4 + tl * 12;
        float4 q0 = s4[0], q1 = s4[1], q2 = s4[2], q3 = s4[3];
        float draw = dtb;
        draw = fmaf(q0.x, dtw[0], draw); draw = fmaf(q0.y, dtw[1], draw);
        draw = fmaf(q0.z, dtw[2], draw); draw = fmaf(q0.w, dtw[3], draw);
        draw = fmaf(q1.x, dtw[4], draw); draw = fmaf(q1.y, dtw[5], draw);
        draw = fmaf(q1.z, dtw[6], draw); draw = fmaf(q1.w, dtw[7], draw);
        draw = fmaf(q2.x, dtw[8], draw); draw = fmaf(q2.y, dtw[9], draw);
        draw = fmaf(q2.z, dtw[10], draw); draw = fmaf(q2.w, dtw[11], draw);
        draw = fmaf(q3.x, dtw[12], draw); draw = fmaf(q3.y, dtw[13], draw);
        draw = fmaf(q3.z, dtw[14], draw); draw = fmaf(q3.w, dtw[15], draw);
        S += softplusf(draw);
        if (__all(amax * S < -30.f)) break;
        float cc[16];
        *(float4*)&cc[0] = s4[8]; *(float4*)&cc[4] = s4[9];
        *(float4*)&cc[8] = s4[10]; *(float4*)&cc[12] = s4[11];
        float corr = 0.f;
        if (fastA) {
            float eS = __expf(-S);
            float e = 1.f;
#pragma unroll
            for (int n = 0; n < 16; n++) {
                e *= eS;
                corr = fmaf(e * hin[n], cc[n], corr);
            }
        } else {
#pragma unroll
            for (int n = 0; n < 16; n++)
                corr = fmaf(__expf(Ad[n] * S) * hin[n], cc[n], corr);
        }
        xp[(size_t)tl * DIQ] = f2bf(bf2f(xp[(size_t)tl * DIQ]) + corr);
    }
}

// ---------------- 2-stage mean/max over L (float4) ----------------
__global__ void k_redu1(const float* __restrict__ o, float* __restrict__ psum,
                        float* __restrict__ pmax) {
    int b = blockIdx.x >> 5, tc = blockIdx.x & 31;  // 192 threads
    int ch0 = threadIdx.x * 4;
    const float* p = o + ((size_t)b * LQ + tc * 32) * DMQ + ch0;
    float s[4] = {0.f, 0.f, 0.f, 0.f};
    float m[4] = {-3.4e38f, -3.4e38f, -3.4e38f, -3.4e38f};
    for (int t = 0; t < 32; t++) {
        float4 v = *(const float4*)(p + (size_t)t * DMQ);
        s[0] += v.x; s[1] += v.y; s[2] += v.z; s[3] += v.w;
        m[0] = fmaxf(m[0], v.x); m[1] = fmaxf(m[1], v.y);
        m[2] = fmaxf(m[2], v.z); m[3] = fmaxf(m[3], v.w);
    }
    *(float4*)(psum + (size_t)(b * 32 + tc) * DMQ + ch0) = *(float4*)s;
    *(float4*)(pmax + (size_t)(b * 32 + tc) * DMQ + ch0) = *(float4*)m;
}
__global__ void k_redu2(const float* __restrict__ psum, const float* __restrict__ pmax,
                        float* __restrict__ avg, float* __restrict__ mx) {
    int i4 = (blockIdx.x * 256 + threadIdx.x) * 4;  // 0..6143 by 4
    int b = i4 / DMQ, ch0 = i4 % DMQ;
    float s[4] = {0.f, 0.f, 0.f, 0.f};
    float m[4] = {-3.4e38f, -3.4e38f, -3.4e38f, -3.4e38f};
    for (int tc = 0; tc < 32; tc++) {
        float4 v = *(const float4*)(psum + (size_t)(b * 32 + tc) * DMQ + ch0);
        float4 w = *(const float4*)(pmax + (size_t)(b * 32 + tc) * DMQ + ch0);
        s[0] += v.x; s[1] += v.y; s[2] += v.z; s[3] += v.w;
        m[0] = fmaxf(m[0], w.x); m[1] = fmaxf(m[1], w.y);
        m[2] = fmaxf(m[2], w.z); m[3] = fmaxf(m[3], w.w);
    }
    float4 sv = {s[0] * (1.f / LQ), s[1] * (1.f / LQ), s[2] * (1.f / LQ), s[3] * (1.f / LQ)};
    *(float4*)(avg + i4) = sv;
    *(float4*)(mx + i4) = *(float4*)m;
}

__global__ void k_att1(const float* __restrict__ avg, const float* __restrict__ mx,
                       const float* __restrict__ w1, float* __restrict__ hs) {
    int idx = blockIdx.x * 256 + threadIdx.x;
    int b = idx / 384, j = idx % 384;
    const float* w = w1 + (size_t)j * DMQ;
    const float* a = avg + (size_t)b * DMQ;
    const float* m2 = mx + (size_t)b * DMQ;
    float s1 = 0.f, s2 = 0.f;
    for (int k = 0; k < DMQ; k += 4) {
        float4 wv = *(const float4*)(w + k);
        float4 av = *(const float4*)(a + k);
        float4 mv = *(const float4*)(m2 + k);
        s1 = fmaf(av.x, wv.x, s1); s1 = fmaf(av.y, wv.y, s1);
        s1 = fmaf(av.z, wv.z, s1); s1 = fmaf(av.w, wv.w, s1);
        s2 = fmaf(mv.x, wv.x, s2); s2 = fmaf(mv.y, wv.y, s2);
        s2 = fmaf(mv.z, wv.z, s2); s2 = fmaf(mv.w, wv.w, s2);
    }
    hs[idx] = fmaxf(s1, 0.f) + fmaxf(s2, 0.f);
}

__global__ void k_att2(const float* __restrict__ hs, const float* __restrict__ w2,
                       float* __restrict__ att) {
    int idx = blockIdx.x * 256 + threadIdx.x;
    int b = idx / DMQ, n = idx % DMQ;
    const float* w = w2 + (size_t)n * 384;
    const float* h = hs + (size_t)b * 384;
    float s = 0.f;
    for (int k = 0; k < 384; k += 4) {
        float4 wv = *(const float4*)(w + k);
        float4 hv = *(const float4*)(h + k);
        s = fmaf(hv.x, wv.x, s); s = fmaf(hv.y, wv.y, s);
        s = fmaf(hv.z, wv.z, s); s = fmaf(hv.w, wv.w, s);
    }
    att[idx] = sigf(s);
}

__global__ void k_scaleb(const float* __restrict__ o, const float* __restrict__ att,
                         ushortT* __restrict__ ob) {
    size_t i4 = ((size_t)blockIdx.x * 256 + threadIdx.x) * 4;
    int ch = (int)(i4 % DMQ);
    int b = (int)(i4 / ((size_t)LQ * DMQ));
    float4 v = *(const float4*)(o + i4);
    float4 a = *(const float4*)(att + (size_t)b * DMQ + ch);
    ushort4 r = {f2bf(v.x * a.x), f2bf(v.y * a.y), f2bf(v.z * a.z), f2bf(v.w * a.w)};
    *(ushort4*)(ob + i4) = r;
}

__global__ void k_diag(float* __restrict__ o, float v) {
    if (blockIdx.x == 0 && threadIdx.x == 0) o[0] = v;
}

extern "C" void kernel_launch(void* const* d_in, const int* in_sizes, int n_in, void* d_out,
                              int out_size, void* d_ws, size_t ws_size, hipStream_t stream) {
    (void)in_sizes; (void)n_in; (void)out_size;
    const float* hid = (const float*)d_in[0];
    const int* mask = (const int*)d_in[1];
    const float* pool_w = (const float*)d_in[2];
    const float* pool_b = (const float*)d_in[3];
    const float* bn_g = (const float*)d_in[4];
    const float* bn_b = (const float*)d_in[5];
    const float* bn_rm = (const float*)d_in[6];
    const float* bn_rv = (const float*)d_in[7];
    const float* ipw = (const float*)d_in[8];
    const float* cw = (const float*)d_in[9];
    const float* cb = (const float*)d_in[10];
    const float* xpw = (const float*)d_in[11];
    const float* dtw = (const float*)d_in[12];
    const float* dtb = (const float*)d_in[13];
    const float* alog = (const float*)d_in[14];
    const float* Dpp = (const float*)d_in[15];
    const float* mow = (const float*)d_in[16];
    const float* opw = (const float*)d_in[17];
    const float* opb = (const float*)d_in[18];
    const float* caw1 = (const float*)d_in[19];
    const float* caw2 = (const float*)d_in[20];
    const float* fusw = (const float*)d_in[21];
    const float* fusb = (const float*)d_in[22];
    float* out = (float*)d_out;

    // workspace layout (float-equivalent offsets)
    const size_t O_IPWB = 32768;
    const size_t O_XPWB = 819200;
    const size_t O_FUSWB = 1015808;
    const size_t O_WTMPB = 1310720;
    const size_t O_XDBL = 1703936;
    const size_t O_CBASE = 4063232;
    const size_t O_RAWX = 7208960;
    const size_t O_SCANX = 19791872;
    const size_t TOTAL_F = 32374784;  // 129.5 MB
    if (ws_size < TOTAL_F * 4) {
        k_diag<<<1, 64, 0, stream>>>(out, (float)(ws_size >> 20));
        return;
    }

    float* ws = (float*)d_ws;
    int* lengths = (int*)ws;
    float* avg = ws + 1024;
    float* mxp = avg + 6144;
    float* hs = mxp + 6144;
    float* att = hs + 3072;
    ushortT* ipwb = (ushortT*)(ws + O_IPWB);
    ushortT* xpwb = (ushortT*)(ws + O_XPWB);
    ushortT* fuswb = (ushortT*)(ws + O_FUSWB);
    ushortT* wtmpb = (ushortT*)(ws + O_WTMPB);
    float* xdbl = ws + O_XDBL;
    ushortT* cbase = (ushortT*)(ws + O_CBASE);
    ushortT* rawx = (ushortT*)(ws + O_RAWX);
    ushortT* scanX = (ushortT*)(ws + O_SCANX);
    // overlays
    float* hbuf = ws + O_RAWX;   // rawx dead after dwconv
    float* sbuf = hbuf + 3145728;
    float* psum = (float*)cbase; // cbase dead after z-GEMM
    float* pmax = psum + 196608;
    ushortT* outb = scanX;       // scanX dead after mo/op GEMMs

    // ---- weight prep ----
    k_lengths<<<dim3(8), dim3(256), 0, stream>>>(mask, lengths);
    k_cvt<<<dim3(6144), dim3(256), 0, stream>>>(ipw, ipwb, 6 * 1024 * 256);
    k_cvt<<<dim3(2304), dim3(256), 0, stream>>>(fusw, fuswb, 768 * 768);
    k_cvtpad48<<<dim3(1536), dim3(256), 0, stream>>>(xpw, xpwb);
    k_wfuse<<<dim3(768), dim3(256), 0, stream>>>(opw, mow, wtmpb);

    // ---- pool (all scales) ----
    k_pool<<<dim3(3 * 8192), dim3(64), 0, stream>>>(hid, pool_w, pool_b, bn_g, bn_b, bn_rm,
                                                    bn_rv, cbase);

    // ---- in_proj x-half (all 6 insts), flip odd insts ----
    gemm_bf16<2, 0, 0, 0, 1, 0><<<dim3(4, 64, 6), 256, 0, stream>>>(
        cbase, ipwb, rawx, nullptr, 512, 256, 256, 512, lengths, 2097152, 1, 262144, 4194304, 0);

    // ---- dwconv + SiLU (all insts) ----
    k_dwconv<<<dim3(384), dim3(256), 0, stream>>>(rawx, cw, cb, scanX);

    // ---- x_proj (all insts) ----
    gemm_bf16<0, 0, 0, 0, 0, 0><<<dim3(1, 64, 6), 256, 0, stream>>>(
        scanX, xpwb, xdbl, nullptr, 48, 512, 512, 48, lengths, 4194304, 0, 65536, 393216, 0);

    // ---- chunked selective scan (in place on scanX) ----
    k_scan1<<<dim3(48 * CCH * 2), dim3(256), 0, stream>>>(scanX, xdbl, dtw, dtb, alog, Dpp,
                                                          hbuf, sbuf);
    k_scan2<<<dim3(48), dim3(512), 0, stream>>>(alog, hbuf, sbuf);
    k_scan3<<<dim3(48 * (CCH - 1) * 2), dim3(256), 0, stream>>>(scanX, xdbl, dtw, dtb, alog,
                                                                hbuf);

    // ---- in_proj z-half (all insts) + fused gate epilogue into scanX ----
    gemm_bf16<2, 0, 0, 0, 1, 1><<<dim3(4, 64, 6), 256, 0, stream>>>(
        cbase, ipwb + 131072, scanX, nullptr, 512, 256, 256, 512, lengths, 2097152, 1, 262144,
        4194304, 0);

    // ---- fused mo+op: dir0 write, dir1 accumulate+bias+flip ----
    gemm_bf16<0, 0, 0, 0, 0, 0><<<dim3(2, 64, 3), 256, 0, stream>>>(
        scanX, wtmpb, out, nullptr, 256, 512, 512, DMQ, lengths, 8388608, 0, 262144, 256, 0);
    gemm_bf16<0, 1, 1, 1, 0, 0><<<dim3(2, 64, 3), 256, 0, stream>>>(
        scanX + 4194304, wtmpb + 131072, out, opb, 256, 512, 512, DMQ, lengths, 8388608, 0,
        262144, 256, 256);

    // ---- attention pooling + final projection ----
    k_redu1<<<dim3(256), dim3(192), 0, stream>>>(out, psum, pmax);
    k_redu2<<<dim3(6), dim3(256), 0, stream>>>(psum, pmax, avg, mxp);
    k_att1<<<dim3(12), dim3(256), 0, stream>>>(avg, mxp, caw1, hs);
    k_att2<<<dim3(24), dim3(256), 0, stream>>>(hs, caw2, att);
    k_scaleb<<<dim3(6144), dim3(256), 0, stream>>>(out, att, outb);
    gemm_bf16<0, 0, 1, 0, 0, 0><<<dim3(6, 64, 1), 256, 0, stream>>>(
        outb, fuswb, out, fusb, DMQ, DMQ, DMQ, DMQ, lengths, 0, 0, 0, 0, 0);
}

// Round 9
// 483.323 us; speedup vs baseline: 6.1363x; 1.0111x over previous
//
#include <hip/hip_runtime.h>
#include <cstddef>
#include <cstdint>

#define LQ 1024
#define DMQ 768
#define DSQ 256
#define DIQ 512
#define CCH 8
#define CT (LQ / CCH)

typedef unsigned short ushortT;
using f32x4 = __attribute__((ext_vector_type(4))) float;
using bf16x8 = __attribute__((ext_vector_type(8))) short;
using u16x8 = __attribute__((ext_vector_type(8))) unsigned short;

__device__ __forceinline__ float sigf(float x) { return 1.f / (1.f + __expf(-x)); }
__device__ __forceinline__ float softplusf(float x) {
    return fmaxf(x, 0.f) + __logf(1.f + __expf(-fabsf(x)));
}
__device__ __forceinline__ ushortT f2bf(float f) {
    unsigned u = __float_as_uint(f);
    u += 0x7FFFu + ((u >> 16) & 1u);
    return (ushortT)(u >> 16);
}
__device__ __forceinline__ float bf2f(ushortT u) {
    return __uint_as_float(((unsigned)u) << 16);
}
__device__ __forceinline__ void gload_lds16(const void* g, void* l) {
    __builtin_amdgcn_global_load_lds((const __attribute__((address_space(1))) void*)g,
                                     (__attribute__((address_space(3))) void*)l, 16, 0, 0);
}
// log-depth powers p[n] = base^(n+1), n=0..15
__device__ __forceinline__ void pow_tree(float e1, float* p) {
    float e2 = e1 * e1, e4 = e2 * e2, e8 = e4 * e4;
    p[0] = e1; p[1] = e2; p[2] = e2 * e1; p[3] = e4;
    p[4] = e4 * e1; p[5] = e4 * e2; p[6] = e4 * p[2]; p[7] = e8;
    p[8] = e8 * e1; p[9] = e8 * e2; p[10] = e8 * p[2]; p[11] = e8 * e4;
    p[12] = e8 * p[4]; p[13] = e8 * p[5]; p[14] = e8 * p[6]; p[15] = e8 * e8;
}

// ---------------- lengths ----------------
__global__ void k_lengths(const int* __restrict__ mask, int* __restrict__ lengths) {
    int b = blockIdx.x;
    int s = 0;
    for (int t = threadIdx.x; t < LQ; t += 256) s += mask[b * LQ + t];
    __shared__ int sm[256];
    sm[threadIdx.x] = s;
    __syncthreads();
    for (int o = 128; o > 0; o >>= 1) {
        if (threadIdx.x < o) sm[threadIdx.x] += sm[threadIdx.x + o];
        __syncthreads();
    }
    if (threadIdx.x == 0) lengths[b] = sm[0];
}

// ---------------- merged weight conversion ----------------
__global__ void k_prep(const float* __restrict__ ipw, const float* __restrict__ fusw,
                       const float* __restrict__ xpw, ushortT* __restrict__ ipwb,
                       ushortT* __restrict__ fuswb, ushortT* __restrict__ xpwb) {
    int i = blockIdx.x * 256 + threadIdx.x;
    if (i < 1572864) { ipwb[i] = f2bf(ipw[i]); return; }
    i -= 1572864;
    if (i < 589824) { fuswb[i] = f2bf(fusw[i]); return; }
    i -= 589824;
    if (i >= 393216) return;
    int inst = i >> 16, rem = i & 65535;
    int row = rem >> 9, col = rem & 511;
    float v = (row < 48) ? xpw[((size_t)inst * 48 + row) * 512 + col] : 0.f;
    xpwb[i] = f2bf(v);
}

// -------- fused weight, dir-interleaved: wf2[i][m][dir*512+d] --------
__global__ void k_wfuse(const float* __restrict__ opw, const float* __restrict__ mow,
                        ushortT* __restrict__ wf) {
    int idx = blockIdx.x * 256 + threadIdx.x;  // 196608 = 6*256*128
    int inst = idx >> 15;
    int rem = idx & 32767;
    int m = rem >> 7;
    int d0 = (rem & 127) * 4;
    int i = inst >> 1, dir = inst & 1;
    const float* a = opw + (size_t)i * 131072 + dir * 256 + (size_t)m * 512;
    const float* bm = mow + (size_t)inst * 131072 + d0;
    float s0 = 0.f, s1 = 0.f, s2 = 0.f, s3 = 0.f;
    for (int c = 0; c < 256; c++) {
        float av = a[c];
        float4 bv = *(const float4*)(bm + (size_t)c * 512);
        s0 = fmaf(av, bv.x, s0);
        s1 = fmaf(av, bv.y, s1);
        s2 = fmaf(av, bv.z, s2);
        s3 = fmaf(av, bv.w, s3);
    }
    ushort4 r = {f2bf(s0), f2bf(s1), f2bf(s2), f2bf(s3)};
    *(ushort4*)(wf + ((size_t)i * 256 + m) * 1024 + dir * 512 + d0) = r;
}

// ------- dilated dw conv + BN + GELU -> c bf16 (all 3 scales, float4/thread) -------
__global__ __launch_bounds__(64) void k_pool(const float* __restrict__ hid,
                                             const float* __restrict__ pw,
                                             const float* __restrict__ pb,
                                             const float* __restrict__ bg,
                                             const float* __restrict__ bb,
                                             const float* __restrict__ brm,
                                             const float* __restrict__ brv,
                                             ushortT* __restrict__ cdst) {
    int gidx = blockIdx.x;  // 3*8192
    int isc = gidx >> 13;
    int idx = gidx & 8191;
    int l = idx & (LQ - 1);
    int b = idx >> 10;
    int ch0 = threadIdx.x * 4;
    int dil = 1 << isc;
    int wci0 = isc * DSQ + ch0;
    const float* xb = hid + (size_t)b * LQ * DMQ + isc * DSQ + ch0;
    float wv[12];
    *(float4*)&wv[0] = *(const float4*)(pw + (size_t)wci0 * 3);
    *(float4*)&wv[4] = *(const float4*)(pw + (size_t)wci0 * 3 + 4);
    *(float4*)&wv[8] = *(const float4*)(pw + (size_t)wci0 * 3 + 8);
    float pbv[4], bgv[4], bbv[4], rmv[4], rvv[4];
    *(float4*)pbv = *(const float4*)(pb + wci0);
    *(float4*)bgv = *(const float4*)(bg + wci0);
    *(float4*)bbv = *(const float4*)(bb + wci0);
    *(float4*)rmv = *(const float4*)(brm + wci0);
    *(float4*)rvv = *(const float4*)(brv + wci0);
    float xm[4] = {0.f, 0.f, 0.f, 0.f}, xc[4], xp[4] = {0.f, 0.f, 0.f, 0.f};
    int lm = l - dil, lp = l + dil;
    if (lm >= 0) *(float4*)xm = *(const float4*)(xb + (size_t)lm * DMQ);
    *(float4*)xc = *(const float4*)(xb + (size_t)l * DMQ);
    if (lp < LQ) *(float4*)xp = *(const float4*)(xb + (size_t)lp * DMQ);
    ushort4 o;
#pragma unroll
    for (int j = 0; j < 4; j++) {
        float acc = pbv[j];
        acc = fmaf(wv[j * 3 + 0], xm[j], acc);
        acc = fmaf(wv[j * 3 + 1], xc[j], acc);
        acc = fmaf(wv[j * 3 + 2], xp[j], acc);
        float xn = (acc - rmv[j]) * rsqrtf(rvv[j] + 1e-5f) * bgv[j] + bbv[j];
        float y = 0.5f * xn * (1.0f + erff(xn * 0.70710678118654752f));
        ((ushortT*)&o)[j] = f2bf(y);
    }
    *(ushort4*)(cdst + (size_t)isc * 2097152 + (size_t)idx * DSQ + ch0) = o;
}

// ---------------- batched bf16 GEMM: C[z] (+)= A[z] * Bw[z]^T ----------------
// FLIPA/FLIPC: 0 none, 1 always, 2 when (z&1). CBF16: C bf16. GATE: C = Y*acc*sig(acc).
template <int FLIPA, int FLIPC, int BIAS, int ACC, int CBF16, int GATE>
__global__ __launch_bounds__(256) void gemm_bf16(
    const ushortT* __restrict__ A, const ushortT* __restrict__ Bw, void* __restrict__ Cv,
    const float* __restrict__ bias, const ushortT* __restrict__ Yb,
    const int* __restrict__ lengths, int N, int Kd, int lda, int ldc, int ldy, long sAz,
    int zshiftA, long sBz, long sCz, long sCzOdd, int zshiftC, long sYz, int sBiasz) {
    __shared__ ushortT Als[128 * 64];
    __shared__ ushortT Bls[128 * 64];
    const int z = blockIdx.z;
    A += (size_t)(z >> zshiftA) * sAz;
    Bw += (size_t)z * sBz;
    size_t cbase = (size_t)(z >> zshiftC) * sCz +
                   (size_t)(z & ((1 << zshiftC) - 1)) * sCzOdd;
    float* Cf = (float*)Cv + (CBF16 ? 0 : cbase);
    ushortT* Cb = (ushortT*)Cv + (CBF16 ? cbase : 0);
    if (BIAS) bias += (size_t)z * sBiasz;
    if (GATE) Yb += (size_t)z * sYz;

    const int tid = threadIdx.x;
    const int lane = tid & 63;
    const int wave = tid >> 6;
    const int wr = wave >> 1, wc = wave & 1;
    const int row0 = blockIdx.y * 128, col0 = blockIdx.x * 128;
    const bool doflipA = (FLIPA == 1) || (FLIPA == 2 && (z & 1));
    const bool doflipC = (FLIPC == 1) || (FLIPC == 2 && (z & 1));
    int len = 0;
    if (FLIPA || FLIPC) len = lengths[row0 >> 10];

    const int srow = wave * 8 + (lane >> 3);  // + it*32
    const int scol = (lane & 7) * 8;

    f32x4 acc[4][4];
#pragma unroll
    for (int i = 0; i < 4; i++)
#pragma unroll
        for (int j = 0; j < 4; j++) acc[i][j] = (f32x4){0.f, 0.f, 0.f, 0.f};

    for (int k0 = 0; k0 < Kd; k0 += 64) {
        __syncthreads();
#pragma unroll
        for (int it = 0; it < 4; it++) {
            int row = it * 32 + srow;
            int grow = row0 + row;
            if (FLIPA) {
                if (doflipA) {
                    int t = grow & (LQ - 1);
                    int ts = (t < len) ? (len - 1 - t) : t;
                    grow = (grow & ~(LQ - 1)) | ts;
                }
            }
            gload_lds16(A + (size_t)grow * lda + k0 + scol, &Als[it * 2048 + wave * 512]);
        }
#pragma unroll
        for (int it = 0; it < 4; it++) {
            int row = it * 32 + srow;
            gload_lds16(Bw + (size_t)(col0 + row) * Kd + k0 + scol,
                        &Bls[it * 2048 + wave * 512]);
        }
        __syncthreads();
#pragma unroll
        for (int ks = 0; ks < 2; ks++) {
            bf16x8 am[4], bv[4];
#pragma unroll
            for (int f = 0; f < 4; f++) {
                am[f] = *(const bf16x8*)&Als[(wr * 64 + f * 16 + (lane & 15)) * 64 + ks * 32 +
                                             (lane >> 4) * 8];
                bv[f] = *(const bf16x8*)&Bls[(wc * 64 + f * 16 + (lane & 15)) * 64 + ks * 32 +
                                             (lane >> 4) * 8];
            }
#pragma unroll
            for (int fm = 0; fm < 4; fm++)
#pragma unroll
                for (int fn = 0; fn < 4; fn++)
                    acc[fm][fn] = __builtin_amdgcn_mfma_f32_16x16x32_bf16(am[fm], bv[fn],
                                                                          acc[fm][fn], 0, 0, 0);
        }
    }
#pragma unroll
    for (int fm = 0; fm < 4; fm++) {
#pragma unroll
        for (int r = 0; r < 4; r++) {
            int growY = row0 + wr * 64 + fm * 16 + (lane >> 4) * 4 + r;
            int growC = growY;
            if (FLIPC) {
                if (doflipC) {
                    int t = growC & (LQ - 1);
                    int ts = (t < len) ? (len - 1 - t) : t;
                    growC = (growC & ~(LQ - 1)) | ts;
                }
            }
#pragma unroll
            for (int fn = 0; fn < 4; fn++) {
                int col = col0 + wc * 64 + fn * 16 + (lane & 15);
                if (col < N) {
                    float v = acc[fm][fn][r];
                    if (CBF16) {
                        if (GATE) {
                            float yv = bf2f(Yb[(size_t)growY * ldy + col]);
                            v = yv * v * sigf(v);
                        }
                        if (BIAS) v += bias[col];
                        Cb[(size_t)growC * ldc + col] = f2bf(v);
                    } else {
                        float* cp = Cf + (size_t)growC * ldc + col;
                        if (ACC) v += *cp;
                        if (BIAS) v += bias[col];
                        *cp = v;
                    }
                }
            }
        }
    }
}

// ---- causal dw conv (K=4) + SiLU: register-window, 8ch x 32t per thread ----
__global__ __launch_bounds__(256) void k_dwconv(const ushortT* __restrict__ rawx,
                                                const float* __restrict__ cw,
                                                const float* __restrict__ cb,
                                                ushortT* __restrict__ sx) {
    int blk = blockIdx.x;
    int tc = blk & 7;
    int sb = blk >> 3;  // inst*8+b
    int inst = sb >> 3;
    int cg = threadIdx.x & 63;
    int sub = threadIdx.x >> 6;
    int ch0 = cg * 8;
    int t0 = tc * 128 + sub * 32;
    const ushortT* base = rawx + (size_t)sb * LQ * DIQ + ch0;
    ushortT* obase = sx + (size_t)sb * LQ * DIQ + ch0;

    float w[8][4], bs[8];
#pragma unroll
    for (int j = 0; j < 8; j++) {
        float4 wv = *(const float4*)(cw + (size_t)inst * 2048 + (size_t)(ch0 + j) * 4);
        w[j][0] = wv.x; w[j][1] = wv.y; w[j][2] = wv.z; w[j][3] = wv.w;
        bs[j] = cb[inst * DIQ + ch0 + j];
    }
    float x3[8], x2[8], x1[8];
#pragma unroll
    for (int j = 0; j < 8; j++) { x3[j] = 0.f; x2[j] = 0.f; x1[j] = 0.f; }
    if (t0 >= 3) {
        u16x8 v3 = *(const u16x8*)(base + (size_t)(t0 - 3) * DIQ);
        u16x8 v2 = *(const u16x8*)(base + (size_t)(t0 - 2) * DIQ);
        u16x8 v1 = *(const u16x8*)(base + (size_t)(t0 - 1) * DIQ);
#pragma unroll
        for (int j = 0; j < 8; j++) {
            x3[j] = bf2f(v3[j]); x2[j] = bf2f(v2[j]); x1[j] = bf2f(v1[j]);
        }
    }
#pragma unroll 4
    for (int t = t0; t < t0 + 32; t++) {
        u16x8 v = *(const u16x8*)(base + (size_t)t * DIQ);
        float xc[8];
#pragma unroll
        for (int j = 0; j < 8; j++) xc[j] = bf2f(v[j]);
        u16x8 o;
#pragma unroll
        for (int j = 0; j < 8; j++) {
            float acc = bs[j];
            acc = fmaf(w[j][0], x3[j], acc);
            acc = fmaf(w[j][1], x2[j], acc);
            acc = fmaf(w[j][2], x1[j], acc);
            acc = fmaf(w[j][3], xc[j], acc);
            o[j] = f2bf(acc * sigf(acc));
        }
        *(u16x8*)(obase + (size_t)t * DIQ) = o;
#pragma unroll
        for (int j = 0; j < 8; j++) { x3[j] = x2[j]; x2[j] = x1[j]; x1[j] = xc[j]; }
    }
}

// ======== chunked selective scan ========
__global__ __launch_bounds__(256) void k_scan1(ushortT* __restrict__ scanX,
                                               const float* __restrict__ xdbl,
                                               const float* __restrict__ dt_w,
                                               const float* __restrict__ dt_b,
                                               const float* __restrict__ A_log,
                                               const float* __restrict__ Dpp,
                                               float* __restrict__ hbuf,
                                               float* __restrict__ sbuf) {
    int bid = blockIdx.x;
    int seq = bid >> 4;
    int r = bid & 15;
    int c = r >> 1, half = r & 1;
    int inst = seq >> 3;
    int ch = half * 256 + threadIdx.x;

    const float4* xd4 = (const float4*)(xdbl + ((size_t)seq * LQ + c * CT) * 48);
    ushortT* xp = scanX + ((size_t)seq * LQ + c * CT) * DIQ + ch;
    int wo = inst * DIQ + ch;
    float dtw[16], Ad[16];
#pragma unroll
    for (int rr = 0; rr < 16; rr++) dtw[rr] = dt_w[(size_t)wo * 16 + rr];
    float dtb = dt_b[wo];
    bool fastA = true;
#pragma unroll
    for (int n = 0; n < 16; n++) {
        Ad[n] = -__expf(A_log[(size_t)wo * 16 + n]);
        fastA = fastA && (fabsf(Ad[n] + (float)(n + 1)) < 1e-3f * (n + 1));
    }
    float Dd = Dpp[wo];
    float h[16];
#pragma unroll
    for (int n = 0; n < 16; n++) h[n] = 0.f;
    float S = 0.f;

    __shared__ float4 sd4[CT * 12];  // 24KB
    for (int u = threadIdx.x; u < CT * 12; u += 256) sd4[u] = xd4[u];
    __syncthreads();

    float xt = bf2f(xp[0]);
    if (fastA) {
        for (int tl = 0; tl < CT; tl++) {
            float xnext = (tl + 1 < CT) ? bf2f(xp[(size_t)(tl + 1) * DIQ]) : 0.f;
            const float4* s4 = sd4 + tl * 12;
            float4 q0 = s4[0], q1 = s4[1], q2 = s4[2], q3 = s4[3];
            float draw = dtb;
            draw = fmaf(q0.x, dtw[0], draw); draw = fmaf(q0.y, dtw[1], draw);
            draw = fmaf(q0.z, dtw[2], draw); draw = fmaf(q0.w, dtw[3], draw);
            draw = fmaf(q1.x, dtw[4], draw); draw = fmaf(q1.y, dtw[5], draw);
            draw = fmaf(q1.z, dtw[6], draw); draw = fmaf(q1.w, dtw[7], draw);
            draw = fmaf(q2.x, dtw[8], draw); draw = fmaf(q2.y, dtw[9], draw);
            draw = fmaf(q2.z, dtw[10], draw); draw = fmaf(q2.w, dtw[11], draw);
            draw = fmaf(q3.x, dtw[12], draw); draw = fmaf(q3.y, dtw[13], draw);
            draw = fmaf(q3.z, dtw[14], draw); draw = fmaf(q3.w, dtw[15], draw);
            float dt = softplusf(draw);
            S += dt;
            float pw[16];
            pow_tree(__expf(-dt), pw);
            float dtx = dt * xt;
            float bb[16], cc[16];
            *(float4*)&bb[0] = s4[4]; *(float4*)&bb[4] = s4[5];
            *(float4*)&bb[8] = s4[6]; *(float4*)&bb[12] = s4[7];
            *(float4*)&cc[0] = s4[8]; *(float4*)&cc[4] = s4[9];
            *(float4*)&cc[8] = s4[10]; *(float4*)&cc[12] = s4[11];
            float y0 = 0.f, y1 = 0.f, y2 = 0.f, y3 = 0.f;
#pragma unroll
            for (int n = 0; n < 16; n += 4) {
                h[n] = fmaf(h[n], pw[n], dtx * bb[n]);
                y0 = fmaf(h[n], cc[n], y0);
                h[n + 1] = fmaf(h[n + 1], pw[n + 1], dtx * bb[n + 1]);
                y1 = fmaf(h[n + 1], cc[n + 1], y1);
                h[n + 2] = fmaf(h[n + 2], pw[n + 2], dtx * bb[n + 2]);
                y2 = fmaf(h[n + 2], cc[n + 2], y2);
                h[n + 3] = fmaf(h[n + 3], pw[n + 3], dtx * bb[n + 3]);
                y3 = fmaf(h[n + 3], cc[n + 3], y3);
            }
            xp[(size_t)tl * DIQ] = f2bf(fmaf(xt, Dd, (y0 + y1) + (y2 + y3)));
            xt = xnext;
        }
    } else {
        for (int tl = 0; tl < CT; tl++) {
            float xnext = (tl + 1 < CT) ? bf2f(xp[(size_t)(tl + 1) * DIQ]) : 0.f;
            const float4* s4 = sd4 + tl * 12;
            float qq[16], bb[16], cc[16];
            *(float4*)&qq[0] = s4[0]; *(float4*)&qq[4] = s4[1];
            *(float4*)&qq[8] = s4[2]; *(float4*)&qq[12] = s4[3];
            *(float4*)&bb[0] = s4[4]; *(float4*)&bb[4] = s4[5];
            *(float4*)&bb[8] = s4[6]; *(float4*)&bb[12] = s4[7];
            *(float4*)&cc[0] = s4[8]; *(float4*)&cc[4] = s4[9];
            *(float4*)&cc[8] = s4[10]; *(float4*)&cc[12] = s4[11];
            float draw = dtb;
#pragma unroll
            for (int rr = 0; rr < 16; rr++) draw = fmaf(qq[rr], dtw[rr], draw);
            float dt = softplusf(draw);
            S += dt;
            float dtx = dt * xt;
            float y = 0.f;
#pragma unroll
            for (int n = 0; n < 16; n++) {
                float e = __expf(dt * Ad[n]);
                h[n] = fmaf(h[n], e, dtx * bb[n]);
                y = fmaf(h[n], cc[n], y);
            }
            xp[(size_t)tl * DIQ] = f2bf(fmaf(xt, Dd, y));
            xt = xnext;
        }
    }
    float* hp = hbuf + (((size_t)(seq * CCH + c) * DIQ) + ch) * 16;
#pragma unroll
    for (int n = 0; n < 16; n += 4)
        *(float4*)(hp + n) = make_float4(h[n], h[n + 1], h[n + 2], h[n + 3]);
    sbuf[(size_t)(seq * CCH + c) * DIQ + ch] = S;
}

__global__ __launch_bounds__(512) void k_scan2(const float* __restrict__ A_log,
                                               float* __restrict__ hbuf,
                                               const float* __restrict__ sbuf) {
    int seq = blockIdx.x;
    int inst = seq >> 3;
    int ch = threadIdx.x;
    int wo = inst * DIQ + ch;
    float Ad[16];
#pragma unroll
    for (int n = 0; n < 16; n++) Ad[n] = -__expf(A_log[(size_t)wo * 16 + n]);
    float hin[16];
#pragma unroll
    for (int n = 0; n < 16; n++) hin[n] = 0.f;
    for (int c = 0; c < CCH; c++) {
        float* hp = hbuf + (((size_t)(seq * CCH + c) * DIQ) + ch) * 16;
        float Sc = sbuf[(size_t)(seq * CCH + c) * DIQ + ch];
        float he[16];
#pragma unroll
        for (int n = 0; n < 16; n += 4) *(float4*)(he + n) = *(const float4*)(hp + n);
#pragma unroll
        for (int n = 0; n < 16; n += 4)
            *(float4*)(hp + n) = make_float4(hin[n], hin[n + 1], hin[n + 2], hin[n + 3]);
#pragma unroll
        for (int n = 0; n < 16; n++) hin[n] = fmaf(hin[n], __expf(Ad[n] * Sc), he[n]);
    }
}

__global__ __launch_bounds__(256) void k_scan3(ushortT* __restrict__ scanX,
                                               const float* __restrict__ xdbl,
                                               const float* __restrict__ dt_w,
                                               const float* __restrict__ dt_b,
                                               const float* __restrict__ A_log,
                                               const float* __restrict__ hbuf) {
    int bid = blockIdx.x;
    int seq = bid / (2 * (CCH - 1));
    int r = bid % (2 * (CCH - 1));
    int c = 1 + (r >> 1), half = r & 1;
    int inst = seq >> 3;
    int ch = half * 256 + threadIdx.x;

    const float4* xd4 = (const float4*)(xdbl + ((size_t)seq * LQ + c * CT) * 48);
    ushortT* xp = scanX + ((size_t)seq * LQ + c * CT) * DIQ + ch;
    int wo = inst * DIQ + ch;
    float dtw[16], Ad[16];
#pragma unroll
    for (int rr = 0; rr < 16; rr++) dtw[rr] = dt_w[(size_t)wo * 16 + rr];
    float dtb = dt_b[wo];
    float amax = -1e30f;
    bool fastA = true;
#pragma unroll
    for (int n = 0; n < 16; n++) {
        Ad[n] = -__expf(A_log[(size_t)wo * 16 + n]);
        amax = fmaxf(amax, Ad[n]);
        fastA = fastA && (fabsf(Ad[n] + (float)(n + 1)) < 1e-3f * (n + 1));
    }
    float hin[16];
    const float* hp = hbuf + (((size_t)(seq * CCH + c) * DIQ) + ch) * 16;
#pragma unroll
    for (int n = 0; n < 16; n += 4) *(float4*)(hin + n) = *(const float4*)(hp + n);

    __shared__ float4 sd4[CT * 12];
    for (int u = threadIdx.x; u < CT * 12; u += 256) sd4[u] = xd4[u];
    __syncthreads();

    float S = 0.f;
    for (int tl = 0; tl < CT; tl++) {
        const float4* s4 = sd4 + tl * 12;
        float4 q0 = s4[0], q1 = s4[1], q2 = s4[2], q3 = s4[3];
        float draw = dtb;
        draw = fmaf(q0.x, dtw[0], draw); draw = fmaf(q0.y, dtw[1], draw);
        draw = fmaf(q0.z, dtw[2], draw); draw = fmaf(q0.w, dtw[3], draw);
        draw = fmaf(q1.x, dtw[4], draw); draw = fmaf(q1.y, dtw[5], draw);
        draw = fmaf(q1.z, dtw[6], draw); draw = fmaf(q1.w, dtw[7], draw);
        draw = fmaf(q2.x, dtw[8], draw); draw = fmaf(q2.y, dtw[9], draw);
        draw = fmaf(q2.z, dtw[10], draw); draw = fmaf(q2.w, dtw[11], draw);
        draw = fmaf(q3.x, dtw[12], draw); draw = fmaf(q3.y, dtw[13], draw);
        draw = fmaf(q3.z, dtw[14], draw); draw = fmaf(q3.w, dtw[15], draw);
        S += softplusf(draw);
        if (__all(amax * S < -30.f)) break;
        float cc[16];
        *(float4*)&cc[0] = s4[8]; *(float4*)&cc[4] = s4[9];
        *(float4*)&cc[8] = s4[10]; *(float4*)&cc[12] = s4[11];
        float corr;
        if (fastA) {
            float pw[16];
            pow_tree(__expf(-S), pw);
            float c0 = 0.f, c1 = 0.f, c2 = 0.f, c3 = 0.f;
#pragma unroll
            for (int n = 0; n < 16; n += 4) {
                c0 = fmaf(pw[n] * hin[n], cc[n], c0);
                c1 = fmaf(pw[n + 1] * hin[n + 1], cc[n + 1], c1);
                c2 = fmaf(pw[n + 2] * hin[n + 2], cc[n + 2], c2);
                c3 = fmaf(pw[n + 3] * hin[n + 3], cc[n + 3], c3);
            }
            corr = (c0 + c1) + (c2 + c3);
        } else {
            corr = 0.f;
#pragma unroll
            for (int n = 0; n < 16; n++)
                corr = fmaf(__expf(Ad[n] * S) * hin[n], cc[n], corr);
        }
        xp[(size_t)tl * DIQ] = f2bf(bf2f(xp[(size_t)tl * DIQ]) + corr);
    }
}

// ---------------- 2-stage mean/max over L (moutb bf16 input) ----------------
__global__ void k_redu1(const ushortT* __restrict__ mo, float* __restrict__ psum,
                        float* __restrict__ pmax) {
    int b = blockIdx.x >> 5, tc = blockIdx.x & 31;  // 192 threads
    int ch0 = threadIdx.x * 4;
    const ushortT* p = mo + ((size_t)b * LQ + tc * 32) * DMQ + ch0;
    float s[4] = {0.f, 0.f, 0.f, 0.f};
    float m[4] = {-3.4e38f, -3.4e38f, -3.4e38f, -3.4e38f};
    for (int t = 0; t < 32; t++) {
        ushort4 v = *(const ushort4*)(p + (size_t)t * DMQ);
        float f0 = bf2f(v.x), f1 = bf2f(v.y), f2 = bf2f(v.z), f3 = bf2f(v.w);
        s[0] += f0; s[1] += f1; s[2] += f2; s[3] += f3;
        m[0] = fmaxf(m[0], f0); m[1] = fmaxf(m[1], f1);
        m[2] = fmaxf(m[2], f2); m[3] = fmaxf(m[3], f3);
    }
    *(float4*)(psum + (size_t)(b * 32 + tc) * DMQ + ch0) = *(float4*)s;
    *(float4*)(pmax + (size_t)(b * 32 + tc) * DMQ + ch0) = *(float4*)m;
}
__global__ void k_redu2(const float* __restrict__ psum, const float* __restrict__ pmax,
                        float* __restrict__ avg, float* __restrict__ mx) {
    int i4 = (blockIdx.x * 256 + threadIdx.x) * 4;
    int b = i4 / DMQ, ch0 = i4 % DMQ;
    float s[4] = {0.f, 0.f, 0.f, 0.f};
    float m[4] = {-3.4e38f, -3.4e38f, -3.4e38f, -3.4e38f};
    for (int tc = 0; tc < 32; tc++) {
        float4 v = *(const float4*)(psum + (size_t)(b * 32 + tc) * DMQ + ch0);
        float4 w = *(const float4*)(pmax + (size_t)(b * 32 + tc) * DMQ + ch0);
        s[0] += v.x; s[1] += v.y; s[2] += v.z; s[3] += v.w;
        m[0] = fmaxf(m[0], w.x); m[1] = fmaxf(m[1], w.y);
        m[2] = fmaxf(m[2], w.z); m[3] = fmaxf(m[3], w.w);
    }
    float4 sv = {s[0] * (1.f / LQ), s[1] * (1.f / LQ), s[2] * (1.f / LQ), s[3] * (1.f / LQ)};
    *(float4*)(avg + i4) = sv;
    *(float4*)(mx + i4) = *(float4*)m;
}

__global__ void k_att1(const float* __restrict__ avg, const float* __restrict__ mx,
                       const float* __restrict__ w1, float* __restrict__ hs) {
    int idx = blockIdx.x * 256 + threadIdx.x;
    int b = idx / 384, j = idx % 384;
    const float* w = w1 + (size_t)j * DMQ;
    const float* a = avg + (size_t)b * DMQ;
    const float* m2 = mx + (size_t)b * DMQ;
    float s1 = 0.f, s2 = 0.f;
    for (int k = 0; k < DMQ; k += 4) {
        float4 wv = *(const float4*)(w + k);
        float4 av = *(const float4*)(a + k);
        float4 mv = *(const float4*)(m2 + k);
        s1 = fmaf(av.x, wv.x, s1); s1 = fmaf(av.y, wv.y, s1);
        s1 = fmaf(av.z, wv.z, s1); s1 = fmaf(av.w, wv.w, s1);
        s2 = fmaf(mv.x, wv.x, s2); s2 = fmaf(mv.y, wv.y, s2);
        s2 = fmaf(mv.z, wv.z, s2); s2 = fmaf(mv.w, wv.w, s2);
    }
    hs[idx] = fmaxf(s1, 0.f) + fmaxf(s2, 0.f);
}

__global__ void k_att2(const float* __restrict__ hs, const float* __restrict__ w2,
                       float* __restrict__ att) {
    int idx = blockIdx.x * 256 + threadIdx.x;
    int b = idx / DMQ, n = idx % DMQ;
    const float* w = w2 + (size_t)n * 384;
    const float* h = hs + (size_t)b * 384;
    float s = 0.f;
    for (int k = 0; k < 384; k += 4) {
        float4 wv = *(const float4*)(w + k);
        float4 hv = *(const float4*)(h + k);
        s = fmaf(hv.x, wv.x, s); s = fmaf(hv.y, wv.y, s);
        s = fmaf(hv.z, wv.z, s); s = fmaf(hv.w, wv.w, s);
    }
    att[idx] = sigf(s);
}

// in-place attention scale on moutb (bf16)
__global__ void k_scalei(ushortT* __restrict__ mo, const float* __restrict__ att) {
    size_t i8 = ((size_t)blockIdx.x * 256 + threadIdx.x) * 8;
    int ch = (int)(i8 % DMQ);
    int b = (int)(i8 / ((size_t)LQ * DMQ));
    u16x8 v = *(const u16x8*)(mo + i8);
    float4 a0 = *(const float4*)(att + (size_t)b * DMQ + ch);
    float4 a1 = *(const float4*)(att + (size_t)b * DMQ + ch + 4);
    u16x8 o;
    o[0] = f2bf(bf2f(v[0]) * a0.x); o[1] = f2bf(bf2f(v[1]) * a0.y);
    o[2] = f2bf(bf2f(v[2]) * a0.z); o[3] = f2bf(bf2f(v[3]) * a0.w);
    o[4] = f2bf(bf2f(v[4]) * a1.x); o[5] = f2bf(bf2f(v[5]) * a1.y);
    o[6] = f2bf(bf2f(v[6]) * a1.z); o[7] = f2bf(bf2f(v[7]) * a1.w);
    *(u16x8*)(mo + i8) = o;
}

__global__ void k_diag(float* __restrict__ o, float v) {
    if (blockIdx.x == 0 && threadIdx.x == 0) o[0] = v;
}

extern "C" void kernel_launch(void* const* d_in, const int* in_sizes, int n_in, void* d_out,
                              int out_size, void* d_ws, size_t ws_size, hipStream_t stream) {
    (void)in_sizes; (void)n_in; (void)out_size;
    const float* hid = (const float*)d_in[0];
    const int* mask = (const int*)d_in[1];
    const float* pool_w = (const float*)d_in[2];
    const float* pool_b = (const float*)d_in[3];
    const float* bn_g = (const float*)d_in[4];
    const float* bn_b = (const float*)d_in[5];
    const float* bn_rm = (const float*)d_in[6];
    const float* bn_rv = (const float*)d_in[7];
    const float* ipw = (const float*)d_in[8];
    const float* cw = (const float*)d_in[9];
    const float* cb = (const float*)d_in[10];
    const float* xpw = (const float*)d_in[11];
    const float* dtw = (const float*)d_in[12];
    const float* dtb = (const float*)d_in[13];
    const float* alog = (const float*)d_in[14];
    const float* Dpp = (const float*)d_in[15];
    const float* mow = (const float*)d_in[16];
    const float* opw = (const float*)d_in[17];
    const float* opb = (const float*)d_in[18];
    const float* caw1 = (const float*)d_in[19];
    const float* caw2 = (const float*)d_in[20];
    const float* fusw = (const float*)d_in[21];
    const float* fusb = (const float*)d_in[22];
    float* out = (float*)d_out;

    // workspace layout (float-equivalent offsets)
    const size_t O_IPWB = 32768;
    const size_t O_XPWB = 819200;
    const size_t O_FUSWB = 1015808;
    const size_t O_WTMPB = 1310720;
    const size_t O_XDBL = 1703936;
    const size_t O_CBASE = 4063232;   // cbase bf16 / later moutb bf16 (3145728 f.e.)
    const size_t O_RAWX = 7208960;    // rawx / hbuf+sbuf / gbuf (12582912 f.e.)
    const size_t O_SCANX = 19791872;  // scanX bf16 / later psum+pmax
    const size_t TOTAL_F = 32374784;  // 129.5 MB
    if (ws_size < TOTAL_F * 4) {
        k_diag<<<1, 64, 0, stream>>>(out, (float)(ws_size >> 20));
        return;
    }

    float* ws = (float*)d_ws;
    int* lengths = (int*)ws;
    float* avg = ws + 1024;
    float* mxp = avg + 6144;
    float* hs = mxp + 6144;
    float* att = hs + 3072;
    ushortT* ipwb = (ushortT*)(ws + O_IPWB);
    ushortT* xpwb = (ushortT*)(ws + O_XPWB);
    ushortT* fuswb = (ushortT*)(ws + O_FUSWB);
    ushortT* wtmpb = (ushortT*)(ws + O_WTMPB);
    float* xdbl = ws + O_XDBL;
    ushortT* cbase = (ushortT*)(ws + O_CBASE);
    ushortT* rawx = (ushortT*)(ws + O_RAWX);
    ushortT* scanX = (ushortT*)(ws + O_SCANX);
    // overlays
    float* hbuf = ws + O_RAWX;            // rawx dead after dwconv
    float* sbuf = hbuf + 3145728;
    ushortT* gbuf = rawx;                 // hbuf/sbuf dead after scan3
    ushortT* moutb = cbase;               // cbase dead after z-GEMM
    float* psum = ws + O_SCANX;           // scanX dead after z-GEMM
    float* pmax = psum + 196608;

    // ---- prep ----
    k_lengths<<<dim3(8), dim3(256), 0, stream>>>(mask, lengths);
    k_prep<<<dim3(9984), dim3(256), 0, stream>>>(ipw, fusw, xpw, ipwb, fuswb, xpwb);
    k_wfuse<<<dim3(768), dim3(256), 0, stream>>>(opw, mow, wtmpb);

    // ---- pool (all scales) ----
    k_pool<<<dim3(3 * 8192), dim3(64), 0, stream>>>(hid, pool_w, pool_b, bn_g, bn_b, bn_rm,
                                                    bn_rv, cbase);

    // ---- in_proj x-half (all 6 insts), flip odd insts ----
    gemm_bf16<2, 0, 0, 0, 1, 0><<<dim3(4, 64, 6), 256, 0, stream>>>(
        cbase, ipwb, rawx, nullptr, nullptr, lengths, 512, 256, 256, 512, 0, 2097152, 1,
        262144, 4194304, 0, 0, 0, 0);

    // ---- dwconv + SiLU ----
    k_dwconv<<<dim3(384), dim3(256), 0, stream>>>(rawx, cw, cb, scanX);

    // ---- x_proj ----
    gemm_bf16<0, 0, 0, 0, 0, 0><<<dim3(1, 64, 6), 256, 0, stream>>>(
        scanX, xpwb, xdbl, nullptr, nullptr, lengths, 48, 512, 512, 48, 0, 4194304, 0, 65536,
        393216, 0, 0, 0, 0);

    // ---- chunked selective scan (in place on scanX) ----
    k_scan1<<<dim3(48 * CCH * 2), dim3(256), 0, stream>>>(scanX, xdbl, dtw, dtb, alog, Dpp,
                                                          hbuf, sbuf);
    k_scan2<<<dim3(48), dim3(512), 0, stream>>>(alog, hbuf, sbuf);
    k_scan3<<<dim3(48 * (CCH - 1) * 2), dim3(256), 0, stream>>>(scanX, xdbl, dtw, dtb, alog,
                                                                hbuf);

    // ---- in_proj z-half + gate epilogue -> gbuf (dir-interleaved, unflip-scatter) ----
    gemm_bf16<2, 2, 0, 0, 1, 1><<<dim3(4, 64, 6), 256, 0, stream>>>(
        cbase, ipwb + 131072, gbuf, nullptr, scanX, lengths, 512, 256, 256, 1024, 512,
        2097152, 1, 262144, 8388608, 512, 1, 4194304, 0);

    // ---- single fused mo+op GEMM (K=1024) -> moutb bf16 (+bias) ----
    gemm_bf16<0, 0, 1, 0, 1, 0><<<dim3(2, 64, 3), 256, 0, stream>>>(
        gbuf, wtmpb, moutb, opb, nullptr, lengths, 256, 1024, 1024, 768, 0, 8388608, 0,
        262144, 256, 0, 0, 0, 256);

    // ---- attention pooling + final projection ----
    k_redu1<<<dim3(256), dim3(192), 0, stream>>>(moutb, psum, pmax);
    k_redu2<<<dim3(6), dim3(256), 0, stream>>>(psum, pmax, avg, mxp);
    k_att1<<<dim3(12), dim3(256), 0, stream>>>(avg, mxp, caw1, hs);
    k_att2<<<dim3(24), dim3(256), 0, stream>>>(hs, caw2, att);
    k_scalei<<<dim3(3072), dim3(256), 0, stream>>>(moutb, att);
    gemm_bf16<0, 0, 1, 0, 0, 0><<<dim3(6, 64, 1), 256, 0, stream>>>(
        moutb, fuswb, out, fusb, nullptr, lengths, DMQ, DMQ, DMQ, DMQ, 0, 0, 0, 0, 0, 0, 0, 0,
        0);
}